// Round 2
// baseline (2463.508 us; speedup 1.0000x reference)
//
#include <hip/hip_runtime.h>
#include <hip/hip_bf16.h>
#include <math.h>

#define BB 16
#define NN 2048
// 0 = threefry partitionable (jax >= 0.4.30 default): split via (0,i) counters, bits = o1^o2
// 1 = original threefry: split via pairs (0,2),(1,3); bits = concat halves
#define PRNG_MODE 0

__global__ void k_sentinel(float* o, int n, float v){
  int i = blockIdx.x*256 + threadIdx.x;
  if (i < n) o[i] = v;
}

/* ---------------- MLP branch ---------------- */

__global__ void k_mlp1(const float* __restrict__ xyz, const float* __restrict__ w1,
                       const float* __restrict__ b1, float* __restrict__ x1){
  int id = blockIdx.x*256 + threadIdx.x;
  if (id >= BB*64*NN) return;
  int n = id & (NN-1), o = (id>>11) & 63, b = id>>17;
  float acc = b1[o];
  #pragma unroll
  for (int c=0;c<3;c++)
    acc += w1[o*3+c] * xyz[(size_t)(b*3+c)*NN + n];
  x1[id] = fmaxf(acc, 0.f);
}

__global__ void k_mlp2(const float* __restrict__ x1, const float* __restrict__ w2,
                       const float* __restrict__ bias, float* __restrict__ x2){
  int id = blockIdx.x*256 + threadIdx.x;
  if (id >= BB*128*NN) return;
  int n = id & (NN-1), o = (id>>11) & 127, b = id>>18;
  float acc = bias[o];
  const float* xr = x1 + (size_t)b*64*NN + n;
  const float* wr = w2 + o*64;
  for (int c=0;c<64;c++) acc += wr[c] * xr[(size_t)c*NN];
  x2[id] = fmaxf(acc, 0.f);
}

__global__ __launch_bounds__(256) void k_rowmax(const float* __restrict__ x, float* __restrict__ o, int cols){
  __shared__ float sm[256];
  int row = blockIdx.x, t = threadIdx.x;
  const float* xr = x + (size_t)row*cols;
  float m = -INFINITY;
  for (int c=t;c<cols;c+=256) m = fmaxf(m, xr[c]);
  sm[t]=m; __syncthreads();
  for (int s=128;s>0;s>>=1){ if (t<s) sm[t]=fmaxf(sm[t], sm[t+s]); __syncthreads(); }
  if (!t) o[row]=sm[0];
}

// x3 = relu(W3 @ [x2; gf_broadcast] + b3), tiled 128x128, K=256 in chunks of 32
__global__ __launch_bounds__(256) void k_mlp3(const float* __restrict__ x2, const float* __restrict__ gf,
                                              const float* __restrict__ w3, const float* __restrict__ b3,
                                              float* __restrict__ x3){
  __shared__ float Wt[128][33];
  __shared__ float Xt[32][128];
  int nt = blockIdx.x, ot = blockIdx.y, b = blockIdx.z;
  int t = threadIdx.x, tx = t & 15, ty = t >> 4;
  int o0 = ot*128, n0 = nt*128;
  float acc[8][8];
  #pragma unroll
  for (int i=0;i<8;i++) for (int j=0;j<8;j++) acc[i][j]=0.f;
  for (int k0=0;k0<256;k0+=32){
    for (int i=t;i<128*32;i+=256){ int oo=i>>5, kk=i&31; Wt[oo][kk]=w3[(o0+oo)*256+k0+kk]; }
    for (int i=t;i<32*128;i+=256){ int kk=i>>7, nn=i&127; int c=k0+kk;
      Xt[kk][nn] = (c<128) ? x2[(size_t)(b*128+c)*NN + n0+nn] : gf[b*128 + (c-128)];
    }
    __syncthreads();
    for (int kk=0;kk<32;kk++){
      float xv[8], wv[8];
      #pragma unroll
      for (int j=0;j<8;j++) xv[j]=Xt[kk][tx*8+j];
      #pragma unroll
      for (int i=0;i<8;i++) wv[i]=Wt[ty*8+i][kk];
      #pragma unroll
      for (int i=0;i<8;i++)
        #pragma unroll
        for (int j=0;j<8;j++) acc[i][j] += wv[i]*xv[j];
    }
    __syncthreads();
  }
  for (int i=0;i<8;i++){
    int o = o0 + ty*8 + i;
    float bi = b3[o];
    for (int j=0;j<8;j++)
      x3[(size_t)(b*256+o)*NN + n0 + tx*8 + j] = fmaxf(acc[i][j]+bi, 0.f);
  }
}

// pmax[b,o,nt] = max over this n-tile of relu(W4 @ x3 + b4)
__global__ __launch_bounds__(256) void k_mlp4max(const float* __restrict__ x3, const float* __restrict__ w4,
                                                 const float* __restrict__ b4, float* __restrict__ pmax){
  __shared__ float Wt[128][33];
  __shared__ float Xt[32][128];
  __shared__ float red[16][8][17];
  int nt = blockIdx.x, ot = blockIdx.y, b = blockIdx.z;
  int t = threadIdx.x, tx = t & 15, ty = t >> 4;
  int o0 = ot*128, n0 = nt*128;
  float acc[8][8];
  #pragma unroll
  for (int i=0;i<8;i++) for (int j=0;j<8;j++) acc[i][j]=0.f;
  for (int k0=0;k0<256;k0+=32){
    for (int i=t;i<128*32;i+=256){ int oo=i>>5, kk=i&31; Wt[oo][kk]=w4[(o0+oo)*256+k0+kk]; }
    for (int i=t;i<32*128;i+=256){ int kk=i>>7, nn=i&127; Xt[kk][nn]=x3[(size_t)(b*256+k0+kk)*NN + n0+nn]; }
    __syncthreads();
    for (int kk=0;kk<32;kk++){
      float xv[8], wv[8];
      #pragma unroll
      for (int j=0;j<8;j++) xv[j]=Xt[kk][tx*8+j];
      #pragma unroll
      for (int i=0;i<8;i++) wv[i]=Wt[ty*8+i][kk];
      #pragma unroll
      for (int i=0;i<8;i++)
        #pragma unroll
        for (int j=0;j<8;j++) acc[i][j] += wv[i]*xv[j];
    }
    __syncthreads();
  }
  for (int i=0;i<8;i++){
    float bi = b4[o0+ty*8+i];
    float m = 0.f;           // relu output >= 0, partial max of relu'd values
    for (int j=0;j<8;j++) m = fmaxf(m, fmaxf(acc[i][j]+bi, 0.f));
    red[ty][i][tx] = m;
  }
  __syncthreads();
  if (t < 128){
    int ty2 = t>>3, i2 = t&7;
    float m = red[ty2][i2][0];
    for (int x=1;x<16;x++) m = fmaxf(m, red[ty2][i2][x]);
    pmax[(size_t)(b*1024 + o0 + ty2*8 + i2)*16 + nt] = m;
  }
}

__global__ void k_xmax(const float* __restrict__ pmax, float* __restrict__ xmax){
  int id = blockIdx.x*256 + threadIdx.x;
  if (id >= BB*1024) return;
  float m = pmax[(size_t)id*16];
  for (int k=1;k<16;k++) m = fmaxf(m, pmax[(size_t)id*16+k]);
  xmax[id] = m;
}

/* ---------------- JAX threefry PRNG permutation ---------------- */

__device__ __forceinline__ void tf2(unsigned k0, unsigned k1, unsigned x0, unsigned x1,
                                    unsigned &o0, unsigned &o1){
  unsigned ks2 = 0x1BD11BDAu ^ k0 ^ k1;
  unsigned a = x0 + k0, b = x1 + k1;
#define TFR(r) { a += b; b = (b<<(r)) | (b>>(32-(r))); b ^= a; }
  TFR(13) TFR(15) TFR(26) TFR(6)  a += k1;  b += ks2 + 1u;
  TFR(17) TFR(29) TFR(16) TFR(24) a += ks2; b += k0  + 2u;
  TFR(13) TFR(15) TFR(26) TFR(6)  a += k0;  b += k1  + 3u;
  TFR(17) TFR(29) TFR(16) TFR(24) a += k1;  b += ks2 + 4u;
  TFR(13) TFR(15) TFR(26) TFR(6)  a += ks2; b += k0  + 5u;
#undef TFR
  o0 = a; o1 = b;
}

// single-block replication of jax.random.permutation(key, n): `rounds` x {split; bits; stable sort}
__global__ __launch_bounds__(1024) void k_perm(int n, int rounds, unsigned k0, unsigned k1,
                                               int* __restrict__ out, int mode){
  __shared__ unsigned keys[2048];
  __shared__ int va[2048];
  __shared__ int vb[2048];
  int t = threadIdx.x;
  for (int i=t;i<n;i+=1024) va[i]=i;
  __syncthreads();
  unsigned ck0=k0, ck1=k1;
  for (int r=0;r<rounds;r++){
    unsigned nk0,nk1,sk0,sk1;
    if (mode == 1){
      unsigned a0,c0,a1,c1;
      tf2(ck0,ck1, 0u,2u, a0,c0);
      tf2(ck0,ck1, 1u,3u, a1,c1);
      nk0=a0; nk1=a1; sk0=c0; sk1=c1;
    } else {
      tf2(ck0,ck1, 0u,0u, nk0,nk1);
      tf2(ck0,ck1, 0u,1u, sk0,sk1);
    }
    ck0=nk0; ck1=nk1;
    if (mode == 1){
      int half=n>>1;
      for (int i=t;i<half;i+=1024){ unsigned a,bq; tf2(sk0,sk1,(unsigned)i,(unsigned)(half+i),a,bq); keys[i]=a; keys[half+i]=bq; }
    } else {
      for (int i=t;i<n;i+=1024){ unsigned a,bq; tf2(sk0,sk1,0u,(unsigned)i,a,bq); keys[i] = a^bq; }
    }
    __syncthreads();
    // stable ascending counting sort: rank = #{j : k_j < k_i or (k_j==k_i and j<i)}
    for (int i=t;i<n;i+=1024){
      unsigned ki = keys[i]; int rank=0;
      for (int j=0;j<n;j++){ unsigned kj=keys[j]; rank += (kj<ki) || (kj==ki && j<i); }
      vb[rank] = va[i];
    }
    __syncthreads();
    for (int i=t;i<n;i+=1024) va[i]=vb[i];
    __syncthreads();
  }
  for (int i=t;i<n;i+=1024) out[i]=va[i];
}

/* ---------------- graph branch ---------------- */

__global__ void k_transpose(const float* __restrict__ xyz, float* __restrict__ verts){
  int id = blockIdx.x*256 + threadIdx.x;
  if (id >= BB*NN*3) return;
  int c = id % 3, v = (id/3) % NN, b = id/(3*NN);
  verts[id] = xyz[(size_t)(b*3+c)*NN + v];
}

// top-(ksel+1) smallest distances, drop first (self). Stable ties -> lowest index (matches XLA top_k).
__global__ __launch_bounds__(256) void k_knn(const float* __restrict__ verts, int V, int ksel,
                                             const int* __restrict__ qmap, int numQ,
                                             int* __restrict__ out){
  __shared__ float dist[2048];
  __shared__ float sd[256];
  __shared__ int si[256];
  int q = blockIdx.x, b = blockIdx.y, t = threadIdx.x;
  const float* vb = verts + (size_t)b*V*3;
  int qv = qmap ? qmap[q] : q;
  float qx = vb[qv*3+0], qy = vb[qv*3+1], qz = vb[qv*3+2];
  float qq = qx*qx + qy*qy + qz*qz;
  for (int w=t; w<V; w+=256){
    float wx=vb[w*3+0], wy=vb[w*3+1], wz=vb[w*3+2];
    float inner = qx*wx + qy*wy + qz*wz;
    float ww = wx*wx + wy*wy + wz*wz;
    dist[w] = qq - 2.f*inner + ww;   // self: exactly 0
  }
  __syncthreads();
  int* orow = out + ((size_t)b*numQ + q)*ksel;
  for (int r=0;r<=ksel;r++){
    float bd = INFINITY; int bi = V;
    for (int w=t; w<V; w+=256){
      float d = dist[w];
      if (d < bd){ bd = d; bi = w; }   // strict < keeps lowest index within stride
    }
    sd[t]=bd; si[t]=bi;
    __syncthreads();
    for (int s=128;s>0;s>>=1){
      if (t<s){
        float od=sd[t+s]; int oi=si[t+s];
        if (od<sd[t] || (od==sd[t] && oi<si[t])){ sd[t]=od; si[t]=oi; }
      }
      __syncthreads();
    }
    int sel = si[0];
    if (t==0){
      if (r>0) orow[r-1]=sel;
      dist[sel]=INFINITY;
    }
    __syncthreads();
  }
}

__global__ void k_dirs(const float* __restrict__ verts, int V, const int* __restrict__ idx,
                       float* __restrict__ dirs, int total){
  int id = blockIdx.x*256 + threadIdx.x;
  if (id >= total) return;
  int v = (id/20) % V, b = id/(20*V);
  const float* vb = verts + (size_t)b*V*3;
  int nb = idx[id];
  float dx = vb[nb*3+0]-vb[v*3+0];
  float dy = vb[nb*3+1]-vb[v*3+1];
  float dz = vb[nb*3+2]-vb[v*3+2];
  float s = 1.f / fmaxf(sqrtf(dx*dx+dy*dy+dz*dz), 1e-12f);
  dirs[(size_t)id*3+0]=dx*s; dirs[(size_t)id*3+1]=dy*s; dirs[(size_t)id*3+2]=dz*s;
}

__global__ void k_surf(const float* __restrict__ dirs, const float* __restrict__ dir0,
                       float* __restrict__ fm0, int V){
  int id = blockIdx.x*256 + threadIdx.x;
  if (id >= BB*V*32) return;
  int k = id & 31; int vv = (id>>5) % V; int b = id/(32*V);
  float nx=dir0[k], ny=dir0[32+k], nz=dir0[64+k];
  float s = 1.f/fmaxf(sqrtf(nx*nx+ny*ny+nz*nz), 1e-12f);
  nx*=s; ny*=s; nz*=s;
  const float* dd = dirs + (size_t)(b*V+vv)*60;
  float m = 0.f;
  for (int n=0;n<20;n++){
    float th = dd[n*3]*nx + dd[n*3+1]*ny + dd[n*3+2]*nz;
    m = fmaxf(m, fmaxf(th, 0.f));
  }
  fm0[(size_t)(b*V+vv)*32 + k] = m;
}

// feat = fm @ W + bias ; fm (R,K) f32, W (K,C)
__global__ void k_feat(const float* __restrict__ fm, const float* __restrict__ w,
                       const float* __restrict__ bias, float* __restrict__ feat,
                       int R, int K, int C){
  int id = blockIdx.x*256 + threadIdx.x;
  if (id >= R*C) return;
  int c = id % C, r = id / C;
  float acc = bias[c];
  const float* fr = fm + (size_t)r*K;
  for (int k=0;k<K;k++) acc += fr[k]*w[(size_t)k*C+c];
  feat[id] = acc;
}

// out = [relu]( feat[:, :OC] + max_n( relu(dirs . ndir_col) * feat[nb, OC: ] ) )
__global__ void k_comb(const float* __restrict__ feat, const int* __restrict__ idx,
                       const float* __restrict__ dirs, const float* __restrict__ dw,
                       float* __restrict__ outp, int V, int OC, int relu_flag){
  int id = blockIdx.x*256 + threadIdx.x;
  if (id >= BB*V*OC) return;
  int oc = id % OC, v = (id/OC) % V, b = id/(OC*V);
  float wx=dw[oc], wy=dw[OC+oc], wz=dw[2*OC+oc];
  float s = 1.f/fmaxf(sqrtf(wx*wx+wy*wy+wz*wz), 1e-12f);
  wx*=s; wy*=s; wz*=s;
  size_t row = (size_t)b*V + v;
  const int* ir = idx + row*20;
  const float* dd = dirs + row*60;
  float center = feat[row*2*OC + oc];
  float m = -INFINITY;
  for (int n=0;n<20;n++){
    int nb = ir[n];
    float th = dd[n*3]*wx + dd[n*3+1]*wy + dd[n*3+2]*wz;
    th = fmaxf(th, 0.f);
    float sup = feat[((size_t)b*V + nb)*2*OC + OC + oc];
    m = fmaxf(m, th*sup);
  }
  float rv = center + m;
  outp[row*OC + oc] = relu_flag ? fmaxf(rv, 0.f) : rv;
}

__global__ void k_pool(const float* __restrict__ fm, const int* __restrict__ idx4,
                       float* __restrict__ outp, int V, int C, int numS){
  int id = blockIdx.x*256 + threadIdx.x;
  if (id >= BB*numS*C) return;
  int c = id % C, sI = (id/C) % numS, b = id/(C*numS);
  const int* ir = idx4 + ((size_t)b*numS + sI)*4;
  float m = -INFINITY;
  for (int n=0;n<4;n++) m = fmaxf(m, fm[((size_t)b*V + ir[n])*C + c]);
  outp[((size_t)b*numS + sI)*C + c] = m;
}

__global__ void k_vgather(const float* __restrict__ vin, const int* __restrict__ perm,
                          float* __restrict__ vout, int V, int numS){
  int id = blockIdx.x*256 + threadIdx.x;
  if (id >= BB*numS*3) return;
  int c = id % 3, sI = (id/3) % numS, b = id/(3*numS);
  vout[id] = vin[((size_t)b*V + perm[sI])*3 + c];
}

__global__ void k_colmax(const float* __restrict__ x, float* __restrict__ o, int Vr, int C){
  int id = blockIdx.x*256 + threadIdx.x;
  if (id >= BB*C) return;
  int c = id % C, b = id / C;
  float m = -INFINITY;
  for (int v=0; v<Vr; v++) m = fmaxf(m, x[(size_t)(b*Vr+v)*C + c]);
  o[id] = m;
}

/* ---------------- FC head ---------------- */

__global__ void k_emb(const float* __restrict__ xmax, const float* __restrict__ fg,
                      const float* __restrict__ fcw, const float* __restrict__ fcb,
                      float* __restrict__ outp){
  int id = blockIdx.x*256 + threadIdx.x;
  if (id >= BB*512) return;
  int e = id % 512, b = id / 512;
  const float* wr = fcw + (size_t)e*2048;
  const float* xb = xmax + b*1024;
  const float* gb = fg + b*1024;
  float acc = fcb[e];
  for (int k=0;k<1024;k++) acc += xb[k]*wr[k];
  for (int k=0;k<1024;k++) acc += gb[k]*wr[1024+k];
  outp[id] = acc;
}

__global__ void k_h(const float* __restrict__ xmax, const float* __restrict__ fg,
                    const float* __restrict__ clw1, const float* __restrict__ clb1,
                    const float* __restrict__ gamma, const float* __restrict__ beta,
                    float* __restrict__ h){
  int id = blockIdx.x*256 + threadIdx.x;
  if (id >= BB*512) return;
  int j = id % 512, b = id / 512;
  const float* wr = clw1 + (size_t)j*2048;
  const float* xb = xmax + b*1024;
  const float* gb = fg + b*1024;
  float acc = clb1[j];
  for (int k=0;k<1024;k++) acc += xb[k]*wr[k];
  for (int k=0;k<1024;k++) acc += gb[k]*wr[1024+k];
  const float inv_s = 1.0f / sqrtf(1.0f + 1e-5f);
  float v = acc * inv_s * gamma[j] + beta[j];
  h[id] = fmaxf(v, 0.f);
}

__global__ void k_pred(const float* __restrict__ h, const float* __restrict__ clw2,
                       const float* __restrict__ clb2, float* __restrict__ outp){
  int id = threadIdx.x;
  if (id >= BB*6) return;
  int o = id % 6, b = id / 6;
  float acc = clb2[o];
  const float* hb = h + b*512;
  const float* wr = clw2 + o*512;
  for (int j=0;j<512;j++) acc += hb[j]*wr[j];
  outp[BB*512 + id] = acc;
}

/* ---------------- launch ---------------- */

static inline int cdiv(long long a, int b){ return (int)((a + b - 1)/b); }

extern "C" void kernel_launch(void* const* d_in, const int* in_sizes, int n_in,
                              void* d_out, int out_size, void* d_ws, size_t ws_size,
                              hipStream_t stream){
  float* out = (float*)d_out;
  if (n_in != 30 || in_sizes[0] != BB*3*NN || out_size != BB*512 + BB*6){
    k_sentinel<<<cdiv(out_size,256),256,0,stream>>>(out, out_size, 2000.0f);
    return;
  }
  const float* xyz  = (const float*)d_in[0];
  const float* w1   = (const float*)d_in[1];
  const float* b1   = (const float*)d_in[2];
  const float* w2   = (const float*)d_in[3];
  const float* b2   = (const float*)d_in[4];
  const float* w3   = (const float*)d_in[5];
  const float* b3   = (const float*)d_in[6];
  const float* w4   = (const float*)d_in[7];
  const float* b4   = (const float*)d_in[8];
  const float* fcw  = (const float*)d_in[9];
  const float* fcb  = (const float*)d_in[10];
  const float* dir0 = (const float*)d_in[11];
  const float* wc1  = (const float*)d_in[12];
  const float* bc1  = (const float*)d_in[13];
  const float* dir1 = (const float*)d_in[14];
  const float* wc2  = (const float*)d_in[15];
  const float* bc2  = (const float*)d_in[16];
  const float* dir2 = (const float*)d_in[17];
  const float* wc3  = (const float*)d_in[18];
  const float* bc3  = (const float*)d_in[19];
  const float* dir3 = (const float*)d_in[20];
  const float* wc4  = (const float*)d_in[21];
  const float* bc4  = (const float*)d_in[22];
  const float* dir4 = (const float*)d_in[23];
  const float* clw1 = (const float*)d_in[24];
  const float* clb1 = (const float*)d_in[25];
  const float* gma  = (const float*)d_in[26];
  const float* bta  = (const float*)d_in[27];
  const float* clw2 = (const float*)d_in[28];
  const float* clb2 = (const float*)d_in[29];

  char* w = (char*)d_ws;
  size_t off = 0;
  auto A = [&](size_t bytes){ size_t r = off; off += (bytes + 255) & ~(size_t)255; return r; };
  const size_t oXMAX = A((size_t)BB*1024*4);
  const size_t oFG   = A((size_t)BB*1024*4);
  const size_t oGF   = A((size_t)BB*128*4);
  const size_t oH    = A((size_t)BB*512*4);
  const size_t oP2048= A(2048*4);
  const size_t oP512 = A(512*4);
  const size_t oPMAX = A((size_t)BB*1024*16*4);
  const size_t oV0   = A((size_t)BB*2048*3*4);
  const size_t oV1   = A((size_t)BB*512*3*4);
  const size_t oV2   = A((size_t)BB*128*3*4);
  const size_t oIDX0 = A((size_t)BB*2048*20*4);
  const size_t oDIR0 = A((size_t)BB*2048*20*3*4);
  const size_t oFM0  = A((size_t)BB*2048*32*4);
  const size_t oFM1  = A((size_t)BB*2048*64*4);
  const size_t oI40  = A((size_t)BB*512*4*4);
  const size_t oFM1P = A((size_t)BB*512*64*4);
  const size_t oIDX1 = A((size_t)BB*512*20*4);
  const size_t oDIR1 = A((size_t)BB*512*20*3*4);
  const size_t oFM2  = A((size_t)BB*512*128*4);
  const size_t oFM3  = A((size_t)BB*512*256*4);
  const size_t oI41  = A((size_t)BB*128*4*4);
  const size_t oFM3P = A((size_t)BB*128*256*4);
  const size_t oIDX2 = A((size_t)BB*128*20*4);
  const size_t oDIR2 = A((size_t)BB*128*20*3*4);
  const size_t oFM4  = A((size_t)BB*128*1024*4);
  const size_t oBIGA = A((size_t)BB*256*NN*4);   // x1, then x3
  const size_t oBIGB = A((size_t)BB*128*NN*4);   // x2, then feat1..feat4
  if (off > ws_size){
    k_sentinel<<<cdiv(out_size,256),256,0,stream>>>(out, out_size, 1000.0f);
    return;
  }
  float* xmax = (float*)(w+oXMAX); float* fg = (float*)(w+oFG);
  float* gf = (float*)(w+oGF);     float* hbuf = (float*)(w+oH);
  int* p2048 = (int*)(w+oP2048);   int* p512 = (int*)(w+oP512);
  float* pmax = (float*)(w+oPMAX);
  float* v0 = (float*)(w+oV0); float* v1 = (float*)(w+oV1); float* v2 = (float*)(w+oV2);
  int* idx0 = (int*)(w+oIDX0); int* idx1 = (int*)(w+oIDX1); int* idx2 = (int*)(w+oIDX2);
  int* i40 = (int*)(w+oI40);   int* i41 = (int*)(w+oI41);
  float* d0 = (float*)(w+oDIR0); float* d1 = (float*)(w+oDIR1); float* d2 = (float*)(w+oDIR2);
  float* fm0 = (float*)(w+oFM0); float* fm1 = (float*)(w+oFM1); float* fm1p = (float*)(w+oFM1P);
  float* fm2 = (float*)(w+oFM2); float* fm3 = (float*)(w+oFM3); float* fm3p = (float*)(w+oFM3P);
  float* fm4 = (float*)(w+oFM4);
  float* x1 = (float*)(w+oBIGA); float* x3 = (float*)(w+oBIGA);
  float* x2 = (float*)(w+oBIGB); float* feat = (float*)(w+oBIGB);

  // MLP branch
  k_mlp1<<<cdiv((long long)BB*64*NN,256),256,0,stream>>>(xyz, w1, b1, x1);
  k_mlp2<<<cdiv((long long)BB*128*NN,256),256,0,stream>>>(x1, w2, b2, x2);
  k_rowmax<<<BB*128,256,0,stream>>>(x2, gf, NN);
  k_mlp3<<<dim3(16,2,BB),256,0,stream>>>(x2, gf, w3, b3, x3);
  k_mlp4max<<<dim3(16,8,BB),256,0,stream>>>(x3, w4, b4, pmax);
  k_xmax<<<cdiv(BB*1024,256),256,0,stream>>>(pmax, xmax);

  // graph branch: stage 0 (V=2048)
  k_transpose<<<cdiv((long long)BB*NN*3,256),256,0,stream>>>(xyz, v0);
  k_perm<<<1,1024,0,stream>>>(2048, 2, 0u, 1u, p2048, PRNG_MODE);  // jax.random.key(1)
  k_perm<<<1,1024,0,stream>>>(512,  1, 0u, 2u, p512,  PRNG_MODE);  // jax.random.key(2)
  k_knn<<<dim3(2048,BB),256,0,stream>>>(v0, 2048, 20, nullptr, 2048, idx0);
  k_dirs<<<cdiv((long long)BB*2048*20,256),256,0,stream>>>(v0, 2048, idx0, d0, BB*2048*20);
  k_surf<<<cdiv((long long)BB*2048*32,256),256,0,stream>>>(d0, dir0, fm0, 2048);
  k_feat<<<cdiv((long long)BB*2048*128,256),256,0,stream>>>(fm0, wc1, bc1, feat, BB*2048, 32, 128);
  k_comb<<<cdiv((long long)BB*2048*64,256),256,0,stream>>>(feat, idx0, d0, dir1, fm1, 2048, 64, 1);
  // pool 1
  k_knn<<<dim3(512,BB),256,0,stream>>>(v0, 2048, 4, p2048, 512, i40);
  k_pool<<<cdiv((long long)BB*512*64,256),256,0,stream>>>(fm1, i40, fm1p, 2048, 64, 512);
  k_vgather<<<cdiv((long long)BB*512*3,256),256,0,stream>>>(v0, p2048, v1, 2048, 512);
  // stage 1 (V=512)
  k_knn<<<dim3(512,BB),256,0,stream>>>(v1, 512, 20, nullptr, 512, idx1);
  k_dirs<<<cdiv((long long)BB*512*20,256),256,0,stream>>>(v1, 512, idx1, d1, BB*512*20);
  k_feat<<<cdiv((long long)BB*512*256,256),256,0,stream>>>(fm1p, wc2, bc2, feat, BB*512, 64, 256);
  k_comb<<<cdiv((long long)BB*512*128,256),256,0,stream>>>(feat, idx1, d1, dir2, fm2, 512, 128, 1);
  k_feat<<<cdiv((long long)BB*512*512,256),256,0,stream>>>(fm2, wc3, bc3, feat, BB*512, 128, 512);
  k_comb<<<cdiv((long long)BB*512*256,256),256,0,stream>>>(feat, idx1, d1, dir3, fm3, 512, 256, 1);
  // pool 2
  k_knn<<<dim3(128,BB),256,0,stream>>>(v1, 512, 4, p512, 128, i41);
  k_pool<<<cdiv((long long)BB*128*256,256),256,0,stream>>>(fm3, i41, fm3p, 512, 256, 128);
  k_vgather<<<cdiv((long long)BB*128*3,256),256,0,stream>>>(v1, p512, v2, 512, 128);
  // stage 2 (V=128)
  k_knn<<<dim3(128,BB),256,0,stream>>>(v2, 128, 20, nullptr, 128, idx2);
  k_dirs<<<cdiv((long long)BB*128*20,256),256,0,stream>>>(v2, 128, idx2, d2, BB*128*20);
  k_feat<<<cdiv((long long)BB*128*2048,256),256,0,stream>>>(fm3p, wc4, bc4, feat, BB*128, 256, 2048);
  k_comb<<<cdiv((long long)BB*128*1024,256),256,0,stream>>>(feat, idx2, d2, dir4, fm4, 128, 1024, 0);
  k_colmax<<<cdiv(BB*1024,256),256,0,stream>>>(fm4, fg, 128, 1024);

  // FC head
  k_emb<<<cdiv(BB*512,256),256,0,stream>>>(xmax, fg, fcw, fcb, out);
  k_h<<<cdiv(BB*512,256),256,0,stream>>>(xmax, fg, clw1, clb1, gma, bta, hbuf);
  k_pred<<<1,128,0,stream>>>(hbuf, clw2, clb2, out);
}

// Round 3
// 2101.659 us; speedup vs baseline: 1.1722x; 1.1722x over previous
//
#include <hip/hip_runtime.h>
#include <hip/hip_bf16.h>
#include <math.h>

#define BB 16
#define NN 2048
#define PRNG_MODE 0

__global__ void k_sentinel(float* o, int n, float v){
  int i = blockIdx.x*256 + threadIdx.x;
  if (i < n) o[i] = v;
}

/* ---------------- MLP branch ---------------- */

__global__ void k_mlp1(const float* __restrict__ xyz, const float* __restrict__ w1,
                       const float* __restrict__ b1, float* __restrict__ x1){
  int id = blockIdx.x*256 + threadIdx.x;
  if (id >= BB*64*NN) return;
  int n = id & (NN-1), o = (id>>11) & 63, b = id>>17;
  float acc = b1[o];
  #pragma unroll
  for (int c=0;c<3;c++)
    acc += w1[o*3+c] * xyz[(size_t)(b*3+c)*NN + n];
  x1[id] = fmaxf(acc, 0.f);
}

__global__ void k_mlp2(const float* __restrict__ x1, const float* __restrict__ w2,
                       const float* __restrict__ bias, float* __restrict__ x2){
  int id = blockIdx.x*256 + threadIdx.x;
  if (id >= BB*128*NN) return;
  int n = id & (NN-1), o = (id>>11) & 127, b = id>>18;
  float acc = bias[o];
  const float* xr = x1 + (size_t)b*64*NN + n;
  const float* wr = w2 + o*64;
  for (int c=0;c<64;c++) acc += wr[c] * xr[(size_t)c*NN];
  x2[id] = fmaxf(acc, 0.f);
}

__global__ __launch_bounds__(256) void k_rowmax(const float* __restrict__ x, float* __restrict__ o, int cols){
  __shared__ float sm[256];
  int row = blockIdx.x, t = threadIdx.x;
  const float* xr = x + (size_t)row*cols;
  float m = -INFINITY;
  for (int c=t;c<cols;c+=256) m = fmaxf(m, xr[c]);
  sm[t]=m; __syncthreads();
  for (int s=128;s>0;s>>=1){ if (t<s) sm[t]=fmaxf(sm[t], sm[t+s]); __syncthreads(); }
  if (!t) o[row]=sm[0];
}

// x3 = relu(W3 @ [x2; gf_broadcast] + b3), tiled 128x128, K=256 in chunks of 32
__global__ __launch_bounds__(256) void k_mlp3(const float* __restrict__ x2, const float* __restrict__ gf,
                                              const float* __restrict__ w3, const float* __restrict__ b3,
                                              float* __restrict__ x3){
  __shared__ float Wt[128][33];
  __shared__ float Xt[32][128];
  int nt = blockIdx.x, ot = blockIdx.y, b = blockIdx.z;
  int t = threadIdx.x, tx = t & 15, ty = t >> 4;
  int o0 = ot*128, n0 = nt*128;
  float acc[8][8];
  #pragma unroll
  for (int i=0;i<8;i++) for (int j=0;j<8;j++) acc[i][j]=0.f;
  for (int k0=0;k0<256;k0+=32){
    for (int i=t;i<128*32;i+=256){ int oo=i>>5, kk=i&31; Wt[oo][kk]=w3[(o0+oo)*256+k0+kk]; }
    for (int i=t;i<32*128;i+=256){ int kk=i>>7, nn=i&127; int c=k0+kk;
      Xt[kk][nn] = (c<128) ? x2[(size_t)(b*128+c)*NN + n0+nn] : gf[b*128 + (c-128)];
    }
    __syncthreads();
    for (int kk=0;kk<32;kk++){
      float xv[8], wv[8];
      #pragma unroll
      for (int j=0;j<8;j++) xv[j]=Xt[kk][tx*8+j];
      #pragma unroll
      for (int i=0;i<8;i++) wv[i]=Wt[ty*8+i][kk];
      #pragma unroll
      for (int i=0;i<8;i++)
        #pragma unroll
        for (int j=0;j<8;j++) acc[i][j] += wv[i]*xv[j];
    }
    __syncthreads();
  }
  for (int i=0;i<8;i++){
    int o = o0 + ty*8 + i;
    float bi = b3[o];
    for (int j=0;j<8;j++)
      x3[(size_t)(b*256+o)*NN + n0 + tx*8 + j] = fmaxf(acc[i][j]+bi, 0.f);
  }
}

// pmax[b,o,nt] = max over this n-tile of relu(W4 @ x3 + b4)
__global__ __launch_bounds__(256) void k_mlp4max(const float* __restrict__ x3, const float* __restrict__ w4,
                                                 const float* __restrict__ b4, float* __restrict__ pmax){
  __shared__ float Wt[128][33];
  __shared__ float Xt[32][128];
  __shared__ float red[16][8][17];
  int nt = blockIdx.x, ot = blockIdx.y, b = blockIdx.z;
  int t = threadIdx.x, tx = t & 15, ty = t >> 4;
  int o0 = ot*128, n0 = nt*128;
  float acc[8][8];
  #pragma unroll
  for (int i=0;i<8;i++) for (int j=0;j<8;j++) acc[i][j]=0.f;
  for (int k0=0;k0<256;k0+=32){
    for (int i=t;i<128*32;i+=256){ int oo=i>>5, kk=i&31; Wt[oo][kk]=w4[(o0+oo)*256+k0+kk]; }
    for (int i=t;i<32*128;i+=256){ int kk=i>>7, nn=i&127; Xt[kk][nn]=x3[(size_t)(b*256+k0+kk)*NN + n0+nn]; }
    __syncthreads();
    for (int kk=0;kk<32;kk++){
      float xv[8], wv[8];
      #pragma unroll
      for (int j=0;j<8;j++) xv[j]=Xt[kk][tx*8+j];
      #pragma unroll
      for (int i=0;i<8;i++) wv[i]=Wt[ty*8+i][kk];
      #pragma unroll
      for (int i=0;i<8;i++)
        #pragma unroll
        for (int j=0;j<8;j++) acc[i][j] += wv[i]*xv[j];
    }
    __syncthreads();
  }
  for (int i=0;i<8;i++){
    float bi = b4[o0+ty*8+i];
    float m = 0.f;
    for (int j=0;j<8;j++) m = fmaxf(m, fmaxf(acc[i][j]+bi, 0.f));
    red[ty][i][tx] = m;
  }
  __syncthreads();
  if (t < 128){
    int ty2 = t>>3, i2 = t&7;
    float m = red[ty2][i2][0];
    for (int x=1;x<16;x++) m = fmaxf(m, red[ty2][i2][x]);
    pmax[(size_t)(b*1024 + o0 + ty2*8 + i2)*16 + nt] = m;
  }
}

__global__ void k_xmax(const float* __restrict__ pmax, float* __restrict__ xmax){
  int id = blockIdx.x*256 + threadIdx.x;
  if (id >= BB*1024) return;
  float m = pmax[(size_t)id*16];
  for (int k=1;k<16;k++) m = fmaxf(m, pmax[(size_t)id*16+k]);
  xmax[id] = m;
}

/* ---------------- JAX threefry PRNG permutation ---------------- */

__device__ __forceinline__ void tf2(unsigned k0, unsigned k1, unsigned x0, unsigned x1,
                                    unsigned &o0, unsigned &o1){
  unsigned ks2 = 0x1BD11BDAu ^ k0 ^ k1;
  unsigned a = x0 + k0, b = x1 + k1;
#define TFR(r) { a += b; b = (b<<(r)) | (b>>(32-(r))); b ^= a; }
  TFR(13) TFR(15) TFR(26) TFR(6)  a += k1;  b += ks2 + 1u;
  TFR(17) TFR(29) TFR(16) TFR(24) a += ks2; b += k0  + 2u;
  TFR(13) TFR(15) TFR(26) TFR(6)  a += k0;  b += k1  + 3u;
  TFR(17) TFR(29) TFR(16) TFR(24) a += k1;  b += ks2 + 4u;
  TFR(13) TFR(15) TFR(26) TFR(6)  a += ks2; b += k0  + 5u;
#undef TFR
  o0 = a; o1 = b;
}

__global__ __launch_bounds__(1024) void k_perm(int n, int rounds, unsigned k0, unsigned k1,
                                               int* __restrict__ out, int mode){
  __shared__ unsigned keys[2048];
  __shared__ int va[2048];
  __shared__ int vb[2048];
  int t = threadIdx.x;
  for (int i=t;i<n;i+=1024) va[i]=i;
  __syncthreads();
  unsigned ck0=k0, ck1=k1;
  for (int r=0;r<rounds;r++){
    unsigned nk0,nk1,sk0,sk1;
    if (mode == 1){
      unsigned a0,c0,a1,c1;
      tf2(ck0,ck1, 0u,2u, a0,c0);
      tf2(ck0,ck1, 1u,3u, a1,c1);
      nk0=a0; nk1=a1; sk0=c0; sk1=c1;
    } else {
      tf2(ck0,ck1, 0u,0u, nk0,nk1);
      tf2(ck0,ck1, 0u,1u, sk0,sk1);
    }
    ck0=nk0; ck1=nk1;
    if (mode == 1){
      int half=n>>1;
      for (int i=t;i<half;i+=1024){ unsigned a,bq; tf2(sk0,sk1,(unsigned)i,(unsigned)(half+i),a,bq); keys[i]=a; keys[half+i]=bq; }
    } else {
      for (int i=t;i<n;i+=1024){ unsigned a,bq; tf2(sk0,sk1,0u,(unsigned)i,a,bq); keys[i] = a^bq; }
    }
    __syncthreads();
    for (int i=t;i<n;i+=1024){
      unsigned ki = keys[i]; int rank=0;
      for (int j=0;j<n;j++){ unsigned kj=keys[j]; rank += (kj<ki) || (kj==ki && j<i); }
      vb[rank] = va[i];
    }
    __syncthreads();
    for (int i=t;i<n;i+=1024) va[i]=vb[i];
    __syncthreads();
  }
  for (int i=t;i<n;i+=1024) out[i]=va[i];
}

/* ---------------- graph branch ---------------- */

__global__ void k_transpose(const float* __restrict__ xyz, float* __restrict__ verts){
  int id = blockIdx.x*256 + threadIdx.x;
  if (id >= BB*NN*3) return;
  int c = id % 3, v = (id/3) % NN, b = id/(3*NN);
  verts[id] = xyz[(size_t)(b*3+c)*NN + v];
}

// Wave-per-query KNN: 4 waves/block, barrier-free lexicographic successor selection.
// V = CPL*64. Stable top-(KSEL+1), drop self; ties -> lowest index (matches XLA top_k).
template<int CPL, int KSEL>
__global__ __launch_bounds__(256) void k_knn_w(const float* __restrict__ verts,
                                               const int* __restrict__ qmap, int numQ,
                                               int* __restrict__ out){
  constexpr int V = CPL*64;
  __shared__ float vx[V], vy[V], vz[V];
  int t = threadIdx.x;
  int b = blockIdx.y;
  const float* vb = verts + (size_t)b*V*3;
  for (int j=t; j<V; j+=256){
    vx[j]=vb[j*3+0]; vy[j]=vb[j*3+1]; vz[j]=vb[j*3+2];
  }
  __syncthreads();
  int wid = t>>6, lane = t&63;
  int q = blockIdx.x*4 + wid;
  if (q >= numQ) return;
  int qv = qmap ? qmap[q] : q;
  float qx = vx[qv], qy = vy[qv], qz = vz[qv];
  float qq = qx*qx + qy*qy + qz*qz;
  float d[CPL];
  #pragma unroll
  for (int i=0;i<CPL;i++){
    int c = lane + i*64;
    float wx=vx[c], wy=vy[c], wz=vz[c];
    float inner = qx*wx + qy*wy + qz*wz;
    float ww = wx*wx + wy*wy + wz*wz;
    d[i] = qq - 2.f*inner + ww;
  }
  int* orow = out + ((size_t)b*numQ + q)*KSEL;
  float last_d = -INFINITY; int last_i = -1;
  for (int r=0; r<=KSEL; r++){
    float bd = INFINITY; int bi = 0x7fffffff;
    #pragma unroll
    for (int i=0;i<CPL;i++){
      int c = lane + i*64;
      bool qual = (d[i] > last_d) || (d[i] == last_d && c > last_i);
      bool better = qual && ((d[i] < bd) || (d[i] == bd && c < bi));
      bd = better ? d[i] : bd;
      bi = better ? c : bi;
    }
    #pragma unroll
    for (int off=32; off>0; off>>=1){
      float od = __shfl_xor(bd, off, 64);
      int   oi = __shfl_xor(bi, off, 64);
      bool take = (od < bd) || (od == bd && oi < bi);
      bd = take ? od : bd;
      bi = take ? oi : bi;
    }
    if (r>0 && lane==0) orow[r-1] = bi;
    last_d = bd; last_i = bi;
  }
}

__global__ void k_dirs(const float* __restrict__ verts, int V, const int* __restrict__ idx,
                       float* __restrict__ dirs, int total){
  int id = blockIdx.x*256 + threadIdx.x;
  if (id >= total) return;
  int v = (id/20) % V, b = id/(20*V);
  const float* vb = verts + (size_t)b*V*3;
  int nb = idx[id];
  float dx = vb[nb*3+0]-vb[v*3+0];
  float dy = vb[nb*3+1]-vb[v*3+1];
  float dz = vb[nb*3+2]-vb[v*3+2];
  float s = 1.f / fmaxf(sqrtf(dx*dx+dy*dy+dz*dz), 1e-12f);
  dirs[(size_t)id*3+0]=dx*s; dirs[(size_t)id*3+1]=dy*s; dirs[(size_t)id*3+2]=dz*s;
}

__global__ void k_surf(const float* __restrict__ dirs, const float* __restrict__ dir0,
                       float* __restrict__ fm0, int V){
  int id = blockIdx.x*256 + threadIdx.x;
  if (id >= BB*V*32) return;
  int k = id & 31; int vv = (id>>5) % V; int b = id/(32*V);
  float nx=dir0[k], ny=dir0[32+k], nz=dir0[64+k];
  float s = 1.f/fmaxf(sqrtf(nx*nx+ny*ny+nz*nz), 1e-12f);
  nx*=s; ny*=s; nz*=s;
  const float* dd = dirs + (size_t)(b*V+vv)*60;
  float m = 0.f;
  for (int n=0;n<20;n++){
    float th = dd[n*3]*nx + dd[n*3+1]*ny + dd[n*3+2]*nz;
    m = fmaxf(m, fmaxf(th, 0.f));
  }
  fm0[(size_t)(b*V+vv)*32 + k] = m;
}

// O = A @ B + bias; A (R,K) rm, B (K,C) rm. Tiles 128x128, K-chunk 32.
// Requires R%128==0, C%128==0, K%32==0.
__global__ __launch_bounds__(256) void k_gemm(const float* __restrict__ A, const float* __restrict__ Bm,
                                              const float* __restrict__ bias, float* __restrict__ O,
                                              int R, int K, int C){
  __shared__ float At[128][33];
  __shared__ float Bt[32][128];
  int ct = blockIdx.x, rt = blockIdx.y;
  int t = threadIdx.x, tx = t & 15, ty = t >> 4;
  int r0 = rt*128, c0 = ct*128;
  float acc[8][8];
  #pragma unroll
  for (int i=0;i<8;i++) for (int j=0;j<8;j++) acc[i][j]=0.f;
  for (int k0=0;k0<K;k0+=32){
    for (int i=t;i<128*32;i+=256){ int rr=i>>5, kk=i&31; At[rr][kk]=A[(size_t)(r0+rr)*K + k0+kk]; }
    for (int i=t;i<32*128;i+=256){ int kk=i>>7, cc=i&127; Bt[kk][cc]=Bm[(size_t)(k0+kk)*C + c0+cc]; }
    __syncthreads();
    for (int kk=0;kk<32;kk++){
      float xv[8], wv[8];
      #pragma unroll
      for (int j=0;j<8;j++) xv[j]=Bt[kk][tx*8+j];
      #pragma unroll
      for (int i=0;i<8;i++) wv[i]=At[ty*8+i][kk];
      #pragma unroll
      for (int i=0;i<8;i++)
        #pragma unroll
        for (int j=0;j<8;j++) acc[i][j] += wv[i]*xv[j];
    }
    __syncthreads();
  }
  for (int i=0;i<8;i++){
    size_t r = r0 + ty*8 + i;
    for (int j=0;j<8;j++){
      int c = c0 + tx*8 + j;
      O[r*C + c] = acc[i][j] + bias[c];
    }
  }
}

// out = [relu]( feat[:, :OC] + max_n( relu(dirs . ndir_col) * feat[nb, OC: ] ) )
__global__ void k_comb(const float* __restrict__ feat, const int* __restrict__ idx,
                       const float* __restrict__ dirs, const float* __restrict__ dw,
                       float* __restrict__ outp, int V, int OC, int relu_flag){
  int id = blockIdx.x*256 + threadIdx.x;
  if (id >= BB*V*OC) return;
  int oc = id % OC, v = (id/OC) % V, b = id/(OC*V);
  float wx=dw[oc], wy=dw[OC+oc], wz=dw[2*OC+oc];
  float s = 1.f/fmaxf(sqrtf(wx*wx+wy*wy+wz*wz), 1e-12f);
  wx*=s; wy*=s; wz*=s;
  size_t row = (size_t)b*V + v;
  const int* ir = idx + row*20;
  const float* dd = dirs + row*60;
  float center = feat[row*2*OC + oc];
  float m = -INFINITY;
  for (int n=0;n<20;n++){
    int nb = ir[n];
    float th = dd[n*3]*wx + dd[n*3+1]*wy + dd[n*3+2]*wz;
    th = fmaxf(th, 0.f);
    float sup = feat[((size_t)b*V + nb)*2*OC + OC + oc];
    m = fmaxf(m, th*sup);
  }
  float rv = center + m;
  outp[row*OC + oc] = relu_flag ? fmaxf(rv, 0.f) : rv;
}

__global__ void k_pool(const float* __restrict__ fm, const int* __restrict__ idx4,
                       float* __restrict__ outp, int V, int C, int numS){
  int id = blockIdx.x*256 + threadIdx.x;
  if (id >= BB*numS*C) return;
  int c = id % C, sI = (id/C) % numS, b = id/(C*numS);
  const int* ir = idx4 + ((size_t)b*numS + sI)*4;
  float m = -INFINITY;
  for (int n=0;n<4;n++) m = fmaxf(m, fm[((size_t)b*V + ir[n])*C + c]);
  outp[((size_t)b*numS + sI)*C + c] = m;
}

__global__ void k_vgather(const float* __restrict__ vin, const int* __restrict__ perm,
                          float* __restrict__ vout, int V, int numS){
  int id = blockIdx.x*256 + threadIdx.x;
  if (id >= BB*numS*3) return;
  int c = id % 3, sI = (id/3) % numS, b = id/(3*numS);
  vout[id] = vin[((size_t)b*V + perm[sI])*3 + c];
}

__global__ void k_colmax(const float* __restrict__ x, float* __restrict__ o, int Vr, int C){
  int id = blockIdx.x*256 + threadIdx.x;
  if (id >= BB*C) return;
  int c = id % C, b = id / C;
  float m = -INFINITY;
  for (int v=0; v<Vr; v++) m = fmaxf(m, x[(size_t)(b*Vr+v)*C + c]);
  o[id] = m;
}

/* ---------------- FC head ---------------- */

__global__ void k_emb(const float* __restrict__ xmax, const float* __restrict__ fg,
                      const float* __restrict__ fcw, const float* __restrict__ fcb,
                      float* __restrict__ outp){
  int id = blockIdx.x*256 + threadIdx.x;
  if (id >= BB*512) return;
  int e = id % 512, b = id / 512;
  const float* wr = fcw + (size_t)e*2048;
  const float* xb = xmax + b*1024;
  const float* gb = fg + b*1024;
  float acc = fcb[e];
  for (int k=0;k<1024;k++) acc += xb[k]*wr[k];
  for (int k=0;k<1024;k++) acc += gb[k]*wr[1024+k];
  outp[id] = acc;
}

__global__ void k_h(const float* __restrict__ xmax, const float* __restrict__ fg,
                    const float* __restrict__ clw1, const float* __restrict__ clb1,
                    const float* __restrict__ gamma, const float* __restrict__ beta,
                    float* __restrict__ h){
  int id = blockIdx.x*256 + threadIdx.x;
  if (id >= BB*512) return;
  int j = id % 512, b = id / 512;
  const float* wr = clw1 + (size_t)j*2048;
  const float* xb = xmax + b*1024;
  const float* gb = fg + b*1024;
  float acc = clb1[j];
  for (int k=0;k<1024;k++) acc += xb[k]*wr[k];
  for (int k=0;k<1024;k++) acc += gb[k]*wr[1024+k];
  const float inv_s = 1.0f / sqrtf(1.0f + 1e-5f);
  float v = acc * inv_s * gamma[j] + beta[j];
  h[id] = fmaxf(v, 0.f);
}

__global__ void k_pred(const float* __restrict__ h, const float* __restrict__ clw2,
                       const float* __restrict__ clb2, float* __restrict__ outp){
  int id = threadIdx.x;
  if (id >= BB*6) return;
  int o = id % 6, b = id / 6;
  float acc = clb2[o];
  const float* hb = h + b*512;
  const float* wr = clw2 + o*512;
  for (int j=0;j<512;j++) acc += hb[j]*wr[j];
  outp[BB*512 + id] = acc;
}

/* ---------------- launch ---------------- */

static inline int cdiv(long long a, int b){ return (int)((a + b - 1)/b); }

extern "C" void kernel_launch(void* const* d_in, const int* in_sizes, int n_in,
                              void* d_out, int out_size, void* d_ws, size_t ws_size,
                              hipStream_t stream){
  float* out = (float*)d_out;
  if (n_in != 30 || in_sizes[0] != BB*3*NN || out_size != BB*512 + BB*6){
    k_sentinel<<<cdiv(out_size,256),256,0,stream>>>(out, out_size, 2000.0f);
    return;
  }
  const float* xyz  = (const float*)d_in[0];
  const float* w1   = (const float*)d_in[1];
  const float* b1   = (const float*)d_in[2];
  const float* w2   = (const float*)d_in[3];
  const float* b2   = (const float*)d_in[4];
  const float* w3   = (const float*)d_in[5];
  const float* b3   = (const float*)d_in[6];
  const float* w4   = (const float*)d_in[7];
  const float* b4   = (const float*)d_in[8];
  const float* fcw  = (const float*)d_in[9];
  const float* fcb  = (const float*)d_in[10];
  const float* dir0 = (const float*)d_in[11];
  const float* wc1  = (const float*)d_in[12];
  const float* bc1  = (const float*)d_in[13];
  const float* dir1 = (const float*)d_in[14];
  const float* wc2  = (const float*)d_in[15];
  const float* bc2  = (const float*)d_in[16];
  const float* dir2 = (const float*)d_in[17];
  const float* wc3  = (const float*)d_in[18];
  const float* bc3  = (const float*)d_in[19];
  const float* dir3 = (const float*)d_in[20];
  const float* wc4  = (const float*)d_in[21];
  const float* bc4  = (const float*)d_in[22];
  const float* dir4 = (const float*)d_in[23];
  const float* clw1 = (const float*)d_in[24];
  const float* clb1 = (const float*)d_in[25];
  const float* gma  = (const float*)d_in[26];
  const float* bta  = (const float*)d_in[27];
  const float* clw2 = (const float*)d_in[28];
  const float* clb2 = (const float*)d_in[29];

  char* w = (char*)d_ws;
  size_t off = 0;
  auto A = [&](size_t bytes){ size_t r = off; off += (bytes + 255) & ~(size_t)255; return r; };
  const size_t oXMAX = A((size_t)BB*1024*4);
  const size_t oFG   = A((size_t)BB*1024*4);
  const size_t oGF   = A((size_t)BB*128*4);
  const size_t oH    = A((size_t)BB*512*4);
  const size_t oP2048= A(2048*4);
  const size_t oP512 = A(512*4);
  const size_t oPMAX = A((size_t)BB*1024*16*4);
  const size_t oV0   = A((size_t)BB*2048*3*4);
  const size_t oV1   = A((size_t)BB*512*3*4);
  const size_t oV2   = A((size_t)BB*128*3*4);
  const size_t oIDX0 = A((size_t)BB*2048*20*4);
  const size_t oDIR0 = A((size_t)BB*2048*20*3*4);
  const size_t oFM0  = A((size_t)BB*2048*32*4);
  const size_t oFM1  = A((size_t)BB*2048*64*4);
  const size_t oI40  = A((size_t)BB*512*4*4);
  const size_t oFM1P = A((size_t)BB*512*64*4);
  const size_t oIDX1 = A((size_t)BB*512*20*4);
  const size_t oDIR1 = A((size_t)BB*512*20*3*4);
  const size_t oFM2  = A((size_t)BB*512*128*4);
  const size_t oFM3  = A((size_t)BB*512*256*4);
  const size_t oI41  = A((size_t)BB*128*4*4);
  const size_t oFM3P = A((size_t)BB*128*256*4);
  const size_t oIDX2 = A((size_t)BB*128*20*4);
  const size_t oDIR2 = A((size_t)BB*128*20*3*4);
  const size_t oFM4  = A((size_t)BB*128*1024*4);
  const size_t oBIGA = A((size_t)BB*256*NN*4);   // x1, then x3
  const size_t oBIGB = A((size_t)BB*128*NN*4);   // x2, then feat1..feat4
  if (off > ws_size){
    k_sentinel<<<cdiv(out_size,256),256,0,stream>>>(out, out_size, 1000.0f);
    return;
  }
  float* xmax = (float*)(w+oXMAX); float* fg = (float*)(w+oFG);
  float* gf = (float*)(w+oGF);     float* hbuf = (float*)(w+oH);
  int* p2048 = (int*)(w+oP2048);   int* p512 = (int*)(w+oP512);
  float* pmax = (float*)(w+oPMAX);
  float* v0 = (float*)(w+oV0); float* v1 = (float*)(w+oV1); float* v2 = (float*)(w+oV2);
  int* idx0 = (int*)(w+oIDX0); int* idx1 = (int*)(w+oIDX1); int* idx2 = (int*)(w+oIDX2);
  int* i40 = (int*)(w+oI40);   int* i41 = (int*)(w+oI41);
  float* d0 = (float*)(w+oDIR0); float* d1 = (float*)(w+oDIR1); float* d2 = (float*)(w+oDIR2);
  float* fm0 = (float*)(w+oFM0); float* fm1 = (float*)(w+oFM1); float* fm1p = (float*)(w+oFM1P);
  float* fm2 = (float*)(w+oFM2); float* fm3 = (float*)(w+oFM3); float* fm3p = (float*)(w+oFM3P);
  float* fm4 = (float*)(w+oFM4);
  float* x1 = (float*)(w+oBIGA); float* x3 = (float*)(w+oBIGA);
  float* x2 = (float*)(w+oBIGB); float* feat = (float*)(w+oBIGB);

  // MLP branch
  k_mlp1<<<cdiv((long long)BB*64*NN,256),256,0,stream>>>(xyz, w1, b1, x1);
  k_mlp2<<<cdiv((long long)BB*128*NN,256),256,0,stream>>>(x1, w2, b2, x2);
  k_rowmax<<<BB*128,256,0,stream>>>(x2, gf, NN);
  k_mlp3<<<dim3(16,2,BB),256,0,stream>>>(x2, gf, w3, b3, x3);
  k_mlp4max<<<dim3(16,8,BB),256,0,stream>>>(x3, w4, b4, pmax);
  k_xmax<<<cdiv(BB*1024,256),256,0,stream>>>(pmax, xmax);

  // graph branch: stage 0 (V=2048)
  k_transpose<<<cdiv((long long)BB*NN*3,256),256,0,stream>>>(xyz, v0);
  k_perm<<<1,1024,0,stream>>>(2048, 2, 0u, 1u, p2048, PRNG_MODE);  // jax.random.key(1)
  k_perm<<<1,1024,0,stream>>>(512,  1, 0u, 2u, p512,  PRNG_MODE);  // jax.random.key(2)
  k_knn_w<32,20><<<dim3(512,BB),256,0,stream>>>(v0, nullptr, 2048, idx0);
  k_dirs<<<cdiv((long long)BB*2048*20,256),256,0,stream>>>(v0, 2048, idx0, d0, BB*2048*20);
  k_surf<<<cdiv((long long)BB*2048*32,256),256,0,stream>>>(d0, dir0, fm0, 2048);
  k_gemm<<<dim3(1,256),256,0,stream>>>(fm0, wc1, bc1, feat, BB*2048, 32, 128);
  k_comb<<<cdiv((long long)BB*2048*64,256),256,0,stream>>>(feat, idx0, d0, dir1, fm1, 2048, 64, 1);
  // pool 1
  k_knn_w<32,4><<<dim3(128,BB),256,0,stream>>>(v0, p2048, 512, i40);
  k_pool<<<cdiv((long long)BB*512*64,256),256,0,stream>>>(fm1, i40, fm1p, 2048, 64, 512);
  k_vgather<<<cdiv((long long)BB*512*3,256),256,0,stream>>>(v0, p2048, v1, 2048, 512);
  // stage 1 (V=512)
  k_knn_w<8,20><<<dim3(128,BB),256,0,stream>>>(v1, nullptr, 512, idx1);
  k_dirs<<<cdiv((long long)BB*512*20,256),256,0,stream>>>(v1, 512, idx1, d1, BB*512*20);
  k_gemm<<<dim3(2,64),256,0,stream>>>(fm1p, wc2, bc2, feat, BB*512, 64, 256);
  k_comb<<<cdiv((long long)BB*512*128,256),256,0,stream>>>(feat, idx1, d1, dir2, fm2, 512, 128, 1);
  k_gemm<<<dim3(4,64),256,0,stream>>>(fm2, wc3, bc3, feat, BB*512, 128, 512);
  k_comb<<<cdiv((long long)BB*512*256,256),256,0,stream>>>(feat, idx1, d1, dir3, fm3, 512, 256, 1);
  // pool 2
  k_knn_w<8,4><<<dim3(32,BB),256,0,stream>>>(v1, p512, 128, i41);
  k_pool<<<cdiv((long long)BB*128*256,256),256,0,stream>>>(fm3, i41, fm3p, 512, 256, 128);
  k_vgather<<<cdiv((long long)BB*128*3,256),256,0,stream>>>(v1, p512, v2, 512, 128);
  // stage 2 (V=128)
  k_knn_w<2,20><<<dim3(32,BB),256,0,stream>>>(v2, nullptr, 128, idx2);
  k_dirs<<<cdiv((long long)BB*128*20,256),256,0,stream>>>(v2, 128, idx2, d2, BB*128*20);
  k_gemm<<<dim3(16,16),256,0,stream>>>(fm3p, wc4, bc4, feat, BB*128, 256, 2048);
  k_comb<<<cdiv((long long)BB*128*1024,256),256,0,stream>>>(feat, idx2, d2, dir4, fm4, 128, 1024, 0);
  k_colmax<<<cdiv(BB*1024,256),256,0,stream>>>(fm4, fg, 128, 1024);

  // FC head
  k_emb<<<cdiv(BB*512,256),256,0,stream>>>(xmax, fg, fcw, fcb, out);
  k_h<<<cdiv(BB*512,256),256,0,stream>>>(xmax, fg, clw1, clb1, gma, bta, hbuf);
  k_pred<<<1,128,0,stream>>>(hbuf, clw2, clb2, out);
}

// Round 4
// 1320.580 us; speedup vs baseline: 1.8655x; 1.5915x over previous
//
#include <hip/hip_runtime.h>
#include <hip/hip_bf16.h>
#include <math.h>

#define BB 16
#define NN 2048

__global__ void k_sentinel(float* o, int n, float v){
  int i = blockIdx.x*256 + threadIdx.x;
  if (i < n) o[i] = v;
}

/* ---------------- MLP branch ---------------- */

__global__ void k_mlp1(const float* __restrict__ xyz, const float* __restrict__ w1,
                       const float* __restrict__ b1, float* __restrict__ x1){
  int id = blockIdx.x*256 + threadIdx.x;
  if (id >= BB*64*NN) return;
  int n = id & (NN-1), o = (id>>11) & 63, b = id>>17;
  float acc = b1[o];
  #pragma unroll
  for (int c=0;c<3;c++)
    acc += w1[o*3+c] * xyz[(size_t)(b*3+c)*NN + n];
  x1[id] = fmaxf(acc, 0.f);
}

__global__ void k_mlp2(const float* __restrict__ x1, const float* __restrict__ w2,
                       const float* __restrict__ bias, float* __restrict__ x2){
  int id = blockIdx.x*256 + threadIdx.x;
  if (id >= BB*128*NN) return;
  int n = id & (NN-1), o = (id>>11) & 127, b = id>>18;
  float acc = bias[o];
  const float* xr = x1 + (size_t)b*64*NN + n;
  const float* wr = w2 + o*64;
  for (int c=0;c<64;c++) acc += wr[c] * xr[(size_t)c*NN];
  x2[id] = fmaxf(acc, 0.f);
}

__global__ __launch_bounds__(256) void k_rowmax(const float* __restrict__ x, float* __restrict__ o, int cols){
  __shared__ float sm[256];
  int row = blockIdx.x, t = threadIdx.x;
  const float* xr = x + (size_t)row*cols;
  float m = -INFINITY;
  for (int c=t;c<cols;c+=256) m = fmaxf(m, xr[c]);
  sm[t]=m; __syncthreads();
  for (int s=128;s>0;s>>=1){ if (t<s) sm[t]=fmaxf(sm[t], sm[t+s]); __syncthreads(); }
  if (!t) o[row]=sm[0];
}

// x3 = relu(W3 @ [x2; gf_broadcast] + b3), tiled 128x128, K=256 in chunks of 32
__global__ __launch_bounds__(256) void k_mlp3(const float* __restrict__ x2, const float* __restrict__ gf,
                                              const float* __restrict__ w3, const float* __restrict__ b3,
                                              float* __restrict__ x3){
  __shared__ float Wt[128][33];
  __shared__ float Xt[32][128];
  int nt = blockIdx.x, ot = blockIdx.y, b = blockIdx.z;
  int t = threadIdx.x, tx = t & 15, ty = t >> 4;
  int o0 = ot*128, n0 = nt*128;
  float acc[8][8];
  #pragma unroll
  for (int i=0;i<8;i++) for (int j=0;j<8;j++) acc[i][j]=0.f;
  for (int k0=0;k0<256;k0+=32){
    for (int i=t;i<128*32;i+=256){ int oo=i>>5, kk=i&31; Wt[oo][kk]=w3[(o0+oo)*256+k0+kk]; }
    for (int i=t;i<32*128;i+=256){ int kk=i>>7, nn=i&127; int c=k0+kk;
      Xt[kk][nn] = (c<128) ? x2[(size_t)(b*128+c)*NN + n0+nn] : gf[b*128 + (c-128)];
    }
    __syncthreads();
    for (int kk=0;kk<32;kk++){
      float xv[8], wv[8];
      #pragma unroll
      for (int j=0;j<8;j++) xv[j]=Xt[kk][tx*8+j];
      #pragma unroll
      for (int i=0;i<8;i++) wv[i]=Wt[ty*8+i][kk];
      #pragma unroll
      for (int i=0;i<8;i++)
        #pragma unroll
        for (int j=0;j<8;j++) acc[i][j] += wv[i]*xv[j];
    }
    __syncthreads();
  }
  for (int i=0;i<8;i++){
    int o = o0 + ty*8 + i;
    float bi = b3[o];
    for (int j=0;j<8;j++)
      x3[(size_t)(b*256+o)*NN + n0 + tx*8 + j] = fmaxf(acc[i][j]+bi, 0.f);
  }
}

// pmax[b,o,nt] = max over this n-tile of relu(W4 @ x3 + b4)
__global__ __launch_bounds__(256) void k_mlp4max(const float* __restrict__ x3, const float* __restrict__ w4,
                                                 const float* __restrict__ b4, float* __restrict__ pmax){
  __shared__ float Wt[128][33];
  __shared__ float Xt[32][128];
  __shared__ float red[16][8][17];
  int nt = blockIdx.x, ot = blockIdx.y, b = blockIdx.z;
  int t = threadIdx.x, tx = t & 15, ty = t >> 4;
  int o0 = ot*128, n0 = nt*128;
  float acc[8][8];
  #pragma unroll
  for (int i=0;i<8;i++) for (int j=0;j<8;j++) acc[i][j]=0.f;
  for (int k0=0;k0<256;k0+=32){
    for (int i=t;i<128*32;i+=256){ int oo=i>>5, kk=i&31; Wt[oo][kk]=w4[(o0+oo)*256+k0+kk]; }
    for (int i=t;i<32*128;i+=256){ int kk=i>>7, nn=i&127; Xt[kk][nn]=x3[(size_t)(b*256+k0+kk)*NN + n0+nn]; }
    __syncthreads();
    for (int kk=0;kk<32;kk++){
      float xv[8], wv[8];
      #pragma unroll
      for (int j=0;j<8;j++) xv[j]=Xt[kk][tx*8+j];
      #pragma unroll
      for (int i=0;i<8;i++) wv[i]=Wt[ty*8+i][kk];
      #pragma unroll
      for (int i=0;i<8;i++)
        #pragma unroll
        for (int j=0;j<8;j++) acc[i][j] += wv[i]*xv[j];
    }
    __syncthreads();
  }
  for (int i=0;i<8;i++){
    float bi = b4[o0+ty*8+i];
    float m = 0.f;
    for (int j=0;j<8;j++) m = fmaxf(m, fmaxf(acc[i][j]+bi, 0.f));
    red[ty][i][tx] = m;
  }
  __syncthreads();
  if (t < 128){
    int ty2 = t>>3, i2 = t&7;
    float m = red[ty2][i2][0];
    for (int x=1;x<16;x++) m = fmaxf(m, red[ty2][i2][x]);
    pmax[(size_t)(b*1024 + o0 + ty2*8 + i2)*16 + nt] = m;
  }
}

__global__ void k_xmax(const float* __restrict__ pmax, float* __restrict__ xmax){
  int id = blockIdx.x*256 + threadIdx.x;
  if (id >= BB*1024) return;
  float m = pmax[(size_t)id*16];
  for (int k=1;k<16;k++) m = fmaxf(m, pmax[(size_t)id*16+k]);
  xmax[id] = m;
}

/* ---------------- JAX threefry PRNG permutation ---------------- */

#define TF2BODY \
  unsigned ks2 = 0x1BD11BDAu ^ k0 ^ k1; \
  unsigned a = x0 + k0, b = x1 + k1; \
  { \
  a += b; b = (b<<13)|(b>>19); b ^= a; \
  a += b; b = (b<<15)|(b>>17); b ^= a; \
  a += b; b = (b<<26)|(b>>6);  b ^= a; \
  a += b; b = (b<<6) |(b>>26); b ^= a;  a += k1;  b += ks2 + 1u; \
  a += b; b = (b<<17)|(b>>15); b ^= a; \
  a += b; b = (b<<29)|(b>>3);  b ^= a; \
  a += b; b = (b<<16)|(b>>16); b ^= a; \
  a += b; b = (b<<24)|(b>>8);  b ^= a;  a += ks2; b += k0  + 2u; \
  a += b; b = (b<<13)|(b>>19); b ^= a; \
  a += b; b = (b<<15)|(b>>17); b ^= a; \
  a += b; b = (b<<26)|(b>>6);  b ^= a; \
  a += b; b = (b<<6) |(b>>26); b ^= a;  a += k0;  b += k1  + 3u; \
  a += b; b = (b<<17)|(b>>15); b ^= a; \
  a += b; b = (b<<29)|(b>>3);  b ^= a; \
  a += b; b = (b<<16)|(b>>16); b ^= a; \
  a += b; b = (b<<24)|(b>>8);  b ^= a;  a += k1;  b += ks2 + 4u; \
  a += b; b = (b<<13)|(b>>19); b ^= a; \
  a += b; b = (b<<15)|(b>>17); b ^= a; \
  a += b; b = (b<<26)|(b>>6);  b ^= a; \
  a += b; b = (b<<6) |(b>>26); b ^= a;  a += ks2; b += k0  + 5u; \
  } \
  o0 = a; o1 = b;

__device__ __forceinline__ void tf2(unsigned k0, unsigned k1, unsigned x0, unsigned x1,
                                    unsigned &o0, unsigned &o1){ TF2BODY }
static void tf2h(unsigned k0, unsigned k1, unsigned x0, unsigned x1,
                 unsigned &o0, unsigned &o1){ TF2BODY }

__global__ void k_permkeys(int n, unsigned sk0, unsigned sk1, unsigned* __restrict__ keys){
  int i = blockIdx.x*256 + threadIdx.x;
  if (i < n){ unsigned a,b2; tf2(sk0, sk1, 0u, (unsigned)i, a, b2); keys[i] = a ^ b2; }
}

// stable ascending rank-scatter: out[rank_i] = (vin ? vin[i] : i)
__global__ void k_permrank(int n, const unsigned* __restrict__ keys,
                           const int* __restrict__ vin, int* __restrict__ vout){
  int i = blockIdx.x*256 + threadIdx.x;
  if (i >= n) return;
  unsigned ki = keys[i];
  int rank = 0;
  for (int j=0;j<n;j++){
    unsigned kj = keys[j];
    rank += (kj < ki) || (kj == ki && j < i);
  }
  vout[rank] = vin ? vin[i] : i;
}

/* ---------------- graph branch ---------------- */

__global__ void k_transpose(const float* __restrict__ xyz, float* __restrict__ verts){
  int id = blockIdx.x*256 + threadIdx.x;
  if (id >= BB*NN*3) return;
  int c = id % 3, v = (id/3) % NN, b = id/(3*NN);
  verts[id] = xyz[(size_t)(b*3+c)*NN + v];
}

// Wave-per-query KNN, no LDS/barriers. verts in batch-component-SoA [b][3][V]
// (xyz input layout). Packed u64 key = (monotone f32 dist << 32) | idx exactly
// reproduces XLA stable top-k (d asc, then idx asc). Lexicographic successor
// selection: round r takes min over keys > last.
template<int CPL, int KSEL>
__global__ __launch_bounds__(256) void k_knn_wq(const float* __restrict__ vbcs,
                                                const int* __restrict__ qmap, int numQ,
                                                int* __restrict__ out){
  constexpr int V = CPL*64;
  int t = threadIdx.x, wid = t>>6, lane = t&63;
  int b = blockIdx.y;
  int q = blockIdx.x*4 + wid;
  if (q >= numQ) return;
  const float* vx = vbcs + (size_t)b*3*V;
  const float* vy = vx + V;
  const float* vz = vy + V;
  int qv = qmap ? qmap[q] : q;
  float qx = vx[qv], qy = vy[qv], qz = vz[qv];
  float qq = qx*qx + qy*qy + qz*qz;
  unsigned long long key[CPL];
  #pragma unroll
  for (int i=0;i<CPL;i++){
    int c = lane + i*64;
    float wx=vx[c], wy=vy[c], wz=vz[c];
    float inner = qx*wx + qy*wy + qz*wz;
    float ww = wx*wx + wy*wy + wz*wz;
    float d = qq - 2.f*inner + ww;
    unsigned db = __float_as_uint(d);
    db = (db & 0x80000000u) ? ~db : (db | 0x80000000u);
    key[i] = ((unsigned long long)db << 32) | (unsigned)c;
  }
  int* orow = out + ((size_t)b*numQ + q)*KSEL;
  unsigned long long last = 0ull;
  for (int r=0; r<=KSEL; r++){
    unsigned long long best = ~0ull;
    #pragma unroll
    for (int i=0;i<CPL;i+=2){
      unsigned long long a  = (key[i]   > last) ? key[i]   : ~0ull;
      unsigned long long b2 = (key[i+1] > last) ? key[i+1] : ~0ull;
      a = (b2 < a) ? b2 : a;
      best = (a < best) ? a : best;
    }
    #pragma unroll
    for (int off=32; off>0; off>>=1){
      unsigned long long o = __shfl_xor(best, off, 64);
      best = (o < best) ? o : best;
    }
    if (r>0 && lane==0) orow[r-1] = (int)(best & 0xffffffffull);
    last = best;
  }
}

__global__ void k_dirs(const float* __restrict__ verts, int V, const int* __restrict__ idx,
                       float* __restrict__ dirs, int total){
  int id = blockIdx.x*256 + threadIdx.x;
  if (id >= total) return;
  int v = (id/20) % V, b = id/(20*V);
  const float* vb = verts + (size_t)b*V*3;
  int nb = idx[id];
  float dx = vb[nb*3+0]-vb[v*3+0];
  float dy = vb[nb*3+1]-vb[v*3+1];
  float dz = vb[nb*3+2]-vb[v*3+2];
  float s = 1.f / fmaxf(sqrtf(dx*dx+dy*dy+dz*dz), 1e-12f);
  dirs[(size_t)id*3+0]=dx*s; dirs[(size_t)id*3+1]=dy*s; dirs[(size_t)id*3+2]=dz*s;
}

__global__ void k_surf(const float* __restrict__ dirs, const float* __restrict__ dir0,
                       float* __restrict__ fm0, int V){
  int id = blockIdx.x*256 + threadIdx.x;
  if (id >= BB*V*32) return;
  int k = id & 31; int vv = (id>>5) % V; int b = id/(32*V);
  float nx=dir0[k], ny=dir0[32+k], nz=dir0[64+k];
  float s = 1.f/fmaxf(sqrtf(nx*nx+ny*ny+nz*nz), 1e-12f);
  nx*=s; ny*=s; nz*=s;
  const float* dd = dirs + (size_t)(b*V+vv)*60;
  float m = 0.f;
  for (int n=0;n<20;n++){
    float th = dd[n*3]*nx + dd[n*3+1]*ny + dd[n*3+2]*nz;
    m = fmaxf(m, fmaxf(th, 0.f));
  }
  fm0[(size_t)(b*V+vv)*32 + k] = m;
}

// O = A @ B + bias; A (R,K) rm, B (K,C) rm. Tiles 128x128, K-chunk 32.
__global__ __launch_bounds__(256) void k_gemm(const float* __restrict__ A, const float* __restrict__ Bm,
                                              const float* __restrict__ bias, float* __restrict__ O,
                                              int R, int K, int C){
  __shared__ float At[128][33];
  __shared__ float Bt[32][128];
  int ct = blockIdx.x, rt = blockIdx.y;
  int t = threadIdx.x, tx = t & 15, ty = t >> 4;
  int r0 = rt*128, c0 = ct*128;
  float acc[8][8];
  #pragma unroll
  for (int i=0;i<8;i++) for (int j=0;j<8;j++) acc[i][j]=0.f;
  for (int k0=0;k0<K;k0+=32){
    for (int i=t;i<128*32;i+=256){ int rr=i>>5, kk=i&31; At[rr][kk]=A[(size_t)(r0+rr)*K + k0+kk]; }
    for (int i=t;i<32*128;i+=256){ int kk=i>>7, cc=i&127; Bt[kk][cc]=Bm[(size_t)(k0+kk)*C + c0+cc]; }
    __syncthreads();
    for (int kk=0;kk<32;kk++){
      float xv[8], wv[8];
      #pragma unroll
      for (int j=0;j<8;j++) xv[j]=Bt[kk][tx*8+j];
      #pragma unroll
      for (int i=0;i<8;i++) wv[i]=At[ty*8+i][kk];
      #pragma unroll
      for (int i=0;i<8;i++)
        #pragma unroll
        for (int j=0;j<8;j++) acc[i][j] += wv[i]*xv[j];
    }
    __syncthreads();
  }
  for (int i=0;i<8;i++){
    size_t r = r0 + ty*8 + i;
    for (int j=0;j<8;j++){
      int c = c0 + tx*8 + j;
      O[r*C + c] = acc[i][j] + bias[c];
    }
  }
}

// out = [relu]( feat[:, :OC] + max_n( relu(dirs . ndir_col) * feat[nb, OC: ] ) )
__global__ void k_comb(const float* __restrict__ feat, const int* __restrict__ idx,
                       const float* __restrict__ dirs, const float* __restrict__ dw,
                       float* __restrict__ outp, int V, int OC, int relu_flag){
  int id = blockIdx.x*256 + threadIdx.x;
  if (id >= BB*V*OC) return;
  int oc = id % OC, v = (id/OC) % V, b = id/(OC*V);
  float wx=dw[oc], wy=dw[OC+oc], wz=dw[2*OC+oc];
  float s = 1.f/fmaxf(sqrtf(wx*wx+wy*wy+wz*wz), 1e-12f);
  wx*=s; wy*=s; wz*=s;
  size_t row = (size_t)b*V + v;
  const int* ir = idx + row*20;
  const float* dd = dirs + row*60;
  float center = feat[row*2*OC + oc];
  float m = -INFINITY;
  for (int n=0;n<20;n++){
    int nb = ir[n];
    float th = dd[n*3]*wx + dd[n*3+1]*wy + dd[n*3+2]*wz;
    th = fmaxf(th, 0.f);
    float sup = feat[((size_t)b*V + nb)*2*OC + OC + oc];
    m = fmaxf(m, th*sup);
  }
  float rv = center + m;
  outp[row*OC + oc] = relu_flag ? fmaxf(rv, 0.f) : rv;
}

__global__ void k_pool(const float* __restrict__ fm, const int* __restrict__ idx4,
                       float* __restrict__ outp, int V, int C, int numS){
  int id = blockIdx.x*256 + threadIdx.x;
  if (id >= BB*numS*C) return;
  int c = id % C, sI = (id/C) % numS, b = id/(C*numS);
  const int* ir = idx4 + ((size_t)b*numS + sI)*4;
  float m = -INFINITY;
  for (int n=0;n<4;n++) m = fmaxf(m, fm[((size_t)b*V + ir[n])*C + c]);
  outp[((size_t)b*numS + sI)*C + c] = m;
}

// gathers pooled verts; writes AOS (for k_dirs) and batch-component-SoA (for knn)
__global__ void k_vgather(const float* __restrict__ vin, const int* __restrict__ perm,
                          float* __restrict__ vout, float* __restrict__ vbcs,
                          int V, int numS){
  int id = blockIdx.x*256 + threadIdx.x;
  if (id >= BB*numS*3) return;
  int c = id % 3, sI = (id/3) % numS, b = id/(3*numS);
  float val = vin[((size_t)b*V + perm[sI])*3 + c];
  vout[id] = val;
  vbcs[((size_t)b*3 + c)*numS + sI] = val;
}

__global__ void k_colmax(const float* __restrict__ x, float* __restrict__ o, int Vr, int C){
  int id = blockIdx.x*256 + threadIdx.x;
  if (id >= BB*C) return;
  int c = id % C, b = id / C;
  float m = -INFINITY;
  for (int v=0; v<Vr; v++) m = fmaxf(m, x[(size_t)(b*Vr+v)*C + c]);
  o[id] = m;
}

/* ---------------- FC head ---------------- */

__global__ void k_emb(const float* __restrict__ xmax, const float* __restrict__ fg,
                      const float* __restrict__ fcw, const float* __restrict__ fcb,
                      float* __restrict__ outp){
  int id = blockIdx.x*256 + threadIdx.x;
  if (id >= BB*512) return;
  int e = id % 512, b = id / 512;
  const float* wr = fcw + (size_t)e*2048;
  const float* xb = xmax + b*1024;
  const float* gb = fg + b*1024;
  float acc = fcb[e];
  for (int k=0;k<1024;k++) acc += xb[k]*wr[k];
  for (int k=0;k<1024;k++) acc += gb[k]*wr[1024+k];
  outp[id] = acc;
}

__global__ void k_h(const float* __restrict__ xmax, const float* __restrict__ fg,
                    const float* __restrict__ clw1, const float* __restrict__ clb1,
                    const float* __restrict__ gamma, const float* __restrict__ beta,
                    float* __restrict__ h){
  int id = blockIdx.x*256 + threadIdx.x;
  if (id >= BB*512) return;
  int j = id % 512, b = id / 512;
  const float* wr = clw1 + (size_t)j*2048;
  const float* xb = xmax + b*1024;
  const float* gb = fg + b*1024;
  float acc = clb1[j];
  for (int k=0;k<1024;k++) acc += xb[k]*wr[k];
  for (int k=0;k<1024;k++) acc += gb[k]*wr[1024+k];
  const float inv_s = 1.0f / sqrtf(1.0f + 1e-5f);
  float v = acc * inv_s * gamma[j] + beta[j];
  h[id] = fmaxf(v, 0.f);
}

__global__ void k_pred(const float* __restrict__ h, const float* __restrict__ clw2,
                       const float* __restrict__ clb2, float* __restrict__ outp){
  int id = threadIdx.x;
  if (id >= BB*6) return;
  int o = id % 6, b = id / 6;
  float acc = clb2[o];
  const float* hb = h + b*512;
  const float* wr = clw2 + o*512;
  for (int j=0;j<512;j++) acc += hb[j]*wr[j];
  outp[BB*512 + id] = acc;
}

/* ---------------- launch ---------------- */

static inline int cdiv(long long a, int b){ return (int)((a + b - 1)/b); }

extern "C" void kernel_launch(void* const* d_in, const int* in_sizes, int n_in,
                              void* d_out, int out_size, void* d_ws, size_t ws_size,
                              hipStream_t stream){
  float* out = (float*)d_out;
  if (n_in != 30 || in_sizes[0] != BB*3*NN || out_size != BB*512 + BB*6){
    k_sentinel<<<cdiv(out_size,256),256,0,stream>>>(out, out_size, 2000.0f);
    return;
  }
  const float* xyz  = (const float*)d_in[0];
  const float* w1   = (const float*)d_in[1];
  const float* b1   = (const float*)d_in[2];
  const float* w2   = (const float*)d_in[3];
  const float* b2   = (const float*)d_in[4];
  const float* w3   = (const float*)d_in[5];
  const float* b3   = (const float*)d_in[6];
  const float* w4   = (const float*)d_in[7];
  const float* b4   = (const float*)d_in[8];
  const float* fcw  = (const float*)d_in[9];
  const float* fcb  = (const float*)d_in[10];
  const float* dir0 = (const float*)d_in[11];
  const float* wc1  = (const float*)d_in[12];
  const float* bc1  = (const float*)d_in[13];
  const float* dir1 = (const float*)d_in[14];
  const float* wc2  = (const float*)d_in[15];
  const float* bc2  = (const float*)d_in[16];
  const float* dir2 = (const float*)d_in[17];
  const float* wc3  = (const float*)d_in[18];
  const float* bc3  = (const float*)d_in[19];
  const float* dir3 = (const float*)d_in[20];
  const float* wc4  = (const float*)d_in[21];
  const float* bc4  = (const float*)d_in[22];
  const float* dir4 = (const float*)d_in[23];
  const float* clw1 = (const float*)d_in[24];
  const float* clb1 = (const float*)d_in[25];
  const float* gma  = (const float*)d_in[26];
  const float* bta  = (const float*)d_in[27];
  const float* clw2 = (const float*)d_in[28];
  const float* clb2 = (const float*)d_in[29];

  char* w = (char*)d_ws;
  size_t off = 0;
  auto A = [&](size_t bytes){ size_t r = off; off += (bytes + 255) & ~(size_t)255; return r; };
  const size_t oXMAX = A((size_t)BB*1024*4);
  const size_t oFG   = A((size_t)BB*1024*4);
  const size_t oGF   = A((size_t)BB*128*4);
  const size_t oH    = A((size_t)BB*512*4);
  const size_t oP2048= A(2048*4);
  const size_t oP512 = A(512*4);
  const size_t oPKEY = A(2048*4);
  const size_t oPA   = A(2048*4);
  const size_t oPMAX = A((size_t)BB*1024*16*4);
  const size_t oV0   = A((size_t)BB*2048*3*4);
  const size_t oV1   = A((size_t)BB*512*3*4);
  const size_t oV2   = A((size_t)BB*128*3*4);
  const size_t oV1S  = A((size_t)BB*3*512*4);
  const size_t oV2S  = A((size_t)BB*3*128*4);
  const size_t oIDX0 = A((size_t)BB*2048*20*4);
  const size_t oDIR0 = A((size_t)BB*2048*20*3*4);
  const size_t oFM0  = A((size_t)BB*2048*32*4);
  const size_t oFM1  = A((size_t)BB*2048*64*4);
  const size_t oI40  = A((size_t)BB*512*4*4);
  const size_t oFM1P = A((size_t)BB*512*64*4);
  const size_t oIDX1 = A((size_t)BB*512*20*4);
  const size_t oDIR1 = A((size_t)BB*512*20*3*4);
  const size_t oFM2  = A((size_t)BB*512*128*4);
  const size_t oFM3  = A((size_t)BB*512*256*4);
  const size_t oI41  = A((size_t)BB*128*4*4);
  const size_t oFM3P = A((size_t)BB*128*256*4);
  const size_t oIDX2 = A((size_t)BB*128*20*4);
  const size_t oDIR2 = A((size_t)BB*128*20*3*4);
  const size_t oFM4  = A((size_t)BB*128*1024*4);
  const size_t oBIGA = A((size_t)BB*256*NN*4);   // x1, then x3
  const size_t oBIGB = A((size_t)BB*128*NN*4);   // x2, then feat1..feat4
  if (off > ws_size){
    k_sentinel<<<cdiv(out_size,256),256,0,stream>>>(out, out_size, 1000.0f);
    return;
  }
  float* xmax = (float*)(w+oXMAX); float* fg = (float*)(w+oFG);
  float* gf = (float*)(w+oGF);     float* hbuf = (float*)(w+oH);
  int* p2048 = (int*)(w+oP2048);   int* p512 = (int*)(w+oP512);
  unsigned* pkeys = (unsigned*)(w+oPKEY); int* pa = (int*)(w+oPA);
  float* pmax = (float*)(w+oPMAX);
  float* v0 = (float*)(w+oV0); float* v1 = (float*)(w+oV1); float* v2 = (float*)(w+oV2);
  float* v1s = (float*)(w+oV1S); float* v2s = (float*)(w+oV2S);
  int* idx0 = (int*)(w+oIDX0); int* idx1 = (int*)(w+oIDX1); int* idx2 = (int*)(w+oIDX2);
  int* i40 = (int*)(w+oI40);   int* i41 = (int*)(w+oI41);
  float* d0 = (float*)(w+oDIR0); float* d1 = (float*)(w+oDIR1); float* d2 = (float*)(w+oDIR2);
  float* fm0 = (float*)(w+oFM0); float* fm1 = (float*)(w+oFM1); float* fm1p = (float*)(w+oFM1P);
  float* fm2 = (float*)(w+oFM2); float* fm3 = (float*)(w+oFM3); float* fm3p = (float*)(w+oFM3P);
  float* fm4 = (float*)(w+oFM4);
  float* x1 = (float*)(w+oBIGA); float* x3 = (float*)(w+oBIGA);
  float* x2 = (float*)(w+oBIGB); float* feat = (float*)(w+oBIGB);

  // MLP branch
  k_mlp1<<<cdiv((long long)BB*64*NN,256),256,0,stream>>>(xyz, w1, b1, x1);
  k_mlp2<<<cdiv((long long)BB*128*NN,256),256,0,stream>>>(x1, w2, b2, x2);
  k_rowmax<<<BB*128,256,0,stream>>>(x2, gf, NN);
  k_mlp3<<<dim3(16,2,BB),256,0,stream>>>(x2, gf, w3, b3, x3);
  k_mlp4max<<<dim3(16,8,BB),256,0,stream>>>(x3, w4, b4, pmax);
  k_xmax<<<cdiv(BB*1024,256),256,0,stream>>>(pmax, xmax);

  // permutations: host-computed threefry round keys (jax.random.permutation, partitionable)
  {
    unsigned ck0=0u, ck1=1u, nk0,nk1, s00,s01, s10,s11, sc0,sc1;
    tf2h(ck0,ck1, 0u,0u, nk0,nk1);   // split key(1) round 0
    tf2h(ck0,ck1, 0u,1u, s00,s01);
    tf2h(nk0,nk1, 0u,1u, s10,s11);   // round 1 subkey
    tf2h(0u,2u,  0u,1u, sc0,sc1);    // key(2), single round
    k_permkeys<<<8,256,0,stream>>>(2048, s00, s01, pkeys);
    k_permrank<<<8,256,0,stream>>>(2048, pkeys, nullptr, pa);
    k_permkeys<<<8,256,0,stream>>>(2048, s10, s11, pkeys);
    k_permrank<<<8,256,0,stream>>>(2048, pkeys, pa, p2048);
    k_permkeys<<<2,256,0,stream>>>(512, sc0, sc1, pkeys);
    k_permrank<<<2,256,0,stream>>>(512, pkeys, nullptr, p512);
  }

  // graph branch: stage 0 (V=2048) — xyz is already [b][3][V] SoA for knn
  k_transpose<<<cdiv((long long)BB*NN*3,256),256,0,stream>>>(xyz, v0);
  k_knn_wq<32,20><<<dim3(512,BB),256,0,stream>>>(xyz, nullptr, 2048, idx0);
  k_dirs<<<cdiv((long long)BB*2048*20,256),256,0,stream>>>(v0, 2048, idx0, d0, BB*2048*20);
  k_surf<<<cdiv((long long)BB*2048*32,256),256,0,stream>>>(d0, dir0, fm0, 2048);
  k_gemm<<<dim3(1,256),256,0,stream>>>(fm0, wc1, bc1, feat, BB*2048, 32, 128);
  k_comb<<<cdiv((long long)BB*2048*64,256),256,0,stream>>>(feat, idx0, d0, dir1, fm1, 2048, 64, 1);
  // pool 1
  k_knn_wq<32,4><<<dim3(128,BB),256,0,stream>>>(xyz, p2048, 512, i40);
  k_pool<<<cdiv((long long)BB*512*64,256),256,0,stream>>>(fm1, i40, fm1p, 2048, 64, 512);
  k_vgather<<<cdiv((long long)BB*512*3,256),256,0,stream>>>(v0, p2048, v1, v1s, 2048, 512);
  // stage 1 (V=512)
  k_knn_wq<8,20><<<dim3(128,BB),256,0,stream>>>(v1s, nullptr, 512, idx1);
  k_dirs<<<cdiv((long long)BB*512*20,256),256,0,stream>>>(v1, 512, idx1, d1, BB*512*20);
  k_gemm<<<dim3(2,64),256,0,stream>>>(fm1p, wc2, bc2, feat, BB*512, 64, 256);
  k_comb<<<cdiv((long long)BB*512*128,256),256,0,stream>>>(feat, idx1, d1, dir2, fm2, 512, 128, 1);
  k_gemm<<<dim3(4,64),256,0,stream>>>(fm2, wc3, bc3, feat, BB*512, 128, 512);
  k_comb<<<cdiv((long long)BB*512*256,256),256,0,stream>>>(feat, idx1, d1, dir3, fm3, 512, 256, 1);
  // pool 2
  k_knn_wq<8,4><<<dim3(32,BB),256,0,stream>>>(v1s, p512, 128, i41);
  k_pool<<<cdiv((long long)BB*128*256,256),256,0,stream>>>(fm3, i41, fm3p, 512, 256, 128);
  k_vgather<<<cdiv((long long)BB*128*3,256),256,0,stream>>>(v1, p512, v2, v2s, 512, 128);
  // stage 2 (V=128)
  k_knn_wq<2,20><<<dim3(32,BB),256,0,stream>>>(v2s, nullptr, 128, idx2);
  k_dirs<<<cdiv((long long)BB*128*20,256),256,0,stream>>>(v2, 128, idx2, d2, BB*128*20);
  k_gemm<<<dim3(16,16),256,0,stream>>>(fm3p, wc4, bc4, feat, BB*128, 256, 2048);
  k_comb<<<cdiv((long long)BB*128*1024,256),256,0,stream>>>(feat, idx2, d2, dir4, fm4, 128, 1024, 0);
  k_colmax<<<cdiv(BB*1024,256),256,0,stream>>>(fm4, fg, 128, 1024);

  // FC head
  k_emb<<<cdiv(BB*512,256),256,0,stream>>>(xmax, fg, fcw, fcb, out);
  k_h<<<cdiv(BB*512,256),256,0,stream>>>(xmax, fg, clw1, clb1, gma, bta, hbuf);
  k_pred<<<1,128,0,stream>>>(hbuf, clw2, clb2, out);
}

// Round 5
// 1067.356 us; speedup vs baseline: 2.3080x; 1.2372x over previous
//
#include <hip/hip_runtime.h>
#include <hip/hip_bf16.h>
#include <math.h>

#define BB 16
#define NN 2048

__global__ void k_sentinel(float* o, int n, float v){
  int i = blockIdx.x*256 + threadIdx.x;
  if (i < n) o[i] = v;
}

/* ---------------- MLP branch ---------------- */

__global__ void k_mlp1(const float* __restrict__ xyz, const float* __restrict__ w1,
                       const float* __restrict__ b1, float* __restrict__ x1){
  int id = blockIdx.x*256 + threadIdx.x;
  if (id >= BB*64*NN) return;
  int n = id & (NN-1), o = (id>>11) & 63, b = id>>17;
  float acc = b1[o];
  #pragma unroll
  for (int c=0;c<3;c++)
    acc += w1[o*3+c] * xyz[(size_t)(b*3+c)*NN + n];
  x1[id] = fmaxf(acc, 0.f);
}

__global__ void k_mlp2(const float* __restrict__ x1, const float* __restrict__ w2,
                       const float* __restrict__ bias, float* __restrict__ x2){
  int id = blockIdx.x*256 + threadIdx.x;
  if (id >= BB*128*NN) return;
  int n = id & (NN-1), o = (id>>11) & 127, b = id>>18;
  float acc = bias[o];
  const float* xr = x1 + (size_t)b*64*NN + n;
  const float* wr = w2 + o*64;
  for (int c=0;c<64;c++) acc += wr[c] * xr[(size_t)c*NN];
  x2[id] = fmaxf(acc, 0.f);
}

__global__ __launch_bounds__(256) void k_rowmax(const float* __restrict__ x, float* __restrict__ o, int cols){
  __shared__ float sm[256];
  int row = blockIdx.x, t = threadIdx.x;
  const float* xr = x + (size_t)row*cols;
  float m = -INFINITY;
  for (int c=t;c<cols;c+=256) m = fmaxf(m, xr[c]);
  sm[t]=m; __syncthreads();
  for (int s=128;s>0;s>>=1){ if (t<s) sm[t]=fmaxf(sm[t], sm[t+s]); __syncthreads(); }
  if (!t) o[row]=sm[0];
}

// x3 = relu(W3 @ [x2; gf_broadcast] + b3), tiled 128x128, K=256 in chunks of 32
__global__ __launch_bounds__(256) void k_mlp3(const float* __restrict__ x2, const float* __restrict__ gf,
                                              const float* __restrict__ w3, const float* __restrict__ b3,
                                              float* __restrict__ x3){
  __shared__ float Wt[128][33];
  __shared__ float Xt[32][128];
  int nt = blockIdx.x, ot = blockIdx.y, b = blockIdx.z;
  int t = threadIdx.x, tx = t & 15, ty = t >> 4;
  int o0 = ot*128, n0 = nt*128;
  float acc[8][8];
  #pragma unroll
  for (int i=0;i<8;i++) for (int j=0;j<8;j++) acc[i][j]=0.f;
  for (int k0=0;k0<256;k0+=32){
    for (int i=t;i<128*32;i+=256){ int oo=i>>5, kk=i&31; Wt[oo][kk]=w3[(o0+oo)*256+k0+kk]; }
    for (int i=t;i<32*128;i+=256){ int kk=i>>7, nn=i&127; int c=k0+kk;
      Xt[kk][nn] = (c<128) ? x2[(size_t)(b*128+c)*NN + n0+nn] : gf[b*128 + (c-128)];
    }
    __syncthreads();
    for (int kk=0;kk<32;kk++){
      float xv[8], wv[8];
      #pragma unroll
      for (int j=0;j<8;j++) xv[j]=Xt[kk][tx*8+j];
      #pragma unroll
      for (int i=0;i<8;i++) wv[i]=Wt[ty*8+i][kk];
      #pragma unroll
      for (int i=0;i<8;i++)
        #pragma unroll
        for (int j=0;j<8;j++) acc[i][j] += wv[i]*xv[j];
    }
    __syncthreads();
  }
  for (int i=0;i<8;i++){
    int o = o0 + ty*8 + i;
    float bi = b3[o];
    for (int j=0;j<8;j++)
      x3[(size_t)(b*256+o)*NN + n0 + tx*8 + j] = fmaxf(acc[i][j]+bi, 0.f);
  }
}

// pmax[b,o,nt] = max over this n-tile of relu(W4 @ x3 + b4)
__global__ __launch_bounds__(256) void k_mlp4max(const float* __restrict__ x3, const float* __restrict__ w4,
                                                 const float* __restrict__ b4, float* __restrict__ pmax){
  __shared__ float Wt[128][33];
  __shared__ float Xt[32][128];
  __shared__ float red[16][8][17];
  int nt = blockIdx.x, ot = blockIdx.y, b = blockIdx.z;
  int t = threadIdx.x, tx = t & 15, ty = t >> 4;
  int o0 = ot*128, n0 = nt*128;
  float acc[8][8];
  #pragma unroll
  for (int i=0;i<8;i++) for (int j=0;j<8;j++) acc[i][j]=0.f;
  for (int k0=0;k0<256;k0+=32){
    for (int i=t;i<128*32;i+=256){ int oo=i>>5, kk=i&31; Wt[oo][kk]=w4[(o0+oo)*256+k0+kk]; }
    for (int i=t;i<32*128;i+=256){ int kk=i>>7, nn=i&127; Xt[kk][nn]=x3[(size_t)(b*256+k0+kk)*NN + n0+nn]; }
    __syncthreads();
    for (int kk=0;kk<32;kk++){
      float xv[8], wv[8];
      #pragma unroll
      for (int j=0;j<8;j++) xv[j]=Xt[kk][tx*8+j];
      #pragma unroll
      for (int i=0;i<8;i++) wv[i]=Wt[ty*8+i][kk];
      #pragma unroll
      for (int i=0;i<8;i++)
        #pragma unroll
        for (int j=0;j<8;j++) acc[i][j] += wv[i]*xv[j];
    }
    __syncthreads();
  }
  for (int i=0;i<8;i++){
    float bi = b4[o0+ty*8+i];
    float m = 0.f;
    for (int j=0;j<8;j++) m = fmaxf(m, fmaxf(acc[i][j]+bi, 0.f));
    red[ty][i][tx] = m;
  }
  __syncthreads();
  if (t < 128){
    int ty2 = t>>3, i2 = t&7;
    float m = red[ty2][i2][0];
    for (int x=1;x<16;x++) m = fmaxf(m, red[ty2][i2][x]);
    pmax[(size_t)(b*1024 + o0 + ty2*8 + i2)*16 + nt] = m;
  }
}

__global__ void k_xmax(const float* __restrict__ pmax, float* __restrict__ xmax){
  int id = blockIdx.x*256 + threadIdx.x;
  if (id >= BB*1024) return;
  float m = pmax[(size_t)id*16];
  for (int k=1;k<16;k++) m = fmaxf(m, pmax[(size_t)id*16+k]);
  xmax[id] = m;
}

/* ---------------- JAX threefry PRNG permutation ---------------- */

#define TF2BODY \
  unsigned ks2 = 0x1BD11BDAu ^ k0 ^ k1; \
  unsigned a = x0 + k0, b = x1 + k1; \
  { \
  a += b; b = (b<<13)|(b>>19); b ^= a; \
  a += b; b = (b<<15)|(b>>17); b ^= a; \
  a += b; b = (b<<26)|(b>>6);  b ^= a; \
  a += b; b = (b<<6) |(b>>26); b ^= a;  a += k1;  b += ks2 + 1u; \
  a += b; b = (b<<17)|(b>>15); b ^= a; \
  a += b; b = (b<<29)|(b>>3);  b ^= a; \
  a += b; b = (b<<16)|(b>>16); b ^= a; \
  a += b; b = (b<<24)|(b>>8);  b ^= a;  a += ks2; b += k0  + 2u; \
  a += b; b = (b<<13)|(b>>19); b ^= a; \
  a += b; b = (b<<15)|(b>>17); b ^= a; \
  a += b; b = (b<<26)|(b>>6);  b ^= a; \
  a += b; b = (b<<6) |(b>>26); b ^= a;  a += k0;  b += k1  + 3u; \
  a += b; b = (b<<17)|(b>>15); b ^= a; \
  a += b; b = (b<<29)|(b>>3);  b ^= a; \
  a += b; b = (b<<16)|(b>>16); b ^= a; \
  a += b; b = (b<<24)|(b>>8);  b ^= a;  a += k1;  b += ks2 + 4u; \
  a += b; b = (b<<13)|(b>>19); b ^= a; \
  a += b; b = (b<<15)|(b>>17); b ^= a; \
  a += b; b = (b<<26)|(b>>6);  b ^= a; \
  a += b; b = (b<<6) |(b>>26); b ^= a;  a += ks2; b += k0  + 5u; \
  } \
  o0 = a; o1 = b;

__device__ __forceinline__ void tf2(unsigned k0, unsigned k1, unsigned x0, unsigned x1,
                                    unsigned &o0, unsigned &o1){ TF2BODY }
static void tf2h(unsigned k0, unsigned k1, unsigned x0, unsigned x1,
                 unsigned &o0, unsigned &o1){ TF2BODY }

__global__ void k_permkeys(int n, unsigned sk0, unsigned sk1, unsigned* __restrict__ keys){
  int i = blockIdx.x*256 + threadIdx.x;
  if (i < n){ unsigned a,b2; tf2(sk0, sk1, 0u, (unsigned)i, a, b2); keys[i] = a ^ b2; }
}

// stable ascending rank-scatter: out[rank_i] = (vin ? vin[i] : i)
__global__ void k_permrank(int n, const unsigned* __restrict__ keys,
                           const int* __restrict__ vin, int* __restrict__ vout){
  int i = blockIdx.x*256 + threadIdx.x;
  if (i >= n) return;
  unsigned ki = keys[i];
  int rank = 0;
  for (int j=0;j<n;j++){
    unsigned kj = keys[j];
    rank += (kj < ki) || (kj == ki && j < i);
  }
  vout[rank] = vin ? vin[i] : i;
}

/* ---------------- graph branch ---------------- */

__global__ void k_transpose(const float* __restrict__ xyz, float* __restrict__ verts){
  int id = blockIdx.x*256 + threadIdx.x;
  if (id >= BB*NN*3) return;
  int c = id % 3, v = (id/3) % NN, b = id/(3*NN);
  verts[id] = xyz[(size_t)(b*3+c)*NN + v];
}

// Wave-per-query KNN with group-minima successor selection. verts in
// batch-component-SoA [b][3][V]. u64 key = (monotone f32 dist << 32) | idx
// reproduces XLA stable top-k exactly. Per round: butterfly-min of lane bests;
// only the winning lane refilters its winning group of GS keys (keys > last
// stay valid for all other groups since extracted best < all remaining keys).
template<int CPL, int KSEL>
__global__ __launch_bounds__(256,4) void k_knn_g(const float* __restrict__ vbcs,
                                                 const int* __restrict__ qmap, int numQ,
                                                 int* __restrict__ out){
  constexpr int V = CPL*64;
  constexpr int GS = (CPL < 8) ? CPL : 8;
  constexpr int NG = CPL/GS;
  constexpr int GSH = (GS==8)?3:((GS==4)?2:((GS==2)?1:0));
  int t = threadIdx.x, wid = t>>6, lane = t&63;
  int b = blockIdx.y;
  int q = blockIdx.x*4 + wid;
  if (q >= numQ) return;
  const float* vx = vbcs + (size_t)b*3*V;
  const float* vy = vx + V;
  const float* vz = vy + V;
  int qv = qmap ? qmap[q] : q;
  float qx = vx[qv], qy = vy[qv], qz = vz[qv];
  float qq = qx*qx + qy*qy + qz*qz;
  unsigned long long key[CPL];
  #pragma unroll
  for (int i=0;i<CPL;i++){
    int c = lane + i*64;
    float wx=vx[c], wy=vy[c], wz=vz[c];
    float inner = qx*wx + qy*wy + qz*wz;
    float ww = wx*wx + wy*wy + wz*wz;
    float d = qq - 2.f*inner + ww;
    unsigned db = __float_as_uint(d);
    db = (db & 0x80000000u) ? ~db : (db | 0x80000000u);
    key[i] = ((unsigned long long)db << 32) | (unsigned)c;
  }
  unsigned long long g[NG];
  #pragma unroll
  for (int gg=0; gg<NG; gg++){
    unsigned long long m = key[gg*GS];
    #pragma unroll
    for (int j=1;j<GS;j++){ unsigned long long kk2 = key[gg*GS+j]; m = (kk2<m)?kk2:m; }
    g[gg] = m;
  }
  unsigned long long lb = g[0];
  #pragma unroll
  for (int gg=1;gg<NG;gg++) lb = (g[gg]<lb)?g[gg]:lb;

  int* orow = out + ((size_t)b*numQ + q)*KSEL;
  unsigned long long last = 0ull;
  for (int r=0; r<=KSEL; r++){
    unsigned long long best = lb;
    #pragma unroll
    for (int off=32; off>0; off>>=1){
      unsigned long long o = __shfl_xor(best, off, 64);
      best = (o < best) ? o : best;
    }
    int c = (int)(best & 0xffffffffull);
    if (r>0 && lane==0) orow[r-1] = c;
    last = best;
    if ((c & 63) == lane){
      int gi = c >> (6 + GSH);
      #pragma unroll
      for (int gg=0; gg<NG; gg++){
        if (gg == gi){
          unsigned long long m = ~0ull;
          #pragma unroll
          for (int j=0;j<GS;j++){
            unsigned long long kk2 = key[gg*GS+j];
            unsigned long long qk = (kk2 > last) ? kk2 : ~0ull;
            m = (qk<m)?qk:m;
          }
          g[gg] = m;
        }
      }
      unsigned long long nb2 = g[0];
      #pragma unroll
      for (int gg=1;gg<NG;gg++) nb2 = (g[gg]<nb2)?g[gg]:nb2;
      lb = nb2;
    }
  }
}

__global__ void k_dirs(const float* __restrict__ verts, int V, const int* __restrict__ idx,
                       float* __restrict__ dirs, int total){
  int id = blockIdx.x*256 + threadIdx.x;
  if (id >= total) return;
  int v = (id/20) % V, b = id/(20*V);
  const float* vb = verts + (size_t)b*V*3;
  int nb = idx[id];
  float dx = vb[nb*3+0]-vb[v*3+0];
  float dy = vb[nb*3+1]-vb[v*3+1];
  float dz = vb[nb*3+2]-vb[v*3+2];
  float s = 1.f / fmaxf(sqrtf(dx*dx+dy*dy+dz*dz), 1e-12f);
  dirs[(size_t)id*3+0]=dx*s; dirs[(size_t)id*3+1]=dy*s; dirs[(size_t)id*3+2]=dz*s;
}

__global__ void k_surf(const float* __restrict__ dirs, const float* __restrict__ dir0,
                       float* __restrict__ fm0, int V){
  int id = blockIdx.x*256 + threadIdx.x;
  if (id >= BB*V*32) return;
  int k = id & 31; int vv = (id>>5) % V; int b = id/(32*V);
  float nx=dir0[k], ny=dir0[32+k], nz=dir0[64+k];
  float s = 1.f/fmaxf(sqrtf(nx*nx+ny*ny+nz*nz), 1e-12f);
  nx*=s; ny*=s; nz*=s;
  const float* dd = dirs + (size_t)(b*V+vv)*60;
  float m = 0.f;
  for (int n=0;n<20;n++){
    float th = dd[n*3]*nx + dd[n*3+1]*ny + dd[n*3+2]*nz;
    m = fmaxf(m, fmaxf(th, 0.f));
  }
  fm0[(size_t)(b*V+vv)*32 + k] = m;
}

// O = A @ B + bias; A (R,K) rm, B (K,C) rm. Tiles 128x128, K-chunk 32.
__global__ __launch_bounds__(256) void k_gemm(const float* __restrict__ A, const float* __restrict__ Bm,
                                              const float* __restrict__ bias, float* __restrict__ O,
                                              int R, int K, int C){
  __shared__ float At[128][33];
  __shared__ float Bt[32][128];
  int ct = blockIdx.x, rt = blockIdx.y;
  int t = threadIdx.x, tx = t & 15, ty = t >> 4;
  int r0 = rt*128, c0 = ct*128;
  float acc[8][8];
  #pragma unroll
  for (int i=0;i<8;i++) for (int j=0;j<8;j++) acc[i][j]=0.f;
  for (int k0=0;k0<K;k0+=32){
    for (int i=t;i<128*32;i+=256){ int rr=i>>5, kk=i&31; At[rr][kk]=A[(size_t)(r0+rr)*K + k0+kk]; }
    for (int i=t;i<32*128;i+=256){ int kk=i>>7, cc=i&127; Bt[kk][cc]=Bm[(size_t)(k0+kk)*C + c0+cc]; }
    __syncthreads();
    for (int kk=0;kk<32;kk++){
      float xv[8], wv[8];
      #pragma unroll
      for (int j=0;j<8;j++) xv[j]=Bt[kk][tx*8+j];
      #pragma unroll
      for (int i=0;i<8;i++) wv[i]=At[ty*8+i][kk];
      #pragma unroll
      for (int i=0;i<8;i++)
        #pragma unroll
        for (int j=0;j<8;j++) acc[i][j] += wv[i]*xv[j];
    }
    __syncthreads();
  }
  for (int i=0;i<8;i++){
    size_t r = r0 + ty*8 + i;
    for (int j=0;j<8;j++){
      int c = c0 + tx*8 + j;
      O[r*C + c] = acc[i][j] + bias[c];
    }
  }
}

// out = [relu]( feat[:, :OC] + max_n( relu(dirs . ndir_col) * feat[nb, OC: ] ) )
__global__ void k_comb(const float* __restrict__ feat, const int* __restrict__ idx,
                       const float* __restrict__ dirs, const float* __restrict__ dw,
                       float* __restrict__ outp, int V, int OC, int relu_flag){
  int id = blockIdx.x*256 + threadIdx.x;
  if (id >= BB*V*OC) return;
  int oc = id % OC, v = (id/OC) % V, b = id/(OC*V);
  float wx=dw[oc], wy=dw[OC+oc], wz=dw[2*OC+oc];
  float s = 1.f/fmaxf(sqrtf(wx*wx+wy*wy+wz*wz), 1e-12f);
  wx*=s; wy*=s; wz*=s;
  size_t row = (size_t)b*V + v;
  const int* ir = idx + row*20;
  const float* dd = dirs + row*60;
  float center = feat[row*2*OC + oc];
  float m = -INFINITY;
  for (int n=0;n<20;n++){
    int nb = ir[n];
    float th = dd[n*3]*wx + dd[n*3+1]*wy + dd[n*3+2]*wz;
    th = fmaxf(th, 0.f);
    float sup = feat[((size_t)b*V + nb)*2*OC + OC + oc];
    m = fmaxf(m, th*sup);
  }
  float rv = center + m;
  outp[row*OC + oc] = relu_flag ? fmaxf(rv, 0.f) : rv;
}

__global__ void k_pool(const float* __restrict__ fm, const int* __restrict__ idx4,
                       float* __restrict__ outp, int V, int C, int numS){
  int id = blockIdx.x*256 + threadIdx.x;
  if (id >= BB*numS*C) return;
  int c = id % C, sI = (id/C) % numS, b = id/(C*numS);
  const int* ir = idx4 + ((size_t)b*numS + sI)*4;
  float m = -INFINITY;
  for (int n=0;n<4;n++) m = fmaxf(m, fm[((size_t)b*V + ir[n])*C + c]);
  outp[((size_t)b*numS + sI)*C + c] = m;
}

// gathers pooled verts; writes AOS (for k_dirs) and batch-component-SoA (for knn)
__global__ void k_vgather(const float* __restrict__ vin, const int* __restrict__ perm,
                          float* __restrict__ vout, float* __restrict__ vbcs,
                          int V, int numS){
  int id = blockIdx.x*256 + threadIdx.x;
  if (id >= BB*numS*3) return;
  int c = id % 3, sI = (id/3) % numS, b = id/(3*numS);
  float val = vin[((size_t)b*V + perm[sI])*3 + c];
  vout[id] = val;
  vbcs[((size_t)b*3 + c)*numS + sI] = val;
}

__global__ void k_colmax(const float* __restrict__ x, float* __restrict__ o, int Vr, int C){
  int id = blockIdx.x*256 + threadIdx.x;
  if (id >= BB*C) return;
  int c = id % C, b = id / C;
  float m = -INFINITY;
  for (int v=0; v<Vr; v++) m = fmaxf(m, x[(size_t)(b*Vr+v)*C + c]);
  o[id] = m;
}

/* ---------------- FC head (wave-per-output dot products) ---------------- */

__global__ __launch_bounds__(256) void k_emb2(const float* __restrict__ xmax, const float* __restrict__ fg,
                                              const float* __restrict__ fcw, const float* __restrict__ fcb,
                                              float* __restrict__ outp){
  int gid = blockIdx.x*4 + (threadIdx.x>>6);
  int lane = threadIdx.x & 63;
  if (gid >= BB*512) return;
  int e = gid & 511, b = gid >> 9;
  const float* wr = fcw + (size_t)e*2048;
  const float* xb = xmax + b*1024;
  const float* gb = fg + b*1024;
  float acc = 0.f;
  for (int k=lane; k<1024; k+=64)
    acc += xb[k]*wr[k] + gb[k]*wr[1024+k];
  #pragma unroll
  for (int off=32; off>0; off>>=1) acc += __shfl_xor(acc, off, 64);
  if (lane==0) outp[gid] = acc + fcb[e];
}

__global__ __launch_bounds__(256) void k_h2(const float* __restrict__ xmax, const float* __restrict__ fg,
                                            const float* __restrict__ clw1, const float* __restrict__ clb1,
                                            const float* __restrict__ gamma, const float* __restrict__ beta,
                                            float* __restrict__ h){
  int gid = blockIdx.x*4 + (threadIdx.x>>6);
  int lane = threadIdx.x & 63;
  if (gid >= BB*512) return;
  int j = gid & 511, b = gid >> 9;
  const float* wr = clw1 + (size_t)j*2048;
  const float* xb = xmax + b*1024;
  const float* gb = fg + b*1024;
  float acc = 0.f;
  for (int k=lane; k<1024; k+=64)
    acc += xb[k]*wr[k] + gb[k]*wr[1024+k];
  #pragma unroll
  for (int off=32; off>0; off>>=1) acc += __shfl_xor(acc, off, 64);
  if (lane==0){
    const float inv_s = 1.0f / sqrtf(1.0f + 1e-5f);
    float v = (acc + clb1[j]) * inv_s * gamma[j] + beta[j];
    h[gid] = fmaxf(v, 0.f);
  }
}

__global__ __launch_bounds__(256) void k_pred2(const float* __restrict__ h, const float* __restrict__ clw2,
                                               const float* __restrict__ clb2, float* __restrict__ outp){
  int gid = blockIdx.x*4 + (threadIdx.x>>6);
  int lane = threadIdx.x & 63;
  if (gid >= BB*6) return;
  int o = gid % 6, b = gid / 6;
  const float* hb = h + b*512;
  const float* wr = clw2 + o*512;
  float acc = 0.f;
  for (int k=lane; k<512; k+=64) acc += hb[k]*wr[k];
  #pragma unroll
  for (int off=32; off>0; off>>=1) acc += __shfl_xor(acc, off, 64);
  if (lane==0) outp[BB*512 + gid] = acc + clb2[o];
}

/* ---------------- launch ---------------- */

static inline int cdiv(long long a, int b){ return (int)((a + b - 1)/b); }

extern "C" void kernel_launch(void* const* d_in, const int* in_sizes, int n_in,
                              void* d_out, int out_size, void* d_ws, size_t ws_size,
                              hipStream_t stream){
  float* out = (float*)d_out;
  if (n_in != 30 || in_sizes[0] != BB*3*NN || out_size != BB*512 + BB*6){
    k_sentinel<<<cdiv(out_size,256),256,0,stream>>>(out, out_size, 2000.0f);
    return;
  }
  const float* xyz  = (const float*)d_in[0];
  const float* w1   = (const float*)d_in[1];
  const float* b1   = (const float*)d_in[2];
  const float* w2   = (const float*)d_in[3];
  const float* b2   = (const float*)d_in[4];
  const float* w3   = (const float*)d_in[5];
  const float* b3   = (const float*)d_in[6];
  const float* w4   = (const float*)d_in[7];
  const float* b4   = (const float*)d_in[8];
  const float* fcw  = (const float*)d_in[9];
  const float* fcb  = (const float*)d_in[10];
  const float* dir0 = (const float*)d_in[11];
  const float* wc1  = (const float*)d_in[12];
  const float* bc1  = (const float*)d_in[13];
  const float* dir1 = (const float*)d_in[14];
  const float* wc2  = (const float*)d_in[15];
  const float* bc2  = (const float*)d_in[16];
  const float* dir2 = (const float*)d_in[17];
  const float* wc3  = (const float*)d_in[18];
  const float* bc3  = (const float*)d_in[19];
  const float* dir3 = (const float*)d_in[20];
  const float* wc4  = (const float*)d_in[21];
  const float* bc4  = (const float*)d_in[22];
  const float* dir4 = (const float*)d_in[23];
  const float* clw1 = (const float*)d_in[24];
  const float* clb1 = (const float*)d_in[25];
  const float* gma  = (const float*)d_in[26];
  const float* bta  = (const float*)d_in[27];
  const float* clw2 = (const float*)d_in[28];
  const float* clb2 = (const float*)d_in[29];

  char* w = (char*)d_ws;
  size_t off = 0;
  auto A = [&](size_t bytes){ size_t r = off; off += (bytes + 255) & ~(size_t)255; return r; };
  const size_t oXMAX = A((size_t)BB*1024*4);
  const size_t oFG   = A((size_t)BB*1024*4);
  const size_t oGF   = A((size_t)BB*128*4);
  const size_t oH    = A((size_t)BB*512*4);
  const size_t oP2048= A(2048*4);
  const size_t oP512 = A(512*4);
  const size_t oPKEY = A(2048*4);
  const size_t oPA   = A(2048*4);
  const size_t oPMAX = A((size_t)BB*1024*16*4);
  const size_t oV0   = A((size_t)BB*2048*3*4);
  const size_t oV1   = A((size_t)BB*512*3*4);
  const size_t oV2   = A((size_t)BB*128*3*4);
  const size_t oV1S  = A((size_t)BB*3*512*4);
  const size_t oV2S  = A((size_t)BB*3*128*4);
  const size_t oIDX0 = A((size_t)BB*2048*20*4);
  const size_t oDIR0 = A((size_t)BB*2048*20*3*4);
  const size_t oFM0  = A((size_t)BB*2048*32*4);
  const size_t oFM1  = A((size_t)BB*2048*64*4);
  const size_t oI40  = A((size_t)BB*512*4*4);
  const size_t oFM1P = A((size_t)BB*512*64*4);
  const size_t oIDX1 = A((size_t)BB*512*20*4);
  const size_t oDIR1 = A((size_t)BB*512*20*3*4);
  const size_t oFM2  = A((size_t)BB*512*128*4);
  const size_t oFM3  = A((size_t)BB*512*256*4);
  const size_t oI41  = A((size_t)BB*128*4*4);
  const size_t oFM3P = A((size_t)BB*128*256*4);
  const size_t oIDX2 = A((size_t)BB*128*20*4);
  const size_t oDIR2 = A((size_t)BB*128*20*3*4);
  const size_t oFM4  = A((size_t)BB*128*1024*4);
  const size_t oBIGA = A((size_t)BB*256*NN*4);   // x1, then x3
  const size_t oBIGB = A((size_t)BB*128*NN*4);   // x2, then feat1..feat4
  if (off > ws_size){
    k_sentinel<<<cdiv(out_size,256),256,0,stream>>>(out, out_size, 1000.0f);
    return;
  }
  float* xmax = (float*)(w+oXMAX); float* fg = (float*)(w+oFG);
  float* gf = (float*)(w+oGF);     float* hbuf = (float*)(w+oH);
  int* p2048 = (int*)(w+oP2048);   int* p512 = (int*)(w+oP512);
  unsigned* pkeys = (unsigned*)(w+oPKEY); int* pa = (int*)(w+oPA);
  float* pmax = (float*)(w+oPMAX);
  float* v0 = (float*)(w+oV0); float* v1 = (float*)(w+oV1); float* v2 = (float*)(w+oV2);
  float* v1s = (float*)(w+oV1S); float* v2s = (float*)(w+oV2S);
  int* idx0 = (int*)(w+oIDX0); int* idx1 = (int*)(w+oIDX1); int* idx2 = (int*)(w+oIDX2);
  int* i40 = (int*)(w+oI40);   int* i41 = (int*)(w+oI41);
  float* d0 = (float*)(w+oDIR0); float* d1 = (float*)(w+oDIR1); float* d2 = (float*)(w+oDIR2);
  float* fm0 = (float*)(w+oFM0); float* fm1 = (float*)(w+oFM1); float* fm1p = (float*)(w+oFM1P);
  float* fm2 = (float*)(w+oFM2); float* fm3 = (float*)(w+oFM3); float* fm3p = (float*)(w+oFM3P);
  float* fm4 = (float*)(w+oFM4);
  float* x1 = (float*)(w+oBIGA); float* x3 = (float*)(w+oBIGA);
  float* x2 = (float*)(w+oBIGB); float* feat = (float*)(w+oBIGB);

  // MLP branch
  k_mlp1<<<cdiv((long long)BB*64*NN,256),256,0,stream>>>(xyz, w1, b1, x1);
  k_mlp2<<<cdiv((long long)BB*128*NN,256),256,0,stream>>>(x1, w2, b2, x2);
  k_rowmax<<<BB*128,256,0,stream>>>(x2, gf, NN);
  k_mlp3<<<dim3(16,2,BB),256,0,stream>>>(x2, gf, w3, b3, x3);
  k_mlp4max<<<dim3(16,8,BB),256,0,stream>>>(x3, w4, b4, pmax);
  k_xmax<<<cdiv(BB*1024,256),256,0,stream>>>(pmax, xmax);

  // permutations: host-computed threefry round keys (jax.random.permutation, partitionable)
  {
    unsigned ck0=0u, ck1=1u, nk0,nk1, s00,s01, s10,s11, sc0,sc1;
    tf2h(ck0,ck1, 0u,0u, nk0,nk1);   // split key(1) round 0
    tf2h(ck0,ck1, 0u,1u, s00,s01);
    tf2h(nk0,nk1, 0u,1u, s10,s11);   // round 1 subkey
    tf2h(0u,2u,  0u,1u, sc0,sc1);    // key(2), single round
    k_permkeys<<<8,256,0,stream>>>(2048, s00, s01, pkeys);
    k_permrank<<<8,256,0,stream>>>(2048, pkeys, nullptr, pa);
    k_permkeys<<<8,256,0,stream>>>(2048, s10, s11, pkeys);
    k_permrank<<<8,256,0,stream>>>(2048, pkeys, pa, p2048);
    k_permkeys<<<2,256,0,stream>>>(512, sc0, sc1, pkeys);
    k_permrank<<<2,256,0,stream>>>(512, pkeys, nullptr, p512);
  }

  // graph branch: stage 0 (V=2048) — xyz is already [b][3][V] SoA for knn
  k_transpose<<<cdiv((long long)BB*NN*3,256),256,0,stream>>>(xyz, v0);
  k_knn_g<32,20><<<dim3(512,BB),256,0,stream>>>(xyz, nullptr, 2048, idx0);
  k_dirs<<<cdiv((long long)BB*2048*20,256),256,0,stream>>>(v0, 2048, idx0, d0, BB*2048*20);
  k_surf<<<cdiv((long long)BB*2048*32,256),256,0,stream>>>(d0, dir0, fm0, 2048);
  k_gemm<<<dim3(1,256),256,0,stream>>>(fm0, wc1, bc1, feat, BB*2048, 32, 128);
  k_comb<<<cdiv((long long)BB*2048*64,256),256,0,stream>>>(feat, idx0, d0, dir1, fm1, 2048, 64, 1);
  // pool 1
  k_knn_g<32,4><<<dim3(128,BB),256,0,stream>>>(xyz, p2048, 512, i40);
  k_pool<<<cdiv((long long)BB*512*64,256),256,0,stream>>>(fm1, i40, fm1p, 2048, 64, 512);
  k_vgather<<<cdiv((long long)BB*512*3,256),256,0,stream>>>(v0, p2048, v1, v1s, 2048, 512);
  // stage 1 (V=512)
  k_knn_g<8,20><<<dim3(128,BB),256,0,stream>>>(v1s, nullptr, 512, idx1);
  k_dirs<<<cdiv((long long)BB*512*20,256),256,0,stream>>>(v1, 512, idx1, d1, BB*512*20);
  k_gemm<<<dim3(2,64),256,0,stream>>>(fm1p, wc2, bc2, feat, BB*512, 64, 256);
  k_comb<<<cdiv((long long)BB*512*128,256),256,0,stream>>>(feat, idx1, d1, dir2, fm2, 512, 128, 1);
  k_gemm<<<dim3(4,64),256,0,stream>>>(fm2, wc3, bc3, feat, BB*512, 128, 512);
  k_comb<<<cdiv((long long)BB*512*256,256),256,0,stream>>>(feat, idx1, d1, dir3, fm3, 512, 256, 1);
  // pool 2
  k_knn_g<8,4><<<dim3(32,BB),256,0,stream>>>(v1s, p512, 128, i41);
  k_pool<<<cdiv((long long)BB*128*256,256),256,0,stream>>>(fm3, i41, fm3p, 512, 256, 128);
  k_vgather<<<cdiv((long long)BB*128*3,256),256,0,stream>>>(v1, p512, v2, v2s, 512, 128);
  // stage 2 (V=128)
  k_knn_g<2,20><<<dim3(32,BB),256,0,stream>>>(v2s, nullptr, 128, idx2);
  k_dirs<<<cdiv((long long)BB*128*20,256),256,0,stream>>>(v2, 128, idx2, d2, BB*128*20);
  k_gemm<<<dim3(16,16),256,0,stream>>>(fm3p, wc4, bc4, feat, BB*128, 256, 2048);
  k_comb<<<cdiv((long long)BB*128*1024,256),256,0,stream>>>(feat, idx2, d2, dir4, fm4, 128, 1024, 0);
  k_colmax<<<cdiv(BB*1024,256),256,0,stream>>>(fm4, fg, 128, 1024);

  // FC head
  k_emb2<<<cdiv(BB*512,4),256,0,stream>>>(xmax, fg, fcw, fcb, out);
  k_h2<<<cdiv(BB*512,4),256,0,stream>>>(xmax, fg, clw1, clb1, gma, bta, hbuf);
  k_pred2<<<cdiv(BB*6,4),256,0,stream>>>(hbuf, clw2, clb2, out);
}

// Round 6
// 1012.383 us; speedup vs baseline: 2.4334x; 1.0543x over previous
//
#include <hip/hip_runtime.h>
#include <hip/hip_bf16.h>
#include <math.h>

#define BB 16
#define NN 2048

typedef __attribute__((ext_vector_type(8))) short s8v;
typedef __attribute__((ext_vector_type(4))) short s4v_;
typedef __attribute__((ext_vector_type(4))) float f4v;

__global__ void k_sentinel(float* o, int n, float v){
  int i = blockIdx.x*256 + threadIdx.x;
  if (i < n) o[i] = v;
}

__device__ __forceinline__ ushort f2bf(float x){
  unsigned u = __float_as_uint(x);
  unsigned r = u + 0x7FFFu + ((u>>16)&1u);
  return (ushort)(r>>16);
}

/* ---------------- MLP branch ---------------- */

__global__ void k_mlp1(const float* __restrict__ xyz, const float* __restrict__ w1,
                       const float* __restrict__ b1, float* __restrict__ x1){
  int id = blockIdx.x*256 + threadIdx.x;
  if (id >= BB*64*NN) return;
  int n = id & (NN-1), o = (id>>11) & 63, b = id>>17;
  float acc = b1[o];
  #pragma unroll
  for (int c=0;c<3;c++)
    acc += w1[o*3+c] * xyz[(size_t)(b*3+c)*NN + n];
  x1[id] = fmaxf(acc, 0.f);
}

__global__ __launch_bounds__(256) void k_rowmax(const float* __restrict__ x, float* __restrict__ o, int cols){
  __shared__ float sm[256];
  int row = blockIdx.x, t = threadIdx.x;
  const float* xr = x + (size_t)row*cols;
  float m = -INFINITY;
  for (int c=t;c<cols;c+=256) m = fmaxf(m, xr[c]);
  sm[t]=m; __syncthreads();
  for (int s=128;s>0;s>>=1){ if (t<s) sm[t]=fmaxf(sm[t], sm[t+s]); __syncthreads(); }
  if (!t) o[row]=sm[0];
}

/* ---------------- split-bf16 MFMA GEMM ----------------
   out[z][o0+r][n0+c] = (RELU?relu:id)( sum_k A[r][k]*B[z][k][c] + bias )
   A: [M][K] f32 row-major (weights or activation rows).
   B: [z][K][N] f32 (k-major, row stride N), rows k>=ksplit read gf broadcast.
   EPI=0: store f32. EPI=1: relu then max over cols -> pmax[z*M+row][ntile].
   BCOL: bias indexed by col (1) or row (0).
   Block: 128(M)x64(N), 4 waves each 64x32, K-chunk 32, mfma_f32_16x16x32_bf16,
   3-pass split (Ah*Bh + Ah*Bl + Al*Bh). */
template<int EPI, int RELU, int BCOL>
__global__ __launch_bounds__(256) void k_mgemm(
    const float* __restrict__ A, const float* __restrict__ B,
    const float* __restrict__ gfb, const float* __restrict__ bias,
    float* __restrict__ outp, float* __restrict__ pmaxp,
    int K, int ksplit, int N, size_t sB, size_t sOut, int M)
{
  __shared__ ushort Ah[128][40], Al[128][40];
  __shared__ ushort Bh[64][44], Bl[64][44];
  __shared__ float red[2][128];
  int t = threadIdx.x, z = blockIdx.z;
  int o0 = blockIdx.y*128, n0 = blockIdx.x*64;
  const float* Bz = B + (size_t)z*sB;
  const float* gfz = gfb ? (gfb + z*128) : nullptr;
  int wid = t>>6, lane = t&63;
  int wm = wid>>1, wn = wid&1;
  int lr = lane&15, kg = lane>>4;

  f4v acc[4][2];
  #pragma unroll
  for (int i=0;i<4;i++)
    #pragma unroll
    for (int j=0;j<2;j++) acc[i][j] = (f4v){0.f,0.f,0.f,0.f};

  for (int k0=0; k0<K; k0+=32){
    __syncthreads();
    // stage A tile 128x32 -> bf16 hi/lo
    #pragma unroll
    for (int i=0;i<16;i++){
      int j = i*256+t; int oo=j>>5, kk=j&31;
      float v = A[(size_t)(o0+oo)*K + k0+kk];
      ushort h = f2bf(v);
      float hf = __uint_as_float((unsigned)h<<16);
      Ah[oo][kk]=h; Al[oo][kk]=f2bf(v-hf);
    }
    // stage B tile 32x64 transposed -> [n][k] bf16 hi/lo
    #pragma unroll
    for (int i=0;i<8;i++){
      int j = i*256+t; int nn=j&63, kk=j>>6;
      int gk = k0+kk;
      float v = (gk < ksplit) ? Bz[(size_t)gk*N + n0+nn] : gfz[gk-ksplit];
      ushort h = f2bf(v);
      float hf = __uint_as_float((unsigned)h<<16);
      Bh[nn][kk]=h; Bl[nn][kk]=f2bf(v-hf);
    }
    __syncthreads();

    s8v ah[4], al[4], bh[2], bl[2];
    #pragma unroll
    for (int mt=0;mt<4;mt++){
      int row = wm*64 + mt*16 + lr;
      ah[mt] = *(const s8v*)&Ah[row][kg*8];
      al[mt] = *(const s8v*)&Al[row][kg*8];
    }
    #pragma unroll
    for (int nt=0;nt<2;nt++){
      int col = wn*32 + nt*16 + lr;
      const ushort* ph = &Bh[col][kg*8];
      const ushort* pl = &Bl[col][kg*8];
      *(s4v_*)&bh[nt] = *(const s4v_*)ph;
      *((s4v_*)&bh[nt]+1) = *(const s4v_*)(ph+4);
      *(s4v_*)&bl[nt] = *(const s4v_*)pl;
      *((s4v_*)&bl[nt]+1) = *(const s4v_*)(pl+4);
    }
    #pragma unroll
    for (int mt=0;mt<4;mt++)
      #pragma unroll
      for (int nt=0;nt<2;nt++){
        acc[mt][nt] = __builtin_amdgcn_mfma_f32_16x16x32_bf16(ah[mt], bh[nt], acc[mt][nt], 0,0,0);
        acc[mt][nt] = __builtin_amdgcn_mfma_f32_16x16x32_bf16(ah[mt], bl[nt], acc[mt][nt], 0,0,0);
        acc[mt][nt] = __builtin_amdgcn_mfma_f32_16x16x32_bf16(al[mt], bh[nt], acc[mt][nt], 0,0,0);
      }
  }

  if (EPI == 0){
    #pragma unroll
    for (int mt=0;mt<4;mt++){
      #pragma unroll
      for (int nt=0;nt<2;nt++){
        int col = n0 + wn*32 + nt*16 + lr;
        #pragma unroll
        for (int e=0;e<4;e++){
          int row = o0 + wm*64 + mt*16 + kg*4 + e;
          float bv = BCOL ? bias[col] : bias[row];
          float v = acc[mt][nt][e] + bv;
          if (RELU) v = fmaxf(v, 0.f);
          outp[(size_t)z*sOut + (size_t)row*N + col] = v;
        }
      }
    }
  } else {
    // relu + max over this block's 64 cols, per row
    #pragma unroll
    for (int mt=0;mt<4;mt++){
      #pragma unroll
      for (int e=0;e<4;e++){
        int row = o0 + wm*64 + mt*16 + kg*4 + e;
        float bv = bias[row];
        float m = fmaxf(fmaxf(acc[mt][0][e]+bv, 0.f), fmaxf(acc[mt][1][e]+bv, 0.f));
        m = fmaxf(m, __shfl_xor(m, 1, 64));
        m = fmaxf(m, __shfl_xor(m, 2, 64));
        m = fmaxf(m, __shfl_xor(m, 4, 64));
        m = fmaxf(m, __shfl_xor(m, 8, 64));
        if (lr == 0) red[wn][wm*64 + mt*16 + kg*4 + e] = m;
      }
    }
    __syncthreads();
    if (t < 128){
      float m = fmaxf(red[0][t], red[1][t]);
      pmaxp[((size_t)z*M + o0 + t)*gridDim.x + blockIdx.x] = m;
    }
  }
}

__global__ void k_xmax(const float* __restrict__ pmax, float* __restrict__ xmax){
  int id = blockIdx.x*256 + threadIdx.x;
  if (id >= BB*1024) return;
  float m = pmax[(size_t)id*32];
  for (int k=1;k<32;k++) m = fmaxf(m, pmax[(size_t)id*32+k]);
  xmax[id] = m;
}

/* ---------------- JAX threefry PRNG permutation ---------------- */

#define TF2BODY \
  unsigned ks2 = 0x1BD11BDAu ^ k0 ^ k1; \
  unsigned a = x0 + k0, b = x1 + k1; \
  { \
  a += b; b = (b<<13)|(b>>19); b ^= a; \
  a += b; b = (b<<15)|(b>>17); b ^= a; \
  a += b; b = (b<<26)|(b>>6);  b ^= a; \
  a += b; b = (b<<6) |(b>>26); b ^= a;  a += k1;  b += ks2 + 1u; \
  a += b; b = (b<<17)|(b>>15); b ^= a; \
  a += b; b = (b<<29)|(b>>3);  b ^= a; \
  a += b; b = (b<<16)|(b>>16); b ^= a; \
  a += b; b = (b<<24)|(b>>8);  b ^= a;  a += ks2; b += k0  + 2u; \
  a += b; b = (b<<13)|(b>>19); b ^= a; \
  a += b; b = (b<<15)|(b>>17); b ^= a; \
  a += b; b = (b<<26)|(b>>6);  b ^= a; \
  a += b; b = (b<<6) |(b>>26); b ^= a;  a += k0;  b += k1  + 3u; \
  a += b; b = (b<<17)|(b>>15); b ^= a; \
  a += b; b = (b<<29)|(b>>3);  b ^= a; \
  a += b; b = (b<<16)|(b>>16); b ^= a; \
  a += b; b = (b<<24)|(b>>8);  b ^= a;  a += k1;  b += ks2 + 4u; \
  a += b; b = (b<<13)|(b>>19); b ^= a; \
  a += b; b = (b<<15)|(b>>17); b ^= a; \
  a += b; b = (b<<26)|(b>>6);  b ^= a; \
  a += b; b = (b<<6) |(b>>26); b ^= a;  a += ks2; b += k0  + 5u; \
  } \
  o0 = a; o1 = b;

__device__ __forceinline__ void tf2(unsigned k0, unsigned k1, unsigned x0, unsigned x1,
                                    unsigned &o0, unsigned &o1){ TF2BODY }
static void tf2h(unsigned k0, unsigned k1, unsigned x0, unsigned x1,
                 unsigned &o0, unsigned &o1){ TF2BODY }

__global__ void k_permkeys(int n, unsigned sk0, unsigned sk1, unsigned* __restrict__ keys){
  int i = blockIdx.x*256 + threadIdx.x;
  if (i < n){ unsigned a,b2; tf2(sk0, sk1, 0u, (unsigned)i, a, b2); keys[i] = a ^ b2; }
}

__global__ void k_permrank(int n, const unsigned* __restrict__ keys,
                           const int* __restrict__ vin, int* __restrict__ vout){
  int i = blockIdx.x*256 + threadIdx.x;
  if (i >= n) return;
  unsigned ki = keys[i];
  int rank = 0;
  for (int j=0;j<n;j++){
    unsigned kj = keys[j];
    rank += (kj < ki) || (kj == ki && j < i);
  }
  vout[rank] = vin ? vin[i] : i;
}

/* ---------------- graph branch ---------------- */

__global__ void k_transpose(const float* __restrict__ xyz, float* __restrict__ verts){
  int id = blockIdx.x*256 + threadIdx.x;
  if (id >= BB*NN*3) return;
  int c = id % 3, v = (id/3) % NN, b = id/(3*NN);
  verts[id] = xyz[(size_t)(b*3+c)*NN + v];
}

template<int CPL, int KSEL>
__global__ __launch_bounds__(256,4) void k_knn_g(const float* __restrict__ vbcs,
                                                 const int* __restrict__ qmap, int numQ,
                                                 int* __restrict__ out){
  constexpr int V = CPL*64;
  constexpr int GS = (CPL < 8) ? CPL : 8;
  constexpr int NG = CPL/GS;
  constexpr int GSH = (GS==8)?3:((GS==4)?2:((GS==2)?1:0));
  int t = threadIdx.x, wid = t>>6, lane = t&63;
  int b = blockIdx.y;
  int q = blockIdx.x*4 + wid;
  if (q >= numQ) return;
  const float* vx = vbcs + (size_t)b*3*V;
  const float* vy = vx + V;
  const float* vz = vy + V;
  int qv = qmap ? qmap[q] : q;
  float qx = vx[qv], qy = vy[qv], qz = vz[qv];
  float qq = qx*qx + qy*qy + qz*qz;
  unsigned long long key[CPL];
  #pragma unroll
  for (int i=0;i<CPL;i++){
    int c = lane + i*64;
    float wx=vx[c], wy=vy[c], wz=vz[c];
    float inner = qx*wx + qy*wy + qz*wz;
    float ww = wx*wx + wy*wy + wz*wz;
    float d = qq - 2.f*inner + ww;
    unsigned db = __float_as_uint(d);
    db = (db & 0x80000000u) ? ~db : (db | 0x80000000u);
    key[i] = ((unsigned long long)db << 32) | (unsigned)c;
  }
  unsigned long long g[NG];
  #pragma unroll
  for (int gg=0; gg<NG; gg++){
    unsigned long long m = key[gg*GS];
    #pragma unroll
    for (int j=1;j<GS;j++){ unsigned long long kk2 = key[gg*GS+j]; m = (kk2<m)?kk2:m; }
    g[gg] = m;
  }
  unsigned long long lb = g[0];
  #pragma unroll
  for (int gg=1;gg<NG;gg++) lb = (g[gg]<lb)?g[gg]:lb;

  int* orow = out + ((size_t)b*numQ + q)*KSEL;
  unsigned long long last = 0ull;
  for (int r=0; r<=KSEL; r++){
    unsigned long long best = lb;
    #pragma unroll
    for (int off=32; off>0; off>>=1){
      unsigned long long o = __shfl_xor(best, off, 64);
      best = (o < best) ? o : best;
    }
    int c = (int)(best & 0xffffffffull);
    if (r>0 && lane==0) orow[r-1] = c;
    last = best;
    if ((c & 63) == lane){
      int gi = c >> (6 + GSH);
      #pragma unroll
      for (int gg=0; gg<NG; gg++){
        if (gg == gi){
          unsigned long long m = ~0ull;
          #pragma unroll
          for (int j=0;j<GS;j++){
            unsigned long long kk2 = key[gg*GS+j];
            unsigned long long qk = (kk2 > last) ? kk2 : ~0ull;
            m = (qk<m)?qk:m;
          }
          g[gg] = m;
        }
      }
      unsigned long long nb2 = g[0];
      #pragma unroll
      for (int gg=1;gg<NG;gg++) nb2 = (g[gg]<nb2)?g[gg]:nb2;
      lb = nb2;
    }
  }
}

__global__ void k_dirs(const float* __restrict__ verts, int V, const int* __restrict__ idx,
                       float* __restrict__ dirs, int total){
  int id = blockIdx.x*256 + threadIdx.x;
  if (id >= total) return;
  int v = (id/20) % V, b = id/(20*V);
  const float* vb = verts + (size_t)b*V*3;
  int nb = idx[id];
  float dx = vb[nb*3+0]-vb[v*3+0];
  float dy = vb[nb*3+1]-vb[v*3+1];
  float dz = vb[nb*3+2]-vb[v*3+2];
  float s = 1.f / fmaxf(sqrtf(dx*dx+dy*dy+dz*dz), 1e-12f);
  dirs[(size_t)id*3+0]=dx*s; dirs[(size_t)id*3+1]=dy*s; dirs[(size_t)id*3+2]=dz*s;
}

__global__ void k_surf(const float* __restrict__ dirs, const float* __restrict__ dir0,
                       float* __restrict__ fm0, int V){
  int id = blockIdx.x*256 + threadIdx.x;
  if (id >= BB*V*32) return;
  int k = id & 31; int vv = (id>>5) % V; int b = id/(32*V);
  float nx=dir0[k], ny=dir0[32+k], nz=dir0[64+k];
  float s = 1.f/fmaxf(sqrtf(nx*nx+ny*ny+nz*nz), 1e-12f);
  nx*=s; ny*=s; nz*=s;
  const float* dd = dirs + (size_t)(b*V+vv)*60;
  float m = 0.f;
  for (int n=0;n<20;n++){
    float th = dd[n*3]*nx + dd[n*3+1]*ny + dd[n*3+2]*nz;
    m = fmaxf(m, fmaxf(th, 0.f));
  }
  fm0[(size_t)(b*V+vv)*32 + k] = m;
}

// out = [relu]( feat[:, :OC] + max_n( relu(dirs . ndir_col) * feat[nb, OC: ] ) )
__global__ void k_comb(const float* __restrict__ feat, const int* __restrict__ idx,
                       const float* __restrict__ dirs, const float* __restrict__ dw,
                       float* __restrict__ outp, int V, int OC, int relu_flag){
  int id = blockIdx.x*256 + threadIdx.x;
  if (id >= BB*V*OC) return;
  int oc = id % OC, v = (id/OC) % V, b = id/(OC*V);
  float wx=dw[oc], wy=dw[OC+oc], wz=dw[2*OC+oc];
  float s = 1.f/fmaxf(sqrtf(wx*wx+wy*wy+wz*wz), 1e-12f);
  wx*=s; wy*=s; wz*=s;
  size_t row = (size_t)b*V + v;
  const int* ir = idx + row*20;
  const float* dd = dirs + row*60;
  float center = feat[row*2*OC + oc];
  float m = -INFINITY;
  for (int n=0;n<20;n++){
    int nb = ir[n];
    float th = dd[n*3]*wx + dd[n*3+1]*wy + dd[n*3+2]*wz;
    th = fmaxf(th, 0.f);
    float sup = feat[((size_t)b*V + nb)*2*OC + OC + oc];
    m = fmaxf(m, th*sup);
  }
  float rv = center + m;
  outp[row*OC + oc] = relu_flag ? fmaxf(rv, 0.f) : rv;
}

__global__ void k_pool(const float* __restrict__ fm, const int* __restrict__ idx4,
                       float* __restrict__ outp, int V, int C, int numS){
  int id = blockIdx.x*256 + threadIdx.x;
  if (id >= BB*numS*C) return;
  int c = id % C, sI = (id/C) % numS, b = id/(C*numS);
  const int* ir = idx4 + ((size_t)b*numS + sI)*4;
  float m = -INFINITY;
  for (int n=0;n<4;n++) m = fmaxf(m, fm[((size_t)b*V + ir[n])*C + c]);
  outp[((size_t)b*numS + sI)*C + c] = m;
}

__global__ void k_vgather(const float* __restrict__ vin, const int* __restrict__ perm,
                          float* __restrict__ vout, float* __restrict__ vbcs,
                          int V, int numS){
  int id = blockIdx.x*256 + threadIdx.x;
  if (id >= BB*numS*3) return;
  int c = id % 3, sI = (id/3) % numS, b = id/(3*numS);
  float val = vin[((size_t)b*V + perm[sI])*3 + c];
  vout[id] = val;
  vbcs[((size_t)b*3 + c)*numS + sI] = val;
}

__global__ void k_colmax(const float* __restrict__ x, float* __restrict__ o, int Vr, int C){
  int id = blockIdx.x*256 + threadIdx.x;
  if (id >= BB*C) return;
  int c = id % C, b = id / C;
  float m = -INFINITY;
  for (int v=0; v<Vr; v++) m = fmaxf(m, x[(size_t)(b*Vr+v)*C + c]);
  o[id] = m;
}

/* ---------------- FC head (wave-per-output dot products) ---------------- */

__global__ __launch_bounds__(256) void k_emb2(const float* __restrict__ xmax, const float* __restrict__ fg,
                                              const float* __restrict__ fcw, const float* __restrict__ fcb,
                                              float* __restrict__ outp){
  int gid = blockIdx.x*4 + (threadIdx.x>>6);
  int lane = threadIdx.x & 63;
  if (gid >= BB*512) return;
  int e = gid & 511, b = gid >> 9;
  const float* wr = fcw + (size_t)e*2048;
  const float* xb = xmax + b*1024;
  const float* gb = fg + b*1024;
  float acc = 0.f;
  for (int k=lane; k<1024; k+=64)
    acc += xb[k]*wr[k] + gb[k]*wr[1024+k];
  #pragma unroll
  for (int off=32; off>0; off>>=1) acc += __shfl_xor(acc, off, 64);
  if (lane==0) outp[gid] = acc + fcb[e];
}

__global__ __launch_bounds__(256) void k_h2(const float* __restrict__ xmax, const float* __restrict__ fg,
                                            const float* __restrict__ clw1, const float* __restrict__ clb1,
                                            const float* __restrict__ gamma, const float* __restrict__ beta,
                                            float* __restrict__ h){
  int gid = blockIdx.x*4 + (threadIdx.x>>6);
  int lane = threadIdx.x & 63;
  if (gid >= BB*512) return;
  int j = gid & 511, b = gid >> 9;
  const float* wr = clw1 + (size_t)j*2048;
  const float* xb = xmax + b*1024;
  const float* gb = fg + b*1024;
  float acc = 0.f;
  for (int k=lane; k<1024; k+=64)
    acc += xb[k]*wr[k] + gb[k]*wr[1024+k];
  #pragma unroll
  for (int off=32; off>0; off>>=1) acc += __shfl_xor(acc, off, 64);
  if (lane==0){
    const float inv_s = 1.0f / sqrtf(1.0f + 1e-5f);
    float v = (acc + clb1[j]) * inv_s * gamma[j] + beta[j];
    h[gid] = fmaxf(v, 0.f);
  }
}

__global__ __launch_bounds__(256) void k_pred2(const float* __restrict__ h, const float* __restrict__ clw2,
                                               const float* __restrict__ clb2, float* __restrict__ outp){
  int gid = blockIdx.x*4 + (threadIdx.x>>6);
  int lane = threadIdx.x & 63;
  if (gid >= BB*6) return;
  int o = gid % 6, b = gid / 6;
  const float* hb = h + b*512;
  const float* wr = clw2 + o*512;
  float acc = 0.f;
  for (int k=lane; k<512; k+=64) acc += hb[k]*wr[k];
  #pragma unroll
  for (int off=32; off>0; off>>=1) acc += __shfl_xor(acc, off, 64);
  if (lane==0) outp[BB*512 + gid] = acc + clb2[o];
}

/* ---------------- launch ---------------- */

static inline int cdiv(long long a, int b){ return (int)((a + b - 1)/b); }

extern "C" void kernel_launch(void* const* d_in, const int* in_sizes, int n_in,
                              void* d_out, int out_size, void* d_ws, size_t ws_size,
                              hipStream_t stream){
  float* out = (float*)d_out;
  if (n_in != 30 || in_sizes[0] != BB*3*NN || out_size != BB*512 + BB*6){
    k_sentinel<<<cdiv(out_size,256),256,0,stream>>>(out, out_size, 2000.0f);
    return;
  }
  const float* xyz  = (const float*)d_in[0];
  const float* w1   = (const float*)d_in[1];
  const float* b1   = (const float*)d_in[2];
  const float* w2   = (const float*)d_in[3];
  const float* b2   = (const float*)d_in[4];
  const float* w3   = (const float*)d_in[5];
  const float* b3   = (const float*)d_in[6];
  const float* w4   = (const float*)d_in[7];
  const float* b4   = (const float*)d_in[8];
  const float* fcw  = (const float*)d_in[9];
  const float* fcb  = (const float*)d_in[10];
  const float* dir0 = (const float*)d_in[11];
  const float* wc1  = (const float*)d_in[12];
  const float* bc1  = (const float*)d_in[13];
  const float* dir1 = (const float*)d_in[14];
  const float* wc2  = (const float*)d_in[15];
  const float* bc2  = (const float*)d_in[16];
  const float* dir2 = (const float*)d_in[17];
  const float* wc3  = (const float*)d_in[18];
  const float* bc3  = (const float*)d_in[19];
  const float* dir3 = (const float*)d_in[20];
  const float* wc4  = (const float*)d_in[21];
  const float* bc4  = (const float*)d_in[22];
  const float* dir4 = (const float*)d_in[23];
  const float* clw1 = (const float*)d_in[24];
  const float* clb1 = (const float*)d_in[25];
  const float* gma  = (const float*)d_in[26];
  const float* bta  = (const float*)d_in[27];
  const float* clw2 = (const float*)d_in[28];
  const float* clb2 = (const float*)d_in[29];

  char* w = (char*)d_ws;
  size_t off = 0;
  auto A = [&](size_t bytes){ size_t r = off; off += (bytes + 255) & ~(size_t)255; return r; };
  const size_t oXMAX = A((size_t)BB*1024*4);
  const size_t oFG   = A((size_t)BB*1024*4);
  const size_t oGF   = A((size_t)BB*128*4);
  const size_t oH    = A((size_t)BB*512*4);
  const size_t oP2048= A(2048*4);
  const size_t oP512 = A(512*4);
  const size_t oPKEY = A(2048*4);
  const size_t oPA   = A(2048*4);
  const size_t oPMAX = A((size_t)BB*1024*32*4);
  const size_t oV0   = A((size_t)BB*2048*3*4);
  const size_t oV1   = A((size_t)BB*512*3*4);
  const size_t oV2   = A((size_t)BB*128*3*4);
  const size_t oV1S  = A((size_t)BB*3*512*4);
  const size_t oV2S  = A((size_t)BB*3*128*4);
  const size_t oIDX0 = A((size_t)BB*2048*20*4);
  const size_t oDIR0 = A((size_t)BB*2048*20*3*4);
  const size_t oFM0  = A((size_t)BB*2048*32*4);
  const size_t oFM1  = A((size_t)BB*2048*64*4);
  const size_t oI40  = A((size_t)BB*512*4*4);
  const size_t oFM1P = A((size_t)BB*512*64*4);
  const size_t oIDX1 = A((size_t)BB*512*20*4);
  const size_t oDIR1 = A((size_t)BB*512*20*3*4);
  const size_t oFM2  = A((size_t)BB*512*128*4);
  const size_t oFM3  = A((size_t)BB*512*256*4);
  const size_t oI41  = A((size_t)BB*128*4*4);
  const size_t oFM3P = A((size_t)BB*128*256*4);
  const size_t oIDX2 = A((size_t)BB*128*20*4);
  const size_t oDIR2 = A((size_t)BB*128*20*3*4);
  const size_t oFM4  = A((size_t)BB*128*1024*4);
  const size_t oBIGA = A((size_t)BB*256*NN*4);   // x1, then x3
  const size_t oBIGB = A((size_t)BB*128*NN*4);   // x2, then feat1..feat4
  if (off > ws_size){
    k_sentinel<<<cdiv(out_size,256),256,0,stream>>>(out, out_size, 1000.0f);
    return;
  }
  float* xmax = (float*)(w+oXMAX); float* fg = (float*)(w+oFG);
  float* gf = (float*)(w+oGF);     float* hbuf = (float*)(w+oH);
  int* p2048 = (int*)(w+oP2048);   int* p512 = (int*)(w+oP512);
  unsigned* pkeys = (unsigned*)(w+oPKEY); int* pa = (int*)(w+oPA);
  float* pmax = (float*)(w+oPMAX);
  float* v0 = (float*)(w+oV0); float* v1 = (float*)(w+oV1); float* v2 = (float*)(w+oV2);
  float* v1s = (float*)(w+oV1S); float* v2s = (float*)(w+oV2S);
  int* idx0 = (int*)(w+oIDX0); int* idx1 = (int*)(w+oIDX1); int* idx2 = (int*)(w+oIDX2);
  int* i40 = (int*)(w+oI40);   int* i41 = (int*)(w+oI41);
  float* d0 = (float*)(w+oDIR0); float* d1 = (float*)(w+oDIR1); float* d2 = (float*)(w+oDIR2);
  float* fm0 = (float*)(w+oFM0); float* fm1 = (float*)(w+oFM1); float* fm1p = (float*)(w+oFM1P);
  float* fm2 = (float*)(w+oFM2); float* fm3 = (float*)(w+oFM3); float* fm3p = (float*)(w+oFM3P);
  float* fm4 = (float*)(w+oFM4);
  float* x1 = (float*)(w+oBIGA); float* x3 = (float*)(w+oBIGA);
  float* x2 = (float*)(w+oBIGB); float* feat = (float*)(w+oBIGB);

  // MLP branch (split-bf16 MFMA GEMMs)
  k_mlp1<<<cdiv((long long)BB*64*NN,256),256,0,stream>>>(xyz, w1, b1, x1);
  k_mgemm<0,1,0><<<dim3(32,1,BB),256,0,stream>>>(w2, x1, nullptr, b2, x2, nullptr,
      64, 64, 2048, (size_t)64*2048, (size_t)128*2048, 128);
  k_rowmax<<<BB*128,256,0,stream>>>(x2, gf, NN);
  k_mgemm<0,1,0><<<dim3(32,2,BB),256,0,stream>>>(w3, x2, gf, b3, x3, nullptr,
      256, 128, 2048, (size_t)128*2048, (size_t)256*2048, 256);
  k_mgemm<1,1,0><<<dim3(32,8,BB),256,0,stream>>>(w4, x3, nullptr, b4, nullptr, pmax,
      256, 256, 2048, (size_t)256*2048, 0, 1024);
  k_xmax<<<cdiv(BB*1024,256),256,0,stream>>>(pmax, xmax);

  // permutations: host-computed threefry round keys
  {
    unsigned ck0=0u, ck1=1u, nk0,nk1, s00,s01, s10,s11, sc0,sc1;
    tf2h(ck0,ck1, 0u,0u, nk0,nk1);
    tf2h(ck0,ck1, 0u,1u, s00,s01);
    tf2h(nk0,nk1, 0u,1u, s10,s11);
    tf2h(0u,2u,  0u,1u, sc0,sc1);
    k_permkeys<<<8,256,0,stream>>>(2048, s00, s01, pkeys);
    k_permrank<<<8,256,0,stream>>>(2048, pkeys, nullptr, pa);
    k_permkeys<<<8,256,0,stream>>>(2048, s10, s11, pkeys);
    k_permrank<<<8,256,0,stream>>>(2048, pkeys, pa, p2048);
    k_permkeys<<<2,256,0,stream>>>(512, sc0, sc1, pkeys);
    k_permrank<<<2,256,0,stream>>>(512, pkeys, nullptr, p512);
  }

  // graph branch: stage 0 (V=2048)
  k_transpose<<<cdiv((long long)BB*NN*3,256),256,0,stream>>>(xyz, v0);
  k_knn_g<32,20><<<dim3(512,BB),256,0,stream>>>(xyz, nullptr, 2048, idx0);
  k_dirs<<<cdiv((long long)BB*2048*20,256),256,0,stream>>>(v0, 2048, idx0, d0, BB*2048*20);
  k_surf<<<cdiv((long long)BB*2048*32,256),256,0,stream>>>(d0, dir0, fm0, 2048);
  k_mgemm<0,0,1><<<dim3(2,256,1),256,0,stream>>>(fm0, wc1, nullptr, bc1, feat, nullptr,
      32, 32, 128, 0, 0, BB*2048);
  k_comb<<<cdiv((long long)BB*2048*64,256),256,0,stream>>>(feat, idx0, d0, dir1, fm1, 2048, 64, 1);
  // pool 1
  k_knn_g<32,4><<<dim3(128,BB),256,0,stream>>>(xyz, p2048, 512, i40);
  k_pool<<<cdiv((long long)BB*512*64,256),256,0,stream>>>(fm1, i40, fm1p, 2048, 64, 512);
  k_vgather<<<cdiv((long long)BB*512*3,256),256,0,stream>>>(v0, p2048, v1, v1s, 2048, 512);
  // stage 1 (V=512)
  k_knn_g<8,20><<<dim3(128,BB),256,0,stream>>>(v1s, nullptr, 512, idx1);
  k_dirs<<<cdiv((long long)BB*512*20,256),256,0,stream>>>(v1, 512, idx1, d1, BB*512*20);
  k_mgemm<0,0,1><<<dim3(4,64,1),256,0,stream>>>(fm1p, wc2, nullptr, bc2, feat, nullptr,
      64, 64, 256, 0, 0, BB*512);
  k_comb<<<cdiv((long long)BB*512*128,256),256,0,stream>>>(feat, idx1, d1, dir2, fm2, 512, 128, 1);
  k_mgemm<0,0,1><<<dim3(8,64,1),256,0,stream>>>(fm2, wc3, nullptr, bc3, feat, nullptr,
      128, 128, 512, 0, 0, BB*512);
  k_comb<<<cdiv((long long)BB*512*256,256),256,0,stream>>>(feat, idx1, d1, dir3, fm3, 512, 256, 1);
  // pool 2
  k_knn_g<8,4><<<dim3(32,BB),256,0,stream>>>(v1s, p512, 128, i41);
  k_pool<<<cdiv((long long)BB*128*256,256),256,0,stream>>>(fm3, i41, fm3p, 512, 256, 128);
  k_vgather<<<cdiv((long long)BB*128*3,256),256,0,stream>>>(v1, p512, v2, v2s, 512, 128);
  // stage 2 (V=128)
  k_knn_g<2,20><<<dim3(32,BB),256,0,stream>>>(v2s, nullptr, 128, idx2);
  k_dirs<<<cdiv((long long)BB*128*20,256),256,0,stream>>>(v2, 128, idx2, d2, BB*128*20);
  k_mgemm<0,0,1><<<dim3(32,16,1),256,0,stream>>>(fm3p, wc4, nullptr, bc4, feat, nullptr,
      256, 256, 2048, 0, 0, BB*128);
  k_comb<<<cdiv((long long)BB*128*1024,256),256,0,stream>>>(feat, idx2, d2, dir4, fm4, 128, 1024, 0);
  k_colmax<<<cdiv(BB*1024,256),256,0,stream>>>(fm4, fg, 128, 1024);

  // FC head
  k_emb2<<<cdiv(BB*512,4),256,0,stream>>>(xmax, fg, fcw, fcb, out);
  k_h2<<<cdiv(BB*512,4),256,0,stream>>>(xmax, fg, clw1, clb1, gma, bta, hbuf);
  k_pred2<<<cdiv(BB*6,4),256,0,stream>>>(hbuf, clw2, clb2, out);
}

// Round 7
// 777.333 us; speedup vs baseline: 3.1692x; 1.3024x over previous
//
#include <hip/hip_runtime.h>
#include <hip/hip_bf16.h>
#include <math.h>

#define BB 16
#define NN 2048

typedef __attribute__((ext_vector_type(8))) short s8v;
typedef __attribute__((ext_vector_type(4))) float f4v;

__global__ void k_sentinel(float* o, int n, float v){
  int i = blockIdx.x*256 + threadIdx.x;
  if (i < n) o[i] = v;
}

__device__ __forceinline__ ushort f2bf(float x){
  unsigned u = __float_as_uint(x);
  unsigned r = u + 0x7FFFu + ((u>>16)&1u);
  return (ushort)(r>>16);
}
__device__ __forceinline__ void splitbf(float v, ushort &h, ushort &l){
  h = f2bf(v);
  float hf = __uint_as_float((unsigned)h<<16);
  l = f2bf(v-hf);
}

/* ---------------- weight pre-split ---------------- */

__global__ void k_wsrm(const float* __restrict__ src, ushort* __restrict__ dh,
                       ushort* __restrict__ dl, int total){
  int id = blockIdx.x*256 + threadIdx.x;
  if (id >= total) return;
  ushort h,l; splitbf(src[id], h, l);
  dh[id]=h; dl[id]=l;
}

// [K][C] -> transposed planes [C][K]
__global__ void k_wstr(const float* __restrict__ src, ushort* __restrict__ dh,
                       ushort* __restrict__ dl, int K, int C){
  int id = blockIdx.x*256 + threadIdx.x;
  if (id >= K*C) return;
  int c = id % C, k = id / C;
  ushort h,l; splitbf(src[id], h, l);
  dh[(size_t)c*K + k]=h; dl[(size_t)c*K + k]=l;
}

/* ---------------- MLP branch ---------------- */

// x1 = relu(w1 @ xyz + b1), written directly as transposed split planes [b][n][64]
__global__ void k_mlp1s(const float* __restrict__ xyz, const float* __restrict__ w1,
                        const float* __restrict__ b1, ushort* __restrict__ xh,
                        ushort* __restrict__ xl){
  int id = blockIdx.x*256 + threadIdx.x;
  if (id >= BB*NN*64) return;
  int o = id & 63, n = (id>>6) & (NN-1), b = id>>17;
  float acc = b1[o];
  #pragma unroll
  for (int c=0;c<3;c++)
    acc += w1[o*3+c] * xyz[(size_t)(b*3+c)*NN + n];
  acc = fmaxf(acc, 0.f);
  ushort h,l; splitbf(acc, h, l);
  xh[id]=h; xl[id]=l;
}

__global__ __launch_bounds__(256) void k_rowmax(const float* __restrict__ x, float* __restrict__ o,
                                                ushort* __restrict__ gh, ushort* __restrict__ gl, int cols){
  __shared__ float sm[256];
  int row = blockIdx.x, t = threadIdx.x;
  const float* xr = x + (size_t)row*cols;
  float m = -INFINITY;
  for (int c=t;c<cols;c+=256) m = fmaxf(m, xr[c]);
  sm[t]=m; __syncthreads();
  for (int s=128;s>0;s>>=1){ if (t<s) sm[t]=fmaxf(sm[t], sm[t+s]); __syncthreads(); }
  if (!t){
    o[row]=sm[0];
    ushort h,l; splitbf(sm[0], h, l);
    gh[row]=h; gl[row]=l;
  }
}

/* ---------------- pre-split bf16 MFMA GEMM ----------------
   out[z][row][col] = epi( sum_k A[row][k]*B[z][k][col] + bias )
   A planes: [M][K] ushort hi/lo. B planes: transposed [z][N][Kb] hi/lo;
   rows k>=ksplit read gf planes [z][K-ksplit] (broadcast over cols).
   EPI: 0 = f32 out; 1 = relu+colmax -> pmax; 2 = f32 + splitT planes;
        3 = splitT planes only. splitT layout: [z][col][M].
   Block 128Mx64N, 4 waves (64x32 each), K-chunk 32, mfma_f32_16x16x32_bf16,
   3-pass split: Ah*Bh + Ah*Bl + Al*Bh. */
template<int EPI, int RELU, int BCOL>
__global__ __launch_bounds__(256) void k_bgemm(
    const ushort* __restrict__ Ahg, const ushort* __restrict__ Alg,
    const ushort* __restrict__ Bhg, const ushort* __restrict__ Blg,
    const ushort* __restrict__ gfh, const ushort* __restrict__ gfl,
    const float* __restrict__ bias,
    float* __restrict__ outp, float* __restrict__ pmaxp,
    ushort* __restrict__ oth, ushort* __restrict__ otl,
    int K, int ksplit, int Kb, int N, size_t sBT, size_t sOut, int M)
{
  __shared__ ushort Ah[128][40], Al[128][40];
  __shared__ ushort Bh[64][40],  Bl[64][40];
  __shared__ float red[2][128];
  int t = threadIdx.x, z = blockIdx.z;
  int o0 = blockIdx.y*128, n0 = blockIdx.x*64;
  int wid = t>>6, lane = t&63;
  int wm = wid>>1, wn = wid&1;
  int lr = lane&15, kg = lane>>4;

  f4v acc[4][2];
  #pragma unroll
  for (int i=0;i<4;i++)
    #pragma unroll
    for (int j=0;j<2;j++) acc[i][j] = (f4v){0.f,0.f,0.f,0.f};

  for (int k0=0; k0<K; k0+=32){
    __syncthreads();
    #pragma unroll
    for (int i=0;i<2;i++){
      int j = i*256+t, oo = j>>2, k8 = (j&3)*8;
      size_t sp = (size_t)(o0+oo)*K + k0 + k8;
      *(s8v*)&Ah[oo][k8] = *(const s8v*)(Ahg+sp);
      *(s8v*)&Al[oo][k8] = *(const s8v*)(Alg+sp);
    }
    {
      int nn = t>>2, k8 = (t&3)*8, gk = k0+k8;
      const ushort *sh, *sl;
      if (gk < ksplit){
        size_t sp = (size_t)z*sBT + (size_t)(n0+nn)*Kb + gk;
        sh = Bhg+sp; sl = Blg+sp;
      } else {
        size_t sp = (size_t)z*(K-ksplit) + (gk-ksplit);
        sh = gfh+sp; sl = gfl+sp;
      }
      *(s8v*)&Bh[nn][k8] = *(const s8v*)sh;
      *(s8v*)&Bl[nn][k8] = *(const s8v*)sl;
    }
    __syncthreads();

    s8v ah[4], al[4], bh[2], bl[2];
    #pragma unroll
    for (int mt=0;mt<4;mt++){
      int row = wm*64 + mt*16 + lr;
      ah[mt] = *(const s8v*)&Ah[row][kg*8];
      al[mt] = *(const s8v*)&Al[row][kg*8];
    }
    #pragma unroll
    for (int nt=0;nt<2;nt++){
      int col = wn*32 + nt*16 + lr;
      bh[nt] = *(const s8v*)&Bh[col][kg*8];
      bl[nt] = *(const s8v*)&Bl[col][kg*8];
    }
    #pragma unroll
    for (int mt=0;mt<4;mt++)
      #pragma unroll
      for (int nt=0;nt<2;nt++){
        acc[mt][nt] = __builtin_amdgcn_mfma_f32_16x16x32_bf16(ah[mt], bh[nt], acc[mt][nt], 0,0,0);
        acc[mt][nt] = __builtin_amdgcn_mfma_f32_16x16x32_bf16(ah[mt], bl[nt], acc[mt][nt], 0,0,0);
        acc[mt][nt] = __builtin_amdgcn_mfma_f32_16x16x32_bf16(al[mt], bh[nt], acc[mt][nt], 0,0,0);
      }
  }

  if (EPI == 1){
    #pragma unroll
    for (int mt=0;mt<4;mt++){
      #pragma unroll
      for (int e=0;e<4;e++){
        int row = o0 + wm*64 + mt*16 + kg*4 + e;
        float bv = bias[row];
        float m = fmaxf(fmaxf(acc[mt][0][e]+bv, 0.f), fmaxf(acc[mt][1][e]+bv, 0.f));
        m = fmaxf(m, __shfl_xor(m, 1, 64));
        m = fmaxf(m, __shfl_xor(m, 2, 64));
        m = fmaxf(m, __shfl_xor(m, 4, 64));
        m = fmaxf(m, __shfl_xor(m, 8, 64));
        if (lr == 0) red[wn][wm*64 + mt*16 + kg*4 + e] = m;
      }
    }
    __syncthreads();
    if (t < 128){
      float m = fmaxf(red[0][t], red[1][t]);
      pmaxp[((size_t)z*M + o0 + t)*gridDim.x + blockIdx.x] = m;
    }
  } else {
    #pragma unroll
    for (int mt=0;mt<4;mt++){
      #pragma unroll
      for (int nt=0;nt<2;nt++){
        int col = n0 + wn*32 + nt*16 + lr;
        #pragma unroll
        for (int e=0;e<4;e++){
          int row = o0 + wm*64 + mt*16 + kg*4 + e;
          float bv = BCOL ? bias[col] : bias[row];
          float v = acc[mt][nt][e] + bv;
          if (RELU) v = fmaxf(v, 0.f);
          if (EPI == 0 || EPI == 2)
            outp[(size_t)z*sOut + (size_t)row*N + col] = v;
          if (EPI >= 2){
            ushort h,l; splitbf(v, h, l);
            size_t p = ((size_t)z*N + col)*(size_t)M + row;
            oth[p]=h; otl[p]=l;
          }
        }
      }
    }
  }
}

__global__ void k_xmax(const float* __restrict__ pmax, float* __restrict__ xmax){
  int id = blockIdx.x*256 + threadIdx.x;
  if (id >= BB*1024) return;
  float m = pmax[(size_t)id*32];
  for (int k=1;k<32;k++) m = fmaxf(m, pmax[(size_t)id*32+k]);
  xmax[id] = m;
}

/* ---------------- JAX threefry PRNG permutation ---------------- */

#define TF2BODY \
  unsigned ks2 = 0x1BD11BDAu ^ k0 ^ k1; \
  unsigned a = x0 + k0, b = x1 + k1; \
  { \
  a += b; b = (b<<13)|(b>>19); b ^= a; \
  a += b; b = (b<<15)|(b>>17); b ^= a; \
  a += b; b = (b<<26)|(b>>6);  b ^= a; \
  a += b; b = (b<<6) |(b>>26); b ^= a;  a += k1;  b += ks2 + 1u; \
  a += b; b = (b<<17)|(b>>15); b ^= a; \
  a += b; b = (b<<29)|(b>>3);  b ^= a; \
  a += b; b = (b<<16)|(b>>16); b ^= a; \
  a += b; b = (b<<24)|(b>>8);  b ^= a;  a += ks2; b += k0  + 2u; \
  a += b; b = (b<<13)|(b>>19); b ^= a; \
  a += b; b = (b<<15)|(b>>17); b ^= a; \
  a += b; b = (b<<26)|(b>>6);  b ^= a; \
  a += b; b = (b<<6) |(b>>26); b ^= a;  a += k0;  b += k1  + 3u; \
  a += b; b = (b<<17)|(b>>15); b ^= a; \
  a += b; b = (b<<29)|(b>>3);  b ^= a; \
  a += b; b = (b<<16)|(b>>16); b ^= a; \
  a += b; b = (b<<24)|(b>>8);  b ^= a;  a += k1;  b += ks2 + 4u; \
  a += b; b = (b<<13)|(b>>19); b ^= a; \
  a += b; b = (b<<15)|(b>>17); b ^= a; \
  a += b; b = (b<<26)|(b>>6);  b ^= a; \
  a += b; b = (b<<6) |(b>>26); b ^= a;  a += ks2; b += k0  + 5u; \
  } \
  o0 = a; o1 = b;

__device__ __forceinline__ void tf2(unsigned k0, unsigned k1, unsigned x0, unsigned x1,
                                    unsigned &o0, unsigned &o1){ TF2BODY }
static void tf2h(unsigned k0, unsigned k1, unsigned x0, unsigned x1,
                 unsigned &o0, unsigned &o1){ TF2BODY }

__global__ void k_permkeys(int n, unsigned sk0, unsigned sk1, unsigned* __restrict__ keys){
  int i = blockIdx.x*256 + threadIdx.x;
  if (i < n){ unsigned a,b2; tf2(sk0, sk1, 0u, (unsigned)i, a, b2); keys[i] = a ^ b2; }
}

__global__ void k_permrank(int n, const unsigned* __restrict__ keys,
                           const int* __restrict__ vin, int* __restrict__ vout){
  int i = blockIdx.x*256 + threadIdx.x;
  if (i >= n) return;
  unsigned ki = keys[i];
  int rank = 0;
  for (int j=0;j<n;j++){
    unsigned kj = keys[j];
    rank += (kj < ki) || (kj == ki && j < i);
  }
  vout[rank] = vin ? vin[i] : i;
}

/* ---------------- graph branch ---------------- */

__global__ void k_transpose(const float* __restrict__ xyz, float* __restrict__ verts){
  int id = blockIdx.x*256 + threadIdx.x;
  if (id >= BB*NN*3) return;
  int c = id % 3, v = (id/3) % NN, b = id/(3*NN);
  verts[id] = xyz[(size_t)(b*3+c)*NN + v];
}

template<int CPL, int KSEL>
__global__ __launch_bounds__(256,4) void k_knn_g(const float* __restrict__ vbcs,
                                                 const int* __restrict__ qmap, int numQ,
                                                 int* __restrict__ out){
  constexpr int V = CPL*64;
  constexpr int GS = (CPL < 8) ? CPL : 8;
  constexpr int NG = CPL/GS;
  constexpr int GSH = (GS==8)?3:((GS==4)?2:((GS==2)?1:0));
  int t = threadIdx.x, wid = t>>6, lane = t&63;
  int b = blockIdx.y;
  int q = blockIdx.x*4 + wid;
  if (q >= numQ) return;
  const float* vx = vbcs + (size_t)b*3*V;
  const float* vy = vx + V;
  const float* vz = vy + V;
  int qv = qmap ? qmap[q] : q;
  float qx = vx[qv], qy = vy[qv], qz = vz[qv];
  float qq = qx*qx + qy*qy + qz*qz;
  unsigned long long key[CPL];
  #pragma unroll
  for (int i=0;i<CPL;i++){
    int c = lane + i*64;
    float wx=vx[c], wy=vy[c], wz=vz[c];
    float inner = qx*wx + qy*wy + qz*wz;
    float ww = wx*wx + wy*wy + wz*wz;
    float d = qq - 2.f*inner + ww;
    unsigned db = __float_as_uint(d);
    db = (db & 0x80000000u) ? ~db : (db | 0x80000000u);
    key[i] = ((unsigned long long)db << 32) | (unsigned)c;
  }
  unsigned long long g[NG];
  #pragma unroll
  for (int gg=0; gg<NG; gg++){
    unsigned long long m = key[gg*GS];
    #pragma unroll
    for (int j=1;j<GS;j++){ unsigned long long kk2 = key[gg*GS+j]; m = (kk2<m)?kk2:m; }
    g[gg] = m;
  }
  unsigned long long lb = g[0];
  #pragma unroll
  for (int gg=1;gg<NG;gg++) lb = (g[gg]<lb)?g[gg]:lb;

  int* orow = out + ((size_t)b*numQ + q)*KSEL;
  unsigned long long last = 0ull;
  for (int r=0; r<=KSEL; r++){
    unsigned long long best = lb;
    #pragma unroll
    for (int off=32; off>0; off>>=1){
      unsigned long long o = __shfl_xor(best, off, 64);
      best = (o < best) ? o : best;
    }
    int c = (int)(best & 0xffffffffull);
    if (r>0 && lane==0) orow[r-1] = c;
    last = best;
    if ((c & 63) == lane){
      int gi = c >> (6 + GSH);
      #pragma unroll
      for (int gg=0; gg<NG; gg++){
        if (gg == gi){
          unsigned long long m = ~0ull;
          #pragma unroll
          for (int j=0;j<GS;j++){
            unsigned long long kk2 = key[gg*GS+j];
            unsigned long long qk = (kk2 > last) ? kk2 : ~0ull;
            m = (qk<m)?qk:m;
          }
          g[gg] = m;
        }
      }
      unsigned long long nb2 = g[0];
      #pragma unroll
      for (int gg=1;gg<NG;gg++) nb2 = (g[gg]<nb2)?g[gg]:nb2;
      lb = nb2;
    }
  }
}

__global__ void k_dirs(const float* __restrict__ verts, int V, const int* __restrict__ idx,
                       float* __restrict__ dirs, int total){
  int id = blockIdx.x*256 + threadIdx.x;
  if (id >= total) return;
  int v = (id/20) % V, b = id/(20*V);
  const float* vb = verts + (size_t)b*V*3;
  int nb = idx[id];
  float dx = vb[nb*3+0]-vb[v*3+0];
  float dy = vb[nb*3+1]-vb[v*3+1];
  float dz = vb[nb*3+2]-vb[v*3+2];
  float s = 1.f / fmaxf(sqrtf(dx*dx+dy*dy+dz*dz), 1e-12f);
  dirs[(size_t)id*3+0]=dx*s; dirs[(size_t)id*3+1]=dy*s; dirs[(size_t)id*3+2]=dz*s;
}

// fm0 written directly as split planes [R][32]
__global__ void k_surf(const float* __restrict__ dirs, const float* __restrict__ dir0,
                       ushort* __restrict__ fh, ushort* __restrict__ fl, int V){
  int id = blockIdx.x*256 + threadIdx.x;
  if (id >= BB*V*32) return;
  int k = id & 31; int vv = (id>>5) % V; int b = id/(32*V);
  float nx=dir0[k], ny=dir0[32+k], nz=dir0[64+k];
  float s = 1.f/fmaxf(sqrtf(nx*nx+ny*ny+nz*nz), 1e-12f);
  nx*=s; ny*=s; nz*=s;
  const float* dd = dirs + (size_t)(b*V+vv)*60;
  float m = 0.f;
  for (int n=0;n<20;n++){
    float th = dd[n*3]*nx + dd[n*3+1]*ny + dd[n*3+2]*nz;
    m = fmaxf(m, fmaxf(th, 0.f));
  }
  ushort h,l; splitbf(m, h, l);
  size_t p = (size_t)(b*V+vv)*32 + k;
  fh[p]=h; fl[p]=l;
}

// out = [relu]( feat[:, :OC] + max_n( relu(dirs . ndir_col) * feat[nb, OC: ] ) )
// OUT=0: f32 (relu per flag). OUT=1: relu + split planes [row][OC].
template<int OUT>
__global__ void k_comb(const float* __restrict__ feat, const int* __restrict__ idx,
                       const float* __restrict__ dirs, const float* __restrict__ dw,
                       float* __restrict__ outp, ushort* __restrict__ oh, ushort* __restrict__ ol,
                       int V, int OC, int relu_flag){
  int id = blockIdx.x*256 + threadIdx.x;
  if (id >= BB*V*OC) return;
  int oc = id % OC, v = (id/OC) % V, b = id/(OC*V);
  float wx=dw[oc], wy=dw[OC+oc], wz=dw[2*OC+oc];
  float s = 1.f/fmaxf(sqrtf(wx*wx+wy*wy+wz*wz), 1e-12f);
  wx*=s; wy*=s; wz*=s;
  size_t row = (size_t)b*V + v;
  const int* ir = idx + row*20;
  const float* dd = dirs + row*60;
  float center = feat[row*2*OC + oc];
  float m = -INFINITY;
  for (int n=0;n<20;n++){
    int nb = ir[n];
    float th = dd[n*3]*wx + dd[n*3+1]*wy + dd[n*3+2]*wz;
    th = fmaxf(th, 0.f);
    float sup = feat[((size_t)b*V + nb)*2*OC + OC + oc];
    m = fmaxf(m, th*sup);
  }
  float rv = center + m;
  if (OUT == 0){
    outp[row*OC + oc] = relu_flag ? fmaxf(rv, 0.f) : rv;
  } else {
    rv = fmaxf(rv, 0.f);
    ushort h,l; splitbf(rv, h, l);
    oh[row*OC + oc]=h; ol[row*OC + oc]=l;
  }
}

// OUT=0: f32. OUT=1: split planes [row][C].
template<int OUT>
__global__ void k_pool(const float* __restrict__ fm, const int* __restrict__ idx4,
                       float* __restrict__ outp, ushort* __restrict__ oh, ushort* __restrict__ ol,
                       int V, int C, int numS){
  int id = blockIdx.x*256 + threadIdx.x;
  if (id >= BB*numS*C) return;
  int c = id % C, sI = (id/C) % numS, b = id/(C*numS);
  const int* ir = idx4 + ((size_t)b*numS + sI)*4;
  float m = -INFINITY;
  for (int n=0;n<4;n++) m = fmaxf(m, fm[((size_t)b*V + ir[n])*C + c]);
  size_t p = ((size_t)b*numS + sI)*C + c;
  if (OUT == 0) outp[p] = m;
  else { ushort h,l; splitbf(m, h, l); oh[p]=h; ol[p]=l; }
}

__global__ void k_vgather(const float* __restrict__ vin, const int* __restrict__ perm,
                          float* __restrict__ vout, float* __restrict__ vbcs,
                          int V, int numS){
  int id = blockIdx.x*256 + threadIdx.x;
  if (id >= BB*numS*3) return;
  int c = id % 3, sI = (id/3) % numS, b = id/(3*numS);
  float val = vin[((size_t)b*V + perm[sI])*3 + c];
  vout[id] = val;
  vbcs[((size_t)b*3 + c)*numS + sI] = val;
}

__global__ void k_colmax(const float* __restrict__ x, float* __restrict__ o, int Vr, int C){
  int id = blockIdx.x*256 + threadIdx.x;
  if (id >= BB*C) return;
  int c = id % C, b = id / C;
  float m = -INFINITY;
  for (int v=0; v<Vr; v++) m = fmaxf(m, x[(size_t)(b*Vr+v)*C + c]);
  o[id] = m;
}

/* ---------------- FC head (wave-per-output dot products) ---------------- */

__global__ __launch_bounds__(256) void k_emb2(const float* __restrict__ xmax, const float* __restrict__ fg,
                                              const float* __restrict__ fcw, const float* __restrict__ fcb,
                                              float* __restrict__ outp){
  int gid = blockIdx.x*4 + (threadIdx.x>>6);
  int lane = threadIdx.x & 63;
  if (gid >= BB*512) return;
  int e = gid & 511, b = gid >> 9;
  const float* wr = fcw + (size_t)e*2048;
  const float* xb = xmax + b*1024;
  const float* gb = fg + b*1024;
  float acc = 0.f;
  for (int k=lane; k<1024; k+=64)
    acc += xb[k]*wr[k] + gb[k]*wr[1024+k];
  #pragma unroll
  for (int off=32; off>0; off>>=1) acc += __shfl_xor(acc, off, 64);
  if (lane==0) outp[gid] = acc + fcb[e];
}

__global__ __launch_bounds__(256) void k_h2(const float* __restrict__ xmax, const float* __restrict__ fg,
                                            const float* __restrict__ clw1, const float* __restrict__ clb1,
                                            const float* __restrict__ gamma, const float* __restrict__ beta,
                                            float* __restrict__ h){
  int gid = blockIdx.x*4 + (threadIdx.x>>6);
  int lane = threadIdx.x & 63;
  if (gid >= BB*512) return;
  int j = gid & 511, b = gid >> 9;
  const float* wr = clw1 + (size_t)j*2048;
  const float* xb = xmax + b*1024;
  const float* gb = fg + b*1024;
  float acc = 0.f;
  for (int k=lane; k<1024; k+=64)
    acc += xb[k]*wr[k] + gb[k]*wr[1024+k];
  #pragma unroll
  for (int off=32; off>0; off>>=1) acc += __shfl_xor(acc, off, 64);
  if (lane==0){
    const float inv_s = 1.0f / sqrtf(1.0f + 1e-5f);
    float v = (acc + clb1[j]) * inv_s * gamma[j] + beta[j];
    h[gid] = fmaxf(v, 0.f);
  }
}

__global__ __launch_bounds__(256) void k_pred2(const float* __restrict__ h, const float* __restrict__ clw2,
                                               const float* __restrict__ clb2, float* __restrict__ outp){
  int gid = blockIdx.x*4 + (threadIdx.x>>6);
  int lane = threadIdx.x & 63;
  if (gid >= BB*6) return;
  int o = gid % 6, b = gid / 6;
  const float* hb = h + b*512;
  const float* wr = clw2 + o*512;
  float acc = 0.f;
  for (int k=lane; k<512; k+=64) acc += hb[k]*wr[k];
  #pragma unroll
  for (int off=32; off>0; off>>=1) acc += __shfl_xor(acc, off, 64);
  if (lane==0) outp[BB*512 + gid] = acc + clb2[o];
}

/* ---------------- launch ---------------- */

static inline int cdiv(long long a, int b){ return (int)((a + b - 1)/b); }

extern "C" void kernel_launch(void* const* d_in, const int* in_sizes, int n_in,
                              void* d_out, int out_size, void* d_ws, size_t ws_size,
                              hipStream_t stream){
  float* out = (float*)d_out;
  if (n_in != 30 || in_sizes[0] != BB*3*NN || out_size != BB*512 + BB*6){
    k_sentinel<<<cdiv(out_size,256),256,0,stream>>>(out, out_size, 2000.0f);
    return;
  }
  const float* xyz  = (const float*)d_in[0];
  const float* w1   = (const float*)d_in[1];
  const float* b1   = (const float*)d_in[2];
  const float* w2   = (const float*)d_in[3];
  const float* b2   = (const float*)d_in[4];
  const float* w3   = (const float*)d_in[5];
  const float* b3   = (const float*)d_in[6];
  const float* w4   = (const float*)d_in[7];
  const float* b4   = (const float*)d_in[8];
  const float* fcw  = (const float*)d_in[9];
  const float* fcb  = (const float*)d_in[10];
  const float* dir0 = (const float*)d_in[11];
  const float* wc1  = (const float*)d_in[12];
  const float* bc1  = (const float*)d_in[13];
  const float* dir1 = (const float*)d_in[14];
  const float* wc2  = (const float*)d_in[15];
  const float* bc2  = (const float*)d_in[16];
  const float* dir2 = (const float*)d_in[17];
  const float* wc3  = (const float*)d_in[18];
  const float* bc3  = (const float*)d_in[19];
  const float* dir3 = (const float*)d_in[20];
  const float* wc4  = (const float*)d_in[21];
  const float* bc4  = (const float*)d_in[22];
  const float* dir4 = (const float*)d_in[23];
  const float* clw1 = (const float*)d_in[24];
  const float* clb1 = (const float*)d_in[25];
  const float* gma  = (const float*)d_in[26];
  const float* bta  = (const float*)d_in[27];
  const float* clw2 = (const float*)d_in[28];
  const float* clb2 = (const float*)d_in[29];

  char* w = (char*)d_ws;
  size_t off = 0;
  auto A = [&](size_t bytes){ size_t r = off; off += (bytes + 255) & ~(size_t)255; return r; };
  const size_t oXMAX = A((size_t)BB*1024*4);
  const size_t oFG   = A((size_t)BB*1024*4);
  const size_t oGF   = A((size_t)BB*128*4);
  const size_t oGFP  = A((size_t)BB*128*2*2);
  const size_t oH    = A((size_t)BB*512*4);
  const size_t oP2048= A(2048*4);
  const size_t oP512 = A(512*4);
  const size_t oPKEY = A(2048*4);
  const size_t oPA   = A(2048*4);
  const size_t oPMAX = A((size_t)BB*1024*32*4);
  const size_t oV0   = A((size_t)BB*2048*3*4);
  const size_t oV1   = A((size_t)BB*512*3*4);
  const size_t oV2   = A((size_t)BB*128*3*4);
  const size_t oV1S  = A((size_t)BB*3*512*4);
  const size_t oV2S  = A((size_t)BB*3*128*4);
  const size_t oIDX0 = A((size_t)BB*2048*20*4);   // also aliased by x2T planes (dead before knn)
  const size_t oDIR0 = A((size_t)BB*2048*20*3*4);
  const size_t oFM0  = A((size_t)BB*2048*32*2*2); // fm0 planes
  const size_t oFM1  = A((size_t)BB*2048*64*4);
  const size_t oI40  = A((size_t)BB*512*4*4);
  const size_t oFM1P = A((size_t)BB*512*64*2*2);  // planes
  const size_t oIDX1 = A((size_t)BB*512*20*4);
  const size_t oDIR1 = A((size_t)BB*512*20*3*4);
  const size_t oFM2  = A((size_t)BB*512*128*2*2); // planes
  const size_t oFM3  = A((size_t)BB*512*256*4);
  const size_t oI41  = A((size_t)BB*128*4*4);
  const size_t oFM3P = A((size_t)BB*128*256*2*2); // planes
  const size_t oIDX2 = A((size_t)BB*128*20*4);
  const size_t oDIR2 = A((size_t)BB*128*20*3*4);
  const size_t oFM4  = A((size_t)BB*128*1024*4);
  const size_t oBIGA = A((size_t)BB*256*NN*4);    // x1T planes then x3T planes
  const size_t oBIGB = A((size_t)BB*128*NN*4);    // x2 f32, then feat f32
  const size_t oW2P  = A((size_t)128*64*2*2);
  const size_t oW3P  = A((size_t)256*256*2*2);
  const size_t oW4P  = A((size_t)1024*256*2*2);
  const size_t oWC1T = A((size_t)32*128*2*2);
  const size_t oWC2T = A((size_t)64*256*2*2);
  const size_t oWC3T = A((size_t)128*512*2*2);
  const size_t oWC4T = A((size_t)256*2048*2*2);
  if (off > ws_size){
    k_sentinel<<<cdiv(out_size,256),256,0,stream>>>(out, out_size, 1000.0f);
    return;
  }
  float* xmax = (float*)(w+oXMAX); float* fg = (float*)(w+oFG);
  float* gf = (float*)(w+oGF);     float* hbuf = (float*)(w+oH);
  ushort* gfh = (ushort*)(w+oGFP); ushort* gfl = gfh + BB*128;
  int* p2048 = (int*)(w+oP2048);   int* p512 = (int*)(w+oP512);
  unsigned* pkeys = (unsigned*)(w+oPKEY); int* pa = (int*)(w+oPA);
  float* pmax = (float*)(w+oPMAX);
  float* v0 = (float*)(w+oV0); float* v1 = (float*)(w+oV1); float* v2 = (float*)(w+oV2);
  float* v1s = (float*)(w+oV1S); float* v2s = (float*)(w+oV2S);
  int* idx0 = (int*)(w+oIDX0); int* idx1 = (int*)(w+oIDX1); int* idx2 = (int*)(w+oIDX2);
  int* i40 = (int*)(w+oI40);   int* i41 = (int*)(w+oI41);
  float* d0 = (float*)(w+oDIR0); float* d1 = (float*)(w+oDIR1); float* d2 = (float*)(w+oDIR2);
  ushort* fm0h = (ushort*)(w+oFM0); ushort* fm0l = fm0h + (size_t)BB*2048*32;
  float* fm1 = (float*)(w+oFM1);
  ushort* fm1ph = (ushort*)(w+oFM1P); ushort* fm1pl = fm1ph + (size_t)BB*512*64;
  ushort* fm2h = (ushort*)(w+oFM2); ushort* fm2l = fm2h + (size_t)BB*512*128;
  float* fm3 = (float*)(w+oFM3);
  ushort* fm3ph = (ushort*)(w+oFM3P); ushort* fm3pl = fm3ph + (size_t)BB*128*256;
  float* fm4 = (float*)(w+oFM4);
  // x1T planes (dead before mlp3) and x3T planes share BIGA
  ushort* x1h = (ushort*)(w+oBIGA); ushort* x1l = x1h + (size_t)BB*2048*64;
  ushort* x3h = (ushort*)(w+oBIGA); ushort* x3l = x3h + (size_t)BB*2048*256;
  // x2T planes alias idx0+dir0 region (16.8MB < 18.3MB; dead before knn writes)
  ushort* x2h = (ushort*)(w+oIDX0); ushort* x2l = x2h + (size_t)BB*2048*128;
  float* x2 = (float*)(w+oBIGB); float* feat = (float*)(w+oBIGB);
  ushort* w2ph = (ushort*)(w+oW2P); ushort* w2pl = w2ph + 128*64;
  ushort* w3ph = (ushort*)(w+oW3P); ushort* w3pl = w3ph + 256*256;
  ushort* w4ph = (ushort*)(w+oW4P); ushort* w4pl = w4ph + 1024*256;
  ushort* wc1h = (ushort*)(w+oWC1T); ushort* wc1l = wc1h + 32*128;
  ushort* wc2h = (ushort*)(w+oWC2T); ushort* wc2l = wc2h + 64*256;
  ushort* wc3h = (ushort*)(w+oWC3T); ushort* wc3l = wc3h + 128*512;
  ushort* wc4h = (ushort*)(w+oWC4T); ushort* wc4l = wc4h + 256*2048;

  // weight pre-split
  k_wsrm<<<cdiv(128*64,256),256,0,stream>>>(w2, w2ph, w2pl, 128*64);
  k_wsrm<<<cdiv(256*256,256),256,0,stream>>>(w3, w3ph, w3pl, 256*256);
  k_wsrm<<<cdiv(1024*256,256),256,0,stream>>>(w4, w4ph, w4pl, 1024*256);
  k_wstr<<<cdiv(32*128,256),256,0,stream>>>(wc1, wc1h, wc1l, 32, 128);
  k_wstr<<<cdiv(64*256,256),256,0,stream>>>(wc2, wc2h, wc2l, 64, 256);
  k_wstr<<<cdiv(128*512,256),256,0,stream>>>(wc3, wc3h, wc3l, 128, 512);
  k_wstr<<<cdiv(256*2048,256),256,0,stream>>>(wc4, wc4h, wc4l, 256, 2048);

  // MLP branch
  k_mlp1s<<<cdiv((long long)BB*NN*64,256),256,0,stream>>>(xyz, w1, b1, x1h, x1l);
  k_bgemm<2,1,0><<<dim3(32,1,BB),256,0,stream>>>(w2ph, w2pl, x1h, x1l, nullptr, nullptr,
      b2, x2, nullptr, x2h, x2l, 64, 64, 64, 2048, (size_t)2048*64, (size_t)128*2048, 128);
  k_rowmax<<<BB*128,256,0,stream>>>(x2, gf, gfh, gfl, NN);
  k_bgemm<3,1,0><<<dim3(32,2,BB),256,0,stream>>>(w3ph, w3pl, x2h, x2l, gfh, gfl,
      b3, nullptr, nullptr, x3h, x3l, 256, 128, 128, 2048, (size_t)2048*128, 0, 256);
  k_bgemm<1,1,0><<<dim3(32,8,BB),256,0,stream>>>(w4ph, w4pl, x3h, x3l, nullptr, nullptr,
      b4, nullptr, pmax, nullptr, nullptr, 256, 256, 256, 2048, (size_t)2048*256, 0, 1024);
  k_xmax<<<cdiv(BB*1024,256),256,0,stream>>>(pmax, xmax);

  // permutations
  {
    unsigned ck0=0u, ck1=1u, nk0,nk1, s00,s01, s10,s11, sc0,sc1;
    tf2h(ck0,ck1, 0u,0u, nk0,nk1);
    tf2h(ck0,ck1, 0u,1u, s00,s01);
    tf2h(nk0,nk1, 0u,1u, s10,s11);
    tf2h(0u,2u,  0u,1u, sc0,sc1);
    k_permkeys<<<8,256,0,stream>>>(2048, s00, s01, pkeys);
    k_permrank<<<8,256,0,stream>>>(2048, pkeys, nullptr, pa);
    k_permkeys<<<8,256,0,stream>>>(2048, s10, s11, pkeys);
    k_permrank<<<8,256,0,stream>>>(2048, pkeys, pa, p2048);
    k_permkeys<<<2,256,0,stream>>>(512, sc0, sc1, pkeys);
    k_permrank<<<2,256,0,stream>>>(512, pkeys, nullptr, p512);
  }

  // graph branch: stage 0 (V=2048)
  k_transpose<<<cdiv((long long)BB*NN*3,256),256,0,stream>>>(xyz, v0);
  k_knn_g<32,20><<<dim3(512,BB),256,0,stream>>>(xyz, nullptr, 2048, idx0);
  k_dirs<<<cdiv((long long)BB*2048*20,256),256,0,stream>>>(v0, 2048, idx0, d0, BB*2048*20);
  k_surf<<<cdiv((long long)BB*2048*32,256),256,0,stream>>>(d0, dir0, fm0h, fm0l, 2048);
  k_bgemm<0,0,1><<<dim3(2,256,1),256,0,stream>>>(fm0h, fm0l, wc1h, wc1l, nullptr, nullptr,
      bc1, feat, nullptr, nullptr, nullptr, 32, 32, 32, 128, 0, 0, BB*2048);
  k_comb<0><<<cdiv((long long)BB*2048*64,256),256,0,stream>>>(feat, idx0, d0, dir1, fm1, nullptr, nullptr, 2048, 64, 1);
  // pool 1
  k_knn_g<32,4><<<dim3(128,BB),256,0,stream>>>(xyz, p2048, 512, i40);
  k_pool<1><<<cdiv((long long)BB*512*64,256),256,0,stream>>>(fm1, i40, nullptr, fm1ph, fm1pl, 2048, 64, 512);
  k_vgather<<<cdiv((long long)BB*512*3,256),256,0,stream>>>(v0, p2048, v1, v1s, 2048, 512);
  // stage 1 (V=512)
  k_knn_g<8,20><<<dim3(128,BB),256,0,stream>>>(v1s, nullptr, 512, idx1);
  k_dirs<<<cdiv((long long)BB*512*20,256),256,0,stream>>>(v1, 512, idx1, d1, BB*512*20);
  k_bgemm<0,0,1><<<dim3(4,64,1),256,0,stream>>>(fm1ph, fm1pl, wc2h, wc2l, nullptr, nullptr,
      bc2, feat, nullptr, nullptr, nullptr, 64, 64, 64, 256, 0, 0, BB*512);
  k_comb<1><<<cdiv((long long)BB*512*128,256),256,0,stream>>>(feat, idx1, d1, dir2, nullptr, fm2h, fm2l, 512, 128, 1);
  k_bgemm<0,0,1><<<dim3(8,64,1),256,0,stream>>>(fm2h, fm2l, wc3h, wc3l, nullptr, nullptr,
      bc3, feat, nullptr, nullptr, nullptr, 128, 128, 128, 512, 0, 0, BB*512);
  k_comb<0><<<cdiv((long long)BB*512*256,256),256,0,stream>>>(feat, idx1, d1, dir3, fm3, nullptr, nullptr, 512, 256, 1);
  // pool 2
  k_knn_g<8,4><<<dim3(32,BB),256,0,stream>>>(v1s, p512, 128, i41);
  k_pool<1><<<cdiv((long long)BB*128*256,256),256,0,stream>>>(fm3, i41, nullptr, fm3ph, fm3pl, 512, 256, 128);
  k_vgather<<<cdiv((long long)BB*128*3,256),256,0,stream>>>(v1, p512, v2, v2s, 512, 128);
  // stage 2 (V=128)
  k_knn_g<2,20><<<dim3(32,BB),256,0,stream>>>(v2s, nullptr, 128, idx2);
  k_dirs<<<cdiv((long long)BB*128*20,256),256,0,stream>>>(v2, 128, idx2, d2, BB*128*20);
  k_bgemm<0,0,1><<<dim3(32,16,1),256,0,stream>>>(fm3ph, fm3pl, wc4h, wc4l, nullptr, nullptr,
      bc4, feat, nullptr, nullptr, nullptr, 256, 256, 256, 2048, 0, 0, BB*128);
  k_comb<0><<<cdiv((long long)BB*128*1024,256),256,0,stream>>>(feat, idx2, d2, dir4, fm4, nullptr, nullptr, 128, 1024, 0);
  k_colmax<<<cdiv(BB*1024,256),256,0,stream>>>(fm4, fg, 128, 1024);

  // FC head
  k_emb2<<<cdiv(BB*512,4),256,0,stream>>>(xmax, fg, fcw, fcb, out);
  k_h2<<<cdiv(BB*512,4),256,0,stream>>>(xmax, fg, clw1, clb1, gma, bta, hbuf);
  k_pred2<<<cdiv(BB*6,4),256,0,stream>>>(hbuf, clw2, clb2, out);
}

// Round 8
// 764.016 us; speedup vs baseline: 3.2244x; 1.0174x over previous
//
#include <hip/hip_runtime.h>
#include <hip/hip_bf16.h>
#include <math.h>

#define BB 16
#define NN 2048

typedef __attribute__((ext_vector_type(8))) short s8v;
typedef __attribute__((ext_vector_type(4))) float f4v;

__global__ void k_sentinel(float* o, int n, float v){
  int i = blockIdx.x*256 + threadIdx.x;
  if (i < n) o[i] = v;
}

__device__ __forceinline__ ushort f2bf(float x){
  unsigned u = __float_as_uint(x);
  unsigned r = u + 0x7FFFu + ((u>>16)&1u);
  return (ushort)(r>>16);
}
__device__ __forceinline__ void splitbf(float v, ushort &h, ushort &l){
  h = f2bf(v);
  float hf = __uint_as_float((unsigned)h<<16);
  l = f2bf(v-hf);
}

/* ---------------- weight pre-split ---------------- */

__global__ void k_wsrm(const float* __restrict__ src, ushort* __restrict__ dh,
                       ushort* __restrict__ dl, int total){
  int id = blockIdx.x*256 + threadIdx.x;
  if (id >= total) return;
  ushort h,l; splitbf(src[id], h, l);
  dh[id]=h; dl[id]=l;
}

// [K][C] -> transposed planes [C][K]
__global__ void k_wstr(const float* __restrict__ src, ushort* __restrict__ dh,
                       ushort* __restrict__ dl, int K, int C){
  int id = blockIdx.x*256 + threadIdx.x;
  if (id >= K*C) return;
  int c = id % C, k = id / C;
  ushort h,l; splitbf(src[id], h, l);
  dh[(size_t)c*K + k]=h; dl[(size_t)c*K + k]=l;
}

/* ---------------- MLP branch ---------------- */

__global__ void k_mlp1s(const float* __restrict__ xyz, const float* __restrict__ w1,
                        const float* __restrict__ b1, ushort* __restrict__ xh,
                        ushort* __restrict__ xl){
  int id = blockIdx.x*256 + threadIdx.x;
  if (id >= BB*NN*64) return;
  int o = id & 63, n = (id>>6) & (NN-1), b = id>>17;
  float acc = b1[o];
  #pragma unroll
  for (int c=0;c<3;c++)
    acc += w1[o*3+c] * xyz[(size_t)(b*3+c)*NN + n];
  acc = fmaxf(acc, 0.f);
  ushort h,l; splitbf(acc, h, l);
  xh[id]=h; xl[id]=l;
}

__global__ __launch_bounds__(256) void k_rowmax(const float* __restrict__ x, float* __restrict__ o,
                                                ushort* __restrict__ gh, ushort* __restrict__ gl, int cols){
  __shared__ float sm[256];
  int row = blockIdx.x, t = threadIdx.x;
  const float* xr = x + (size_t)row*cols;
  float m = -INFINITY;
  for (int c=t;c<cols;c+=256) m = fmaxf(m, xr[c]);
  sm[t]=m; __syncthreads();
  for (int s=128;s>0;s>>=1){ if (t<s) sm[t]=fmaxf(sm[t], sm[t+s]); __syncthreads(); }
  if (!t){
    o[row]=sm[0];
    ushort h,l; splitbf(sm[0], h, l);
    gh[row]=h; gl[row]=l;
  }
}

/* ---------------- pre-split bf16 MFMA GEMM ---------------- */
template<int EPI, int RELU, int BCOL>
__global__ __launch_bounds__(256) void k_bgemm(
    const ushort* __restrict__ Ahg, const ushort* __restrict__ Alg,
    const ushort* __restrict__ Bhg, const ushort* __restrict__ Blg,
    const ushort* __restrict__ gfh, const ushort* __restrict__ gfl,
    const float* __restrict__ bias,
    float* __restrict__ outp, float* __restrict__ pmaxp,
    ushort* __restrict__ oth, ushort* __restrict__ otl,
    int K, int ksplit, int Kb, int N, size_t sBT, size_t sOut, int M)
{
  __shared__ ushort Ah[128][40], Al[128][40];
  __shared__ ushort Bh[64][40],  Bl[64][40];
  __shared__ float red[2][128];
  int t = threadIdx.x, z = blockIdx.z;
  int o0 = blockIdx.y*128, n0 = blockIdx.x*64;
  int wid = t>>6, lane = t&63;
  int wm = wid>>1, wn = wid&1;
  int lr = lane&15, kg = lane>>4;

  f4v acc[4][2];
  #pragma unroll
  for (int i=0;i<4;i++)
    #pragma unroll
    for (int j=0;j<2;j++) acc[i][j] = (f4v){0.f,0.f,0.f,0.f};

  for (int k0=0; k0<K; k0+=32){
    __syncthreads();
    #pragma unroll
    for (int i=0;i<2;i++){
      int j = i*256+t, oo = j>>2, k8 = (j&3)*8;
      size_t sp = (size_t)(o0+oo)*K + k0 + k8;
      *(s8v*)&Ah[oo][k8] = *(const s8v*)(Ahg+sp);
      *(s8v*)&Al[oo][k8] = *(const s8v*)(Alg+sp);
    }
    {
      int nn = t>>2, k8 = (t&3)*8, gk = k0+k8;
      const ushort *sh, *sl;
      if (gk < ksplit){
        size_t sp = (size_t)z*sBT + (size_t)(n0+nn)*Kb + gk;
        sh = Bhg+sp; sl = Blg+sp;
      } else {
        size_t sp = (size_t)z*(K-ksplit) + (gk-ksplit);
        sh = gfh+sp; sl = gfl+sp;
      }
      *(s8v*)&Bh[nn][k8] = *(const s8v*)sh;
      *(s8v*)&Bl[nn][k8] = *(const s8v*)sl;
    }
    __syncthreads();

    s8v ah[4], al[4], bh[2], bl[2];
    #pragma unroll
    for (int mt=0;mt<4;mt++){
      int row = wm*64 + mt*16 + lr;
      ah[mt] = *(const s8v*)&Ah[row][kg*8];
      al[mt] = *(const s8v*)&Al[row][kg*8];
    }
    #pragma unroll
    for (int nt=0;nt<2;nt++){
      int col = wn*32 + nt*16 + lr;
      bh[nt] = *(const s8v*)&Bh[col][kg*8];
      bl[nt] = *(const s8v*)&Bl[col][kg*8];
    }
    #pragma unroll
    for (int mt=0;mt<4;mt++)
      #pragma unroll
      for (int nt=0;nt<2;nt++){
        acc[mt][nt] = __builtin_amdgcn_mfma_f32_16x16x32_bf16(ah[mt], bh[nt], acc[mt][nt], 0,0,0);
        acc[mt][nt] = __builtin_amdgcn_mfma_f32_16x16x32_bf16(ah[mt], bl[nt], acc[mt][nt], 0,0,0);
        acc[mt][nt] = __builtin_amdgcn_mfma_f32_16x16x32_bf16(al[mt], bh[nt], acc[mt][nt], 0,0,0);
      }
  }

  if (EPI == 1){
    #pragma unroll
    for (int mt=0;mt<4;mt++){
      #pragma unroll
      for (int e=0;e<4;e++){
        int row = o0 + wm*64 + mt*16 + kg*4 + e;
        float bv = bias[row];
        float m = fmaxf(fmaxf(acc[mt][0][e]+bv, 0.f), fmaxf(acc[mt][1][e]+bv, 0.f));
        m = fmaxf(m, __shfl_xor(m, 1, 64));
        m = fmaxf(m, __shfl_xor(m, 2, 64));
        m = fmaxf(m, __shfl_xor(m, 4, 64));
        m = fmaxf(m, __shfl_xor(m, 8, 64));
        if (lr == 0) red[wn][wm*64 + mt*16 + kg*4 + e] = m;
      }
    }
    __syncthreads();
    if (t < 128){
      float m = fmaxf(red[0][t], red[1][t]);
      pmaxp[((size_t)z*M + o0 + t)*gridDim.x + blockIdx.x] = m;
    }
  } else {
    #pragma unroll
    for (int mt=0;mt<4;mt++){
      #pragma unroll
      for (int nt=0;nt<2;nt++){
        int col = n0 + wn*32 + nt*16 + lr;
        #pragma unroll
        for (int e=0;e<4;e++){
          int row = o0 + wm*64 + mt*16 + kg*4 + e;
          float bv = BCOL ? bias[col] : bias[row];
          float v = acc[mt][nt][e] + bv;
          if (RELU) v = fmaxf(v, 0.f);
          if (EPI == 0 || EPI == 2)
            outp[(size_t)z*sOut + (size_t)row*N + col] = v;
          if (EPI >= 2){
            ushort h,l; splitbf(v, h, l);
            size_t p = ((size_t)z*N + col)*(size_t)M + row;
            oth[p]=h; otl[p]=l;
          }
        }
      }
    }
  }
}

__global__ void k_xmax(const float* __restrict__ pmax, float* __restrict__ xmax){
  int id = blockIdx.x*256 + threadIdx.x;
  if (id >= BB*1024) return;
  float m = pmax[(size_t)id*32];
  for (int k=1;k<32;k++) m = fmaxf(m, pmax[(size_t)id*32+k]);
  xmax[id] = m;
}

/* ---------------- JAX threefry PRNG permutation ---------------- */

#define TF2BODY \
  unsigned ks2 = 0x1BD11BDAu ^ k0 ^ k1; \
  unsigned a = x0 + k0, b = x1 + k1; \
  { \
  a += b; b = (b<<13)|(b>>19); b ^= a; \
  a += b; b = (b<<15)|(b>>17); b ^= a; \
  a += b; b = (b<<26)|(b>>6);  b ^= a; \
  a += b; b = (b<<6) |(b>>26); b ^= a;  a += k1;  b += ks2 + 1u; \
  a += b; b = (b<<17)|(b>>15); b ^= a; \
  a += b; b = (b<<29)|(b>>3);  b ^= a; \
  a += b; b = (b<<16)|(b>>16); b ^= a; \
  a += b; b = (b<<24)|(b>>8);  b ^= a;  a += ks2; b += k0  + 2u; \
  a += b; b = (b<<13)|(b>>19); b ^= a; \
  a += b; b = (b<<15)|(b>>17); b ^= a; \
  a += b; b = (b<<26)|(b>>6);  b ^= a; \
  a += b; b = (b<<6) |(b>>26); b ^= a;  a += k0;  b += k1  + 3u; \
  a += b; b = (b<<17)|(b>>15); b ^= a; \
  a += b; b = (b<<29)|(b>>3);  b ^= a; \
  a += b; b = (b<<16)|(b>>16); b ^= a; \
  a += b; b = (b<<24)|(b>>8);  b ^= a;  a += k1;  b += ks2 + 4u; \
  a += b; b = (b<<13)|(b>>19); b ^= a; \
  a += b; b = (b<<15)|(b>>17); b ^= a; \
  a += b; b = (b<<26)|(b>>6);  b ^= a; \
  a += b; b = (b<<6) |(b>>26); b ^= a;  a += ks2; b += k0  + 5u; \
  } \
  o0 = a; o1 = b;

__device__ __forceinline__ void tf2(unsigned k0, unsigned k1, unsigned x0, unsigned x1,
                                    unsigned &o0, unsigned &o1){ TF2BODY }
static void tf2h(unsigned k0, unsigned k1, unsigned x0, unsigned x1,
                 unsigned &o0, unsigned &o1){ TF2BODY }

__global__ void k_permkeys(int n, unsigned sk0, unsigned sk1, unsigned* __restrict__ keys){
  int i = blockIdx.x*256 + threadIdx.x;
  if (i < n){ unsigned a,b2; tf2(sk0, sk1, 0u, (unsigned)i, a, b2); keys[i] = a ^ b2; }
}

__global__ void k_permrank(int n, const unsigned* __restrict__ keys,
                           const int* __restrict__ vin, int* __restrict__ vout){
  int i = blockIdx.x*256 + threadIdx.x;
  if (i >= n) return;
  unsigned ki = keys[i];
  int rank = 0;
  for (int j=0;j<n;j++){
    unsigned kj = keys[j];
    rank += (kj < ki) || (kj == ki && j < i);
  }
  vout[rank] = vin ? vin[i] : i;
}

/* ---------------- graph branch ---------------- */

__global__ void k_transpose(const float* __restrict__ xyz, float* __restrict__ verts){
  int id = blockIdx.x*256 + threadIdx.x;
  if (id >= BB*NN*3) return;
  int c = id % 3, v = (id/3) % NN, b = id/(3*NN);
  verts[id] = xyz[(size_t)(b*3+c)*NN + v];
}

// Wave-per-query KNN, register-resident u32 distances (idx implicit in slot:
// c = lane + i*64). u64 key (d<<32)|c built on the fly for group minima and
// winner-lane refilter -> same exact XLA stable top-k order as before, but
// ~60 VGPRs total (no AGPR/scratch spill).
template<int CPL, int KSEL>
__global__ __launch_bounds__(256,6) void k_knn_r(const float* __restrict__ vbcs,
                                                 const int* __restrict__ qmap, int numQ,
                                                 int* __restrict__ out){
  constexpr int V = CPL*64;
  constexpr int GS = (CPL < 8) ? CPL : 8;
  constexpr int NG = CPL/GS;
  constexpr int GSH = (GS==8)?3:((GS==4)?2:((GS==2)?1:0));
  int t = threadIdx.x, wid = t>>6, lane = t&63;
  int b = blockIdx.y;
  int q = blockIdx.x*4 + wid;
  if (q >= numQ) return;
  const float* vx = vbcs + (size_t)b*3*V;
  const float* vy = vx + V;
  const float* vz = vy + V;
  int qv = qmap ? qmap[q] : q;
  float qx = vx[qv], qy = vy[qv], qz = vz[qv];
  float qq = qx*qx + qy*qy + qz*qz;
  unsigned d[CPL];
  #pragma unroll
  for (int i=0;i<CPL;i++){
    int c = lane + i*64;
    float wx=vx[c], wy=vy[c], wz=vz[c];
    float inner = qx*wx + qy*wy + qz*wz;
    float ww = wx*wx + wy*wy + wz*wz;
    float dd = qq - 2.f*inner + ww;
    unsigned db = __float_as_uint(dd);
    d[i] = (db & 0x80000000u) ? ~db : (db | 0x80000000u);
  }
  unsigned long long g[NG];
  #pragma unroll
  for (int gg=0; gg<NG; gg++){
    unsigned long long m = ~0ull;
    #pragma unroll
    for (int j=0;j<GS;j++){
      int i = gg*GS+j;
      unsigned long long kk = ((unsigned long long)d[i]<<32) | (unsigned)(lane + i*64);
      m = (kk<m)?kk:m;
    }
    g[gg] = m;
  }
  unsigned long long lb = g[0];
  #pragma unroll
  for (int gg=1;gg<NG;gg++) lb = (g[gg]<lb)?g[gg]:lb;

  int* orow = out + ((size_t)b*numQ + q)*KSEL;
  unsigned long long last = 0ull;
  for (int r=0; r<=KSEL; r++){
    unsigned long long best = lb;
    #pragma unroll
    for (int off=32; off>0; off>>=1){
      unsigned long long o = __shfl_xor(best, off, 64);
      best = (o < best) ? o : best;
    }
    int c = (int)(best & 0xffffffffull);
    if (r>0 && lane==0) orow[r-1] = c;
    last = best;
    if ((c & 63) == lane){
      int gi = c >> (6 + GSH);
      #pragma unroll
      for (int gg=0; gg<NG; gg++){
        if (gg == gi){
          unsigned long long m = ~0ull;
          #pragma unroll
          for (int j=0;j<GS;j++){
            int i = gg*GS+j;
            unsigned long long kk = ((unsigned long long)d[i]<<32) | (unsigned)(lane + i*64);
            unsigned long long qk = (kk > last) ? kk : ~0ull;
            m = (qk<m)?qk:m;
          }
          g[gg] = m;
        }
      }
      unsigned long long nb2 = g[0];
      #pragma unroll
      for (int gg=1;gg<NG;gg++) nb2 = (g[gg]<nb2)?g[gg]:nb2;
      lb = nb2;
    }
  }
}

// pool KNN = prefix of the stage KNN (same dist matrix, stable top-k):
// i4[b][s][j] = idxsrc[b][perm[s]][j], j<4
__global__ void k_poolidx(const int* __restrict__ idxsrc, const int* __restrict__ perm,
                          int* __restrict__ outp, int Vsrc, int numS, int total){
  int id = blockIdx.x*256 + threadIdx.x;
  if (id >= total) return;
  int j = id & 3, s = (id>>2) % numS, b = id/(numS*4);
  outp[id] = idxsrc[((size_t)b*Vsrc + perm[s])*20 + j];
}

__global__ void k_dirs(const float* __restrict__ verts, int V, const int* __restrict__ idx,
                       float* __restrict__ dirs, int total){
  int id = blockIdx.x*256 + threadIdx.x;
  if (id >= total) return;
  int v = (id/20) % V, b = id/(20*V);
  const float* vb = verts + (size_t)b*V*3;
  int nb = idx[id];
  float dx = vb[nb*3+0]-vb[v*3+0];
  float dy = vb[nb*3+1]-vb[v*3+1];
  float dz = vb[nb*3+2]-vb[v*3+2];
  float s = 1.f / fmaxf(sqrtf(dx*dx+dy*dy+dz*dz), 1e-12f);
  dirs[(size_t)id*3+0]=dx*s; dirs[(size_t)id*3+1]=dy*s; dirs[(size_t)id*3+2]=dz*s;
}

__global__ void k_surf(const float* __restrict__ dirs, const float* __restrict__ dir0,
                       ushort* __restrict__ fh, ushort* __restrict__ fl, int V){
  int id = blockIdx.x*256 + threadIdx.x;
  if (id >= BB*V*32) return;
  int k = id & 31; int vv = (id>>5) % V; int b = id/(32*V);
  float nx=dir0[k], ny=dir0[32+k], nz=dir0[64+k];
  float s = 1.f/fmaxf(sqrtf(nx*nx+ny*ny+nz*nz), 1e-12f);
  nx*=s; ny*=s; nz*=s;
  const float* dd = dirs + (size_t)(b*V+vv)*60;
  float m = 0.f;
  for (int n=0;n<20;n++){
    float th = dd[n*3]*nx + dd[n*3+1]*ny + dd[n*3+2]*nz;
    m = fmaxf(m, fmaxf(th, 0.f));
  }
  ushort h,l; splitbf(m, h, l);
  size_t p = (size_t)(b*V+vv)*32 + k;
  fh[p]=h; fl[p]=l;
}

// out = [relu]( feat[:, :OC] + max_n( relu(dirs . ndir_col) * feat[nb, OC: ] ) )
template<int OUT>
__global__ void k_comb(const float* __restrict__ feat, const int* __restrict__ idx,
                       const float* __restrict__ dirs, const float* __restrict__ dw,
                       float* __restrict__ outp, ushort* __restrict__ oh, ushort* __restrict__ ol,
                       int V, int OC, int relu_flag){
  int id = blockIdx.x*256 + threadIdx.x;
  if (id >= BB*V*OC) return;
  int oc = id % OC, v = (id/OC) % V, b = id/(OC*V);
  float wx=dw[oc], wy=dw[OC+oc], wz=dw[2*OC+oc];
  float s = 1.f/fmaxf(sqrtf(wx*wx+wy*wy+wz*wz), 1e-12f);
  wx*=s; wy*=s; wz*=s;
  size_t row = (size_t)b*V + v;
  const int* ir = idx + row*20;
  const float* dd = dirs + row*60;
  float center = feat[row*2*OC + oc];
  float m = -INFINITY;
  for (int n=0;n<20;n++){
    int nb = ir[n];
    float th = dd[n*3]*wx + dd[n*3+1]*wy + dd[n*3+2]*wz;
    th = fmaxf(th, 0.f);
    float sup = feat[((size_t)b*V + nb)*2*OC + OC + oc];
    m = fmaxf(m, th*sup);
  }
  float rv = center + m;
  if (OUT == 0){
    outp[row*OC + oc] = relu_flag ? fmaxf(rv, 0.f) : rv;
  } else {
    rv = fmaxf(rv, 0.f);
    ushort h,l; splitbf(rv, h, l);
    oh[row*OC + oc]=h; ol[row*OC + oc]=l;
  }
}

template<int OUT>
__global__ void k_pool(const float* __restrict__ fm, const int* __restrict__ idx4,
                       float* __restrict__ outp, ushort* __restrict__ oh, ushort* __restrict__ ol,
                       int V, int C, int numS){
  int id = blockIdx.x*256 + threadIdx.x;
  if (id >= BB*numS*C) return;
  int c = id % C, sI = (id/C) % numS, b = id/(C*numS);
  const int* ir = idx4 + ((size_t)b*numS + sI)*4;
  float m = -INFINITY;
  for (int n=0;n<4;n++) m = fmaxf(m, fm[((size_t)b*V + ir[n])*C + c]);
  size_t p = ((size_t)b*numS + sI)*C + c;
  if (OUT == 0) outp[p] = m;
  else { ushort h,l; splitbf(m, h, l); oh[p]=h; ol[p]=l; }
}

__global__ void k_vgather(const float* __restrict__ vin, const int* __restrict__ perm,
                          float* __restrict__ vout, float* __restrict__ vbcs,
                          int V, int numS){
  int id = blockIdx.x*256 + threadIdx.x;
  if (id >= BB*numS*3) return;
  int c = id % 3, sI = (id/3) % numS, b = id/(3*numS);
  float val = vin[((size_t)b*V + perm[sI])*3 + c];
  vout[id] = val;
  vbcs[((size_t)b*3 + c)*numS + sI] = val;
}

__global__ void k_colmax(const float* __restrict__ x, float* __restrict__ o, int Vr, int C){
  int id = blockIdx.x*256 + threadIdx.x;
  if (id >= BB*C) return;
  int c = id % C, b = id / C;
  float m = -INFINITY;
  for (int v=0; v<Vr; v++) m = fmaxf(m, x[(size_t)(b*Vr+v)*C + c]);
  o[id] = m;
}

/* ---------------- FC head ---------------- */

__global__ __launch_bounds__(256) void k_emb2(const float* __restrict__ xmax, const float* __restrict__ fg,
                                              const float* __restrict__ fcw, const float* __restrict__ fcb,
                                              float* __restrict__ outp){
  int gid = blockIdx.x*4 + (threadIdx.x>>6);
  int lane = threadIdx.x & 63;
  if (gid >= BB*512) return;
  int e = gid & 511, b = gid >> 9;
  const float* wr = fcw + (size_t)e*2048;
  const float* xb = xmax + b*1024;
  const float* gb = fg + b*1024;
  float acc = 0.f;
  for (int k=lane; k<1024; k+=64)
    acc += xb[k]*wr[k] + gb[k]*wr[1024+k];
  #pragma unroll
  for (int off=32; off>0; off>>=1) acc += __shfl_xor(acc, off, 64);
  if (lane==0) outp[gid] = acc + fcb[e];
}

__global__ __launch_bounds__(256) void k_h2(const float* __restrict__ xmax, const float* __restrict__ fg,
                                            const float* __restrict__ clw1, const float* __restrict__ clb1,
                                            const float* __restrict__ gamma, const float* __restrict__ beta,
                                            float* __restrict__ h){
  int gid = blockIdx.x*4 + (threadIdx.x>>6);
  int lane = threadIdx.x & 63;
  if (gid >= BB*512) return;
  int j = gid & 511, b = gid >> 9;
  const float* wr = clw1 + (size_t)j*2048;
  const float* xb = xmax + b*1024;
  const float* gb = fg + b*1024;
  float acc = 0.f;
  for (int k=lane; k<1024; k+=64)
    acc += xb[k]*wr[k] + gb[k]*wr[1024+k];
  #pragma unroll
  for (int off=32; off>0; off>>=1) acc += __shfl_xor(acc, off, 64);
  if (lane==0){
    const float inv_s = 1.0f / sqrtf(1.0f + 1e-5f);
    float v = (acc + clb1[j]) * inv_s * gamma[j] + beta[j];
    h[gid] = fmaxf(v, 0.f);
  }
}

__global__ __launch_bounds__(256) void k_pred2(const float* __restrict__ h, const float* __restrict__ clw2,
                                               const float* __restrict__ clb2, float* __restrict__ outp){
  int gid = blockIdx.x*4 + (threadIdx.x>>6);
  int lane = threadIdx.x & 63;
  if (gid >= BB*6) return;
  int o = gid % 6, b = gid / 6;
  const float* hb = h + b*512;
  const float* wr = clw2 + o*512;
  float acc = 0.f;
  for (int k=lane; k<512; k+=64) acc += hb[k]*wr[k];
  #pragma unroll
  for (int off=32; off>0; off>>=1) acc += __shfl_xor(acc, off, 64);
  if (lane==0) outp[BB*512 + gid] = acc + clb2[o];
}

/* ---------------- launch ---------------- */

static inline int cdiv(long long a, int b){ return (int)((a + b - 1)/b); }

extern "C" void kernel_launch(void* const* d_in, const int* in_sizes, int n_in,
                              void* d_out, int out_size, void* d_ws, size_t ws_size,
                              hipStream_t stream){
  float* out = (float*)d_out;
  if (n_in != 30 || in_sizes[0] != BB*3*NN || out_size != BB*512 + BB*6){
    k_sentinel<<<cdiv(out_size,256),256,0,stream>>>(out, out_size, 2000.0f);
    return;
  }
  const float* xyz  = (const float*)d_in[0];
  const float* w1   = (const float*)d_in[1];
  const float* b1   = (const float*)d_in[2];
  const float* w2   = (const float*)d_in[3];
  const float* b2   = (const float*)d_in[4];
  const float* w3   = (const float*)d_in[5];
  const float* b3   = (const float*)d_in[6];
  const float* w4   = (const float*)d_in[7];
  const float* b4   = (const float*)d_in[8];
  const float* fcw  = (const float*)d_in[9];
  const float* fcb  = (const float*)d_in[10];
  const float* dir0 = (const float*)d_in[11];
  const float* wc1  = (const float*)d_in[12];
  const float* bc1  = (const float*)d_in[13];
  const float* dir1 = (const float*)d_in[14];
  const float* wc2  = (const float*)d_in[15];
  const float* bc2  = (const float*)d_in[16];
  const float* dir2 = (const float*)d_in[17];
  const float* wc3  = (const float*)d_in[18];
  const float* bc3  = (const float*)d_in[19];
  const float* dir3 = (const float*)d_in[20];
  const float* wc4  = (const float*)d_in[21];
  const float* bc4  = (const float*)d_in[22];
  const float* dir4 = (const float*)d_in[23];
  const float* clw1 = (const float*)d_in[24];
  const float* clb1 = (const float*)d_in[25];
  const float* gma  = (const float*)d_in[26];
  const float* bta  = (const float*)d_in[27];
  const float* clw2 = (const float*)d_in[28];
  const float* clb2 = (const float*)d_in[29];

  char* w = (char*)d_ws;
  size_t off = 0;
  auto A = [&](size_t bytes){ size_t r = off; off += (bytes + 255) & ~(size_t)255; return r; };
  const size_t oXMAX = A((size_t)BB*1024*4);
  const size_t oFG   = A((size_t)BB*1024*4);
  const size_t oGF   = A((size_t)BB*128*4);
  const size_t oGFP  = A((size_t)BB*128*2*2);
  const size_t oH    = A((size_t)BB*512*4);
  const size_t oP2048= A(2048*4);
  const size_t oP512 = A(512*4);
  const size_t oPKEY = A(2048*4);
  const size_t oPA   = A(2048*4);
  const size_t oPMAX = A((size_t)BB*1024*32*4);
  const size_t oV0   = A((size_t)BB*2048*3*4);
  const size_t oV1   = A((size_t)BB*512*3*4);
  const size_t oV2   = A((size_t)BB*128*3*4);
  const size_t oV1S  = A((size_t)BB*3*512*4);
  const size_t oV2S  = A((size_t)BB*3*128*4);
  const size_t oIDX0 = A((size_t)BB*2048*20*4);   // aliased by x2T planes (dead before knn)
  const size_t oDIR0 = A((size_t)BB*2048*20*3*4);
  const size_t oFM0  = A((size_t)BB*2048*32*2*2);
  const size_t oFM1  = A((size_t)BB*2048*64*4);
  const size_t oI40  = A((size_t)BB*512*4*4);
  const size_t oFM1P = A((size_t)BB*512*64*2*2);
  const size_t oIDX1 = A((size_t)BB*512*20*4);
  const size_t oDIR1 = A((size_t)BB*512*20*3*4);
  const size_t oFM2  = A((size_t)BB*512*128*2*2);
  const size_t oFM3  = A((size_t)BB*512*256*4);
  const size_t oI41  = A((size_t)BB*128*4*4);
  const size_t oFM3P = A((size_t)BB*128*256*2*2);
  const size_t oIDX2 = A((size_t)BB*128*20*4);
  const size_t oDIR2 = A((size_t)BB*128*20*3*4);
  const size_t oFM4  = A((size_t)BB*128*1024*4);
  const size_t oBIGA = A((size_t)BB*256*NN*4);    // x1T planes then x3T planes
  const size_t oBIGB = A((size_t)BB*128*NN*4);    // x2 f32, then feat f32
  const size_t oW2P  = A((size_t)128*64*2*2);
  const size_t oW3P  = A((size_t)256*256*2*2);
  const size_t oW4P  = A((size_t)1024*256*2*2);
  const size_t oWC1T = A((size_t)32*128*2*2);
  const size_t oWC2T = A((size_t)64*256*2*2);
  const size_t oWC3T = A((size_t)128*512*2*2);
  const size_t oWC4T = A((size_t)256*2048*2*2);
  if (off > ws_size){
    k_sentinel<<<cdiv(out_size,256),256,0,stream>>>(out, out_size, 1000.0f);
    return;
  }
  float* xmax = (float*)(w+oXMAX); float* fg = (float*)(w+oFG);
  float* gf = (float*)(w+oGF);     float* hbuf = (float*)(w+oH);
  ushort* gfh = (ushort*)(w+oGFP); ushort* gfl = gfh + BB*128;
  int* p2048 = (int*)(w+oP2048);   int* p512 = (int*)(w+oP512);
  unsigned* pkeys = (unsigned*)(w+oPKEY); int* pa = (int*)(w+oPA);
  float* pmax = (float*)(w+oPMAX);
  float* v0 = (float*)(w+oV0); float* v1 = (float*)(w+oV1); float* v2 = (float*)(w+oV2);
  float* v1s = (float*)(w+oV1S); float* v2s = (float*)(w+oV2S);
  int* idx0 = (int*)(w+oIDX0); int* idx1 = (int*)(w+oIDX1); int* idx2 = (int*)(w+oIDX2);
  int* i40 = (int*)(w+oI40);   int* i41 = (int*)(w+oI41);
  float* d0 = (float*)(w+oDIR0); float* d1 = (float*)(w+oDIR1); float* d2 = (float*)(w+oDIR2);
  ushort* fm0h = (ushort*)(w+oFM0); ushort* fm0l = fm0h + (size_t)BB*2048*32;
  float* fm1 = (float*)(w+oFM1);
  ushort* fm1ph = (ushort*)(w+oFM1P); ushort* fm1pl = fm1ph + (size_t)BB*512*64;
  ushort* fm2h = (ushort*)(w+oFM2); ushort* fm2l = fm2h + (size_t)BB*512*128;
  float* fm3 = (float*)(w+oFM3);
  ushort* fm3ph = (ushort*)(w+oFM3P); ushort* fm3pl = fm3ph + (size_t)BB*128*256;
  float* fm4 = (float*)(w+oFM4);
  ushort* x1h = (ushort*)(w+oBIGA); ushort* x1l = x1h + (size_t)BB*2048*64;
  ushort* x3h = (ushort*)(w+oBIGA); ushort* x3l = x3h + (size_t)BB*2048*256;
  ushort* x2h = (ushort*)(w+oIDX0); ushort* x2l = x2h + (size_t)BB*2048*128;
  float* x2 = (float*)(w+oBIGB); float* feat = (float*)(w+oBIGB);
  ushort* w2ph = (ushort*)(w+oW2P); ushort* w2pl = w2ph + 128*64;
  ushort* w3ph = (ushort*)(w+oW3P); ushort* w3pl = w3ph + 256*256;
  ushort* w4ph = (ushort*)(w+oW4P); ushort* w4pl = w4ph + 1024*256;
  ushort* wc1h = (ushort*)(w+oWC1T); ushort* wc1l = wc1h + 32*128;
  ushort* wc2h = (ushort*)(w+oWC2T); ushort* wc2l = wc2h + 64*256;
  ushort* wc3h = (ushort*)(w+oWC3T); ushort* wc3l = wc3h + 128*512;
  ushort* wc4h = (ushort*)(w+oWC4T); ushort* wc4l = wc4h + 256*2048;

  // weight pre-split
  k_wsrm<<<cdiv(128*64,256),256,0,stream>>>(w2, w2ph, w2pl, 128*64);
  k_wsrm<<<cdiv(256*256,256),256,0,stream>>>(w3, w3ph, w3pl, 256*256);
  k_wsrm<<<cdiv(1024*256,256),256,0,stream>>>(w4, w4ph, w4pl, 1024*256);
  k_wstr<<<cdiv(32*128,256),256,0,stream>>>(wc1, wc1h, wc1l, 32, 128);
  k_wstr<<<cdiv(64*256,256),256,0,stream>>>(wc2, wc2h, wc2l, 64, 256);
  k_wstr<<<cdiv(128*512,256),256,0,stream>>>(wc3, wc3h, wc3l, 128, 512);
  k_wstr<<<cdiv(256*2048,256),256,0,stream>>>(wc4, wc4h, wc4l, 256, 2048);

  // MLP branch
  k_mlp1s<<<cdiv((long long)BB*NN*64,256),256,0,stream>>>(xyz, w1, b1, x1h, x1l);
  k_bgemm<2,1,0><<<dim3(32,1,BB),256,0,stream>>>(w2ph, w2pl, x1h, x1l, nullptr, nullptr,
      b2, x2, nullptr, x2h, x2l, 64, 64, 64, 2048, (size_t)2048*64, (size_t)128*2048, 128);
  k_rowmax<<<BB*128,256,0,stream>>>(x2, gf, gfh, gfl, NN);
  k_bgemm<3,1,0><<<dim3(32,2,BB),256,0,stream>>>(w3ph, w3pl, x2h, x2l, gfh, gfl,
      b3, nullptr, nullptr, x3h, x3l, 256, 128, 128, 2048, (size_t)2048*128, 0, 256);
  k_bgemm<1,1,0><<<dim3(32,8,BB),256,0,stream>>>(w4ph, w4pl, x3h, x3l, nullptr, nullptr,
      b4, nullptr, pmax, nullptr, nullptr, 256, 256, 256, 2048, (size_t)2048*256, 0, 1024);
  k_xmax<<<cdiv(BB*1024,256),256,0,stream>>>(pmax, xmax);

  // permutations
  {
    unsigned ck0=0u, ck1=1u, nk0,nk1, s00,s01, s10,s11, sc0,sc1;
    tf2h(ck0,ck1, 0u,0u, nk0,nk1);
    tf2h(ck0,ck1, 0u,1u, s00,s01);
    tf2h(nk0,nk1, 0u,1u, s10,s11);
    tf2h(0u,2u,  0u,1u, sc0,sc1);
    k_permkeys<<<8,256,0,stream>>>(2048, s00, s01, pkeys);
    k_permrank<<<8,256,0,stream>>>(2048, pkeys, nullptr, pa);
    k_permkeys<<<8,256,0,stream>>>(2048, s10, s11, pkeys);
    k_permrank<<<8,256,0,stream>>>(2048, pkeys, pa, p2048);
    k_permkeys<<<2,256,0,stream>>>(512, sc0, sc1, pkeys);
    k_permrank<<<2,256,0,stream>>>(512, pkeys, nullptr, p512);
  }

  // graph branch: stage 0 (V=2048)
  k_transpose<<<cdiv((long long)BB*NN*3,256),256,0,stream>>>(xyz, v0);
  k_knn_r<32,20><<<dim3(512,BB),256,0,stream>>>(xyz, nullptr, 2048, idx0);
  k_dirs<<<cdiv((long long)BB*2048*20,256),256,0,stream>>>(v0, 2048, idx0, d0, BB*2048*20);
  k_surf<<<cdiv((long long)BB*2048*32,256),256,0,stream>>>(d0, dir0, fm0h, fm0l, 2048);
  k_bgemm<0,0,1><<<dim3(2,256,1),256,0,stream>>>(fm0h, fm0l, wc1h, wc1l, nullptr, nullptr,
      bc1, feat, nullptr, nullptr, nullptr, 32, 32, 32, 128, 0, 0, BB*2048);
  k_comb<0><<<cdiv((long long)BB*2048*64,256),256,0,stream>>>(feat, idx0, d0, dir1, fm1, nullptr, nullptr, 2048, 64, 1);
  // pool 1 (pool KNN = prefix of idx0)
  k_poolidx<<<cdiv(BB*512*4,256),256,0,stream>>>(idx0, p2048, i40, 2048, 512, BB*512*4);
  k_pool<1><<<cdiv((long long)BB*512*64,256),256,0,stream>>>(fm1, i40, nullptr, fm1ph, fm1pl, 2048, 64, 512);
  k_vgather<<<cdiv((long long)BB*512*3,256),256,0,stream>>>(v0, p2048, v1, v1s, 2048, 512);
  // stage 1 (V=512)
  k_knn_r<8,20><<<dim3(128,BB),256,0,stream>>>(v1s, nullptr, 512, idx1);
  k_dirs<<<cdiv((long long)BB*512*20,256),256,0,stream>>>(v1, 512, idx1, d1, BB*512*20);
  k_bgemm<0,0,1><<<dim3(4,64,1),256,0,stream>>>(fm1ph, fm1pl, wc2h, wc2l, nullptr, nullptr,
      bc2, feat, nullptr, nullptr, nullptr, 64, 64, 64, 256, 0, 0, BB*512);
  k_comb<1><<<cdiv((long long)BB*512*128,256),256,0,stream>>>(feat, idx1, d1, dir2, nullptr, fm2h, fm2l, 512, 128, 1);
  k_bgemm<0,0,1><<<dim3(8,64,1),256,0,stream>>>(fm2h, fm2l, wc3h, wc3l, nullptr, nullptr,
      bc3, feat, nullptr, nullptr, nullptr, 128, 128, 128, 512, 0, 0, BB*512);
  k_comb<0><<<cdiv((long long)BB*512*256,256),256,0,stream>>>(feat, idx1, d1, dir3, fm3, nullptr, nullptr, 512, 256, 1);
  // pool 2 (pool KNN = prefix of idx1)
  k_poolidx<<<cdiv(BB*128*4,256),256,0,stream>>>(idx1, p512, i41, 512, 128, BB*128*4);
  k_pool<1><<<cdiv((long long)BB*128*256,256),256,0,stream>>>(fm3, i41, nullptr, fm3ph, fm3pl, 512, 256, 128);
  k_vgather<<<cdiv((long long)BB*128*3,256),256,0,stream>>>(v1, p512, v2, v2s, 512, 128);
  // stage 2 (V=128)
  k_knn_r<2,20><<<dim3(32,BB),256,0,stream>>>(v2s, nullptr, 128, idx2);
  k_dirs<<<cdiv((long long)BB*128*20,256),256,0,stream>>>(v2, 128, idx2, d2, BB*128*20);
  k_bgemm<0,0,1><<<dim3(32,16,1),256,0,stream>>>(fm3ph, fm3pl, wc4h, wc4l, nullptr, nullptr,
      bc4, feat, nullptr, nullptr, nullptr, 256, 256, 256, 2048, 0, 0, BB*128);
  k_comb<0><<<cdiv((long long)BB*128*1024,256),256,0,stream>>>(feat, idx2, d2, dir4, fm4, nullptr, nullptr, 128, 1024, 0);
  k_colmax<<<cdiv(BB*1024,256),256,0,stream>>>(fm4, fg, 128, 1024);

  // FC head
  k_emb2<<<cdiv(BB*512,4),256,0,stream>>>(xmax, fg, fcw, fcb, out);
  k_h2<<<cdiv(BB*512,4),256,0,stream>>>(xmax, fg, clw1, clb1, gma, bta, hbuf);
  k_pred2<<<cdiv(BB*6,4),256,0,stream>>>(hbuf, clw2, clb2, out);
}

// Round 9
// 718.115 us; speedup vs baseline: 3.4305x; 1.0639x over previous
//
#include <hip/hip_runtime.h>
#include <hip/hip_bf16.h>
#include <math.h>

#define BB 16
#define NN 2048

typedef __attribute__((ext_vector_type(8))) short s8v;
typedef __attribute__((ext_vector_type(4))) float f4v;

__global__ void k_sentinel(float* o, int n, float v){
  int i = blockIdx.x*256 + threadIdx.x;
  if (i < n) o[i] = v;
}

__device__ __forceinline__ ushort f2bf(float x){
  unsigned u = __float_as_uint(x);
  unsigned r = u + 0x7FFFu + ((u>>16)&1u);
  return (ushort)(r>>16);
}
__device__ __forceinline__ void splitbf(float v, ushort &h, ushort &l){
  h = f2bf(v);
  float hf = __uint_as_float((unsigned)h<<16);
  l = f2bf(v-hf);
}

/* ---------------- weight pre-split (merged) ---------------- */

__global__ void k_wsplit3(const float* __restrict__ s1, ushort* __restrict__ d1h, ushort* __restrict__ d1l, int n1,
                          const float* __restrict__ s2, ushort* __restrict__ d2h, ushort* __restrict__ d2l, int n2,
                          const float* __restrict__ s3, ushort* __restrict__ d3h, ushort* __restrict__ d3l, int n3){
  int id = blockIdx.x*256 + threadIdx.x;
  const float* s; ushort *dh, *dl; int i;
  if (id < n1){ s=s1; dh=d1h; dl=d1l; i=id; }
  else if (id < n1+n2){ s=s2; dh=d2h; dl=d2l; i=id-n1; }
  else if (id < n1+n2+n3){ s=s3; dh=d3h; dl=d3l; i=id-n1-n2; }
  else return;
  ushort h,l; splitbf(s[i], h, l);
  dh[i]=h; dl[i]=l;
}

// [K][C] -> transposed planes [C][K], 4 segments
__global__ void k_wstr4(const float* __restrict__ s1, ushort* __restrict__ d1h, ushort* __restrict__ d1l, int K1, int C1,
                        const float* __restrict__ s2, ushort* __restrict__ d2h, ushort* __restrict__ d2l, int K2, int C2,
                        const float* __restrict__ s3, ushort* __restrict__ d3h, ushort* __restrict__ d3l, int K3, int C3,
                        const float* __restrict__ s4, ushort* __restrict__ d4h, ushort* __restrict__ d4l, int K4, int C4){
  int id = blockIdx.x*256 + threadIdx.x;
  int n1=K1*C1, n2=K2*C2, n3=K3*C3, n4=K4*C4;
  const float* s; ushort *dh, *dl; int i, K, C;
  if (id < n1){ s=s1; dh=d1h; dl=d1l; i=id; K=K1; C=C1; }
  else if (id < n1+n2){ s=s2; dh=d2h; dl=d2l; i=id-n1; K=K2; C=C2; }
  else if (id < n1+n2+n3){ s=s3; dh=d3h; dl=d3l; i=id-n1-n2; K=K3; C=C3; }
  else if (id < n1+n2+n3+n4){ s=s4; dh=d4h; dl=d4l; i=id-n1-n2-n3; K=K4; C=C4; }
  else return;
  int c = i % C, k = i / C;
  ushort h,l; splitbf(s[i], h, l);
  dh[(size_t)c*K + k]=h; dl[(size_t)c*K + k]=l;
}

/* ---------------- MLP branch ---------------- */

__global__ void k_mlp1s(const float* __restrict__ xyz, const float* __restrict__ w1,
                        const float* __restrict__ b1, ushort* __restrict__ xh,
                        ushort* __restrict__ xl){
  int id = blockIdx.x*256 + threadIdx.x;
  if (id >= BB*NN*64) return;
  int o = id & 63, n = (id>>6) & (NN-1), b = id>>17;
  float acc = b1[o];
  #pragma unroll
  for (int c=0;c<3;c++)
    acc += w1[o*3+c] * xyz[(size_t)(b*3+c)*NN + n];
  acc = fmaxf(acc, 0.f);
  ushort h,l; splitbf(acc, h, l);
  xh[id]=h; xl[id]=l;
}

// finish gf: max over `parts` partials, emit split planes
__global__ void k_gmax(const float* __restrict__ pmax, ushort* __restrict__ gh,
                       ushort* __restrict__ gl, int parts, int total){
  int id = blockIdx.x*256 + threadIdx.x;
  if (id >= total) return;
  float m = pmax[(size_t)id*parts];
  for (int k=1;k<parts;k++) m = fmaxf(m, pmax[(size_t)id*parts+k]);
  ushort h,l; splitbf(m, h, l);
  gh[id]=h; gl[id]=l;
}

/* ---------------- pre-split bf16 MFMA GEMM ----------------
   EPI: 0 = f32 out; 1 = relu+colmax -> pmax; 3 = splitT planes only;
        4 = relu + splitT planes + colmax partials. */
template<int EPI, int RELU, int BCOL>
__global__ __launch_bounds__(256) void k_bgemm(
    const ushort* __restrict__ Ahg, const ushort* __restrict__ Alg,
    const ushort* __restrict__ Bhg, const ushort* __restrict__ Blg,
    const ushort* __restrict__ gfh, const ushort* __restrict__ gfl,
    const float* __restrict__ bias,
    float* __restrict__ outp, float* __restrict__ pmaxp,
    ushort* __restrict__ oth, ushort* __restrict__ otl,
    int K, int ksplit, int Kb, int N, size_t sBT, size_t sOut, int M)
{
  __shared__ ushort Ah[128][40], Al[128][40];
  __shared__ ushort Bh[64][40],  Bl[64][40];
  __shared__ float red[2][128];
  int t = threadIdx.x, z = blockIdx.z;
  int o0 = blockIdx.y*128, n0 = blockIdx.x*64;
  int wid = t>>6, lane = t&63;
  int wm = wid>>1, wn = wid&1;
  int lr = lane&15, kg = lane>>4;

  f4v acc[4][2];
  #pragma unroll
  for (int i=0;i<4;i++)
    #pragma unroll
    for (int j=0;j<2;j++) acc[i][j] = (f4v){0.f,0.f,0.f,0.f};

  for (int k0=0; k0<K; k0+=32){
    __syncthreads();
    #pragma unroll
    for (int i=0;i<2;i++){
      int j = i*256+t, oo = j>>2, k8 = (j&3)*8;
      size_t sp = (size_t)(o0+oo)*K + k0 + k8;
      *(s8v*)&Ah[oo][k8] = *(const s8v*)(Ahg+sp);
      *(s8v*)&Al[oo][k8] = *(const s8v*)(Alg+sp);
    }
    {
      int nn = t>>2, k8 = (t&3)*8, gk = k0+k8;
      const ushort *sh, *sl;
      if (gk < ksplit){
        size_t sp = (size_t)z*sBT + (size_t)(n0+nn)*Kb + gk;
        sh = Bhg+sp; sl = Blg+sp;
      } else {
        size_t sp = (size_t)z*(K-ksplit) + (gk-ksplit);
        sh = gfh+sp; sl = gfl+sp;
      }
      *(s8v*)&Bh[nn][k8] = *(const s8v*)sh;
      *(s8v*)&Bl[nn][k8] = *(const s8v*)sl;
    }
    __syncthreads();

    s8v ah[4], al[4], bh[2], bl[2];
    #pragma unroll
    for (int mt=0;mt<4;mt++){
      int row = wm*64 + mt*16 + lr;
      ah[mt] = *(const s8v*)&Ah[row][kg*8];
      al[mt] = *(const s8v*)&Al[row][kg*8];
    }
    #pragma unroll
    for (int nt=0;nt<2;nt++){
      int col = wn*32 + nt*16 + lr;
      bh[nt] = *(const s8v*)&Bh[col][kg*8];
      bl[nt] = *(const s8v*)&Bl[col][kg*8];
    }
    #pragma unroll
    for (int mt=0;mt<4;mt++)
      #pragma unroll
      for (int nt=0;nt<2;nt++){
        acc[mt][nt] = __builtin_amdgcn_mfma_f32_16x16x32_bf16(ah[mt], bh[nt], acc[mt][nt], 0,0,0);
        acc[mt][nt] = __builtin_amdgcn_mfma_f32_16x16x32_bf16(ah[mt], bl[nt], acc[mt][nt], 0,0,0);
        acc[mt][nt] = __builtin_amdgcn_mfma_f32_16x16x32_bf16(al[mt], bh[nt], acc[mt][nt], 0,0,0);
      }
  }

  if (EPI == 1 || EPI == 4){
    #pragma unroll
    for (int mt=0;mt<4;mt++){
      #pragma unroll
      for (int e=0;e<4;e++){
        int row = o0 + wm*64 + mt*16 + kg*4 + e;
        float bv = bias[row];
        float v0 = fmaxf(acc[mt][0][e]+bv, 0.f);
        float v1 = fmaxf(acc[mt][1][e]+bv, 0.f);
        if (EPI == 4){
          int col0 = n0 + wn*32 + lr;
          ushort h,l;
          splitbf(v0, h, l);
          size_t p0 = ((size_t)z*N + col0)*(size_t)M + row;
          oth[p0]=h; otl[p0]=l;
          splitbf(v1, h, l);
          size_t p1 = ((size_t)z*N + col0+16)*(size_t)M + row;
          oth[p1]=h; otl[p1]=l;
        }
        float m = fmaxf(v0, v1);
        m = fmaxf(m, __shfl_xor(m, 1, 64));
        m = fmaxf(m, __shfl_xor(m, 2, 64));
        m = fmaxf(m, __shfl_xor(m, 4, 64));
        m = fmaxf(m, __shfl_xor(m, 8, 64));
        if (lr == 0) red[wn][wm*64 + mt*16 + kg*4 + e] = m;
      }
    }
    __syncthreads();
    if (t < 128){
      float m = fmaxf(red[0][t], red[1][t]);
      pmaxp[((size_t)z*M + o0 + t)*gridDim.x + blockIdx.x] = m;
    }
  } else {
    #pragma unroll
    for (int mt=0;mt<4;mt++){
      #pragma unroll
      for (int nt=0;nt<2;nt++){
        int col = n0 + wn*32 + nt*16 + lr;
        #pragma unroll
        for (int e=0;e<4;e++){
          int row = o0 + wm*64 + mt*16 + kg*4 + e;
          float bv = BCOL ? bias[col] : bias[row];
          float v = acc[mt][nt][e] + bv;
          if (RELU) v = fmaxf(v, 0.f);
          if (EPI == 0)
            outp[(size_t)z*sOut + (size_t)row*N + col] = v;
          if (EPI == 3){
            ushort h,l; splitbf(v, h, l);
            size_t p = ((size_t)z*N + col)*(size_t)M + row;
            oth[p]=h; otl[p]=l;
          }
        }
      }
    }
  }
}

__global__ void k_xmax(const float* __restrict__ pmax, float* __restrict__ xmax){
  int id = blockIdx.x*256 + threadIdx.x;
  if (id >= BB*1024) return;
  float m = pmax[(size_t)id*32];
  for (int k=1;k<32;k++) m = fmaxf(m, pmax[(size_t)id*32+k]);
  xmax[id] = m;
}

/* ---------------- JAX threefry PRNG permutation ---------------- */

#define TF2BODY \
  unsigned ks2 = 0x1BD11BDAu ^ k0 ^ k1; \
  unsigned a = x0 + k0, b = x1 + k1; \
  { \
  a += b; b = (b<<13)|(b>>19); b ^= a; \
  a += b; b = (b<<15)|(b>>17); b ^= a; \
  a += b; b = (b<<26)|(b>>6);  b ^= a; \
  a += b; b = (b<<6) |(b>>26); b ^= a;  a += k1;  b += ks2 + 1u; \
  a += b; b = (b<<17)|(b>>15); b ^= a; \
  a += b; b = (b<<29)|(b>>3);  b ^= a; \
  a += b; b = (b<<16)|(b>>16); b ^= a; \
  a += b; b = (b<<24)|(b>>8);  b ^= a;  a += ks2; b += k0  + 2u; \
  a += b; b = (b<<13)|(b>>19); b ^= a; \
  a += b; b = (b<<15)|(b>>17); b ^= a; \
  a += b; b = (b<<26)|(b>>6);  b ^= a; \
  a += b; b = (b<<6) |(b>>26); b ^= a;  a += k0;  b += k1  + 3u; \
  a += b; b = (b<<17)|(b>>15); b ^= a; \
  a += b; b = (b<<29)|(b>>3);  b ^= a; \
  a += b; b = (b<<16)|(b>>16); b ^= a; \
  a += b; b = (b<<24)|(b>>8);  b ^= a;  a += k1;  b += ks2 + 4u; \
  a += b; b = (b<<13)|(b>>19); b ^= a; \
  a += b; b = (b<<15)|(b>>17); b ^= a; \
  a += b; b = (b<<26)|(b>>6);  b ^= a; \
  a += b; b = (b<<6) |(b>>26); b ^= a;  a += ks2; b += k0  + 5u; \
  } \
  o0 = a; o1 = b;

__device__ __forceinline__ void tf2(unsigned k0, unsigned k1, unsigned x0, unsigned x1,
                                    unsigned &o0, unsigned &o1){ TF2BODY }
static void tf2h(unsigned k0, unsigned k1, unsigned x0, unsigned x1,
                 unsigned &o0, unsigned &o1){ TF2BODY }

// all three key arrays in one launch
__global__ void k_permkeys3(unsigned a0, unsigned a1, unsigned* __restrict__ ka,
                            unsigned b0, unsigned b1, unsigned* __restrict__ kb,
                            unsigned c0, unsigned c1, unsigned* __restrict__ kc){
  int id = blockIdx.x*256 + threadIdx.x;
  if (id < 2048){ unsigned x,y; tf2(a0,a1, 0u,(unsigned)id, x,y); ka[id] = x^y; }
  if (id < 2048){ unsigned x,y; tf2(b0,b1, 0u,(unsigned)id, x,y); kb[id] = x^y; }
  if (id < 512){ unsigned x,y; tf2(c0,c1, 0u,(unsigned)id, x,y); kc[id] = x^y; }
}

__global__ void k_permrank(int n, const unsigned* __restrict__ keys,
                           const int* __restrict__ vin, int* __restrict__ vout){
  int i = blockIdx.x*256 + threadIdx.x;
  if (i >= n) return;
  unsigned ki = keys[i];
  int rank = 0;
  for (int j=0;j<n;j++){
    unsigned kj = keys[j];
    rank += (kj < ki) || (kj == ki && j < i);
  }
  vout[rank] = vin ? vin[i] : i;
}

/* ---------------- graph branch ---------------- */

__global__ void k_transpose(const float* __restrict__ xyz, float* __restrict__ verts){
  int id = blockIdx.x*256 + threadIdx.x;
  if (id >= BB*NN*3) return;
  int c = id % 3, v = (id/3) % NN, b = id/(3*NN);
  verts[id] = xyz[(size_t)(b*3+c)*NN + v];
}

// Wave-per-query KNN v4: u32 monotone distances in regs (static idx), group
// minima as u64 (d<<32|pos), u32-only butterfly + ballot winner. Winner's
// min(g[]) IS the extracted (d,pos); refilter only its GS-slot group with
// kk > mbest. Emits the exact top-(KSEL+1) set (ties broken by (d,lane,pos) —
// deviates from XLA only on bitwise-equal f32 distances); order-insensitive
// consumers. Self (d==0 exactly) extracted at r=0 and dropped.
template<int CPL, int KSEL>
__global__ __launch_bounds__(256,4) void k_knn_s(const float* __restrict__ vbcs,
                                                 int numQ, int* __restrict__ out){
  constexpr int V = CPL*64;
  constexpr int GS = (CPL < 8) ? CPL : 8;
  constexpr int NG = CPL/GS;
  int t = threadIdx.x, wid = t>>6, lane = t&63;
  int b = blockIdx.y;
  int q = blockIdx.x*4 + wid;
  if (q >= numQ) return;
  const float* vx = vbcs + (size_t)b*3*V;
  const float* vy = vx + V;
  const float* vz = vy + V;
  float qx = vx[q], qy = vy[q], qz = vz[q];
  float qq = qx*qx + qy*qy + qz*qz;
  unsigned d[CPL];
  #pragma unroll
  for (int i=0;i<CPL;i++){
    int c = lane + i*64;
    float wx=vx[c], wy=vy[c], wz=vz[c];
    float inner = qx*wx + qy*wy + qz*wz;
    float ww = wx*wx + wy*wy + wz*wz;
    float dd = qq - 2.f*inner + ww;
    unsigned db = __float_as_uint(dd);
    d[i] = (db & 0x80000000u) ? ~db : (db | 0x80000000u);
  }
  unsigned long long g[NG];
  #pragma unroll
  for (int gg=0; gg<NG; gg++){
    unsigned long long m = ~0ull;
    #pragma unroll
    for (int j=0;j<GS;j++){
      int p = gg*GS+j;
      unsigned long long kk = ((unsigned long long)d[p]<<32) | (unsigned)p;
      m = (kk<m)?kk:m;
    }
    g[gg] = m;
  }
  unsigned lmin = (unsigned)(g[0]>>32);
  #pragma unroll
  for (int gg=1;gg<NG;gg++){ unsigned x = (unsigned)(g[gg]>>32); lmin = (x<lmin)?x:lmin; }

  int* orow = out + ((size_t)b*numQ + q)*KSEL;
  for (int r=0; r<=KSEL; r++){
    unsigned bd = lmin;
    #pragma unroll
    for (int off=32; off>0; off>>=1){
      unsigned o = __shfl_xor(bd, off, 64);
      bd = (o < bd) ? o : bd;
    }
    unsigned long long bal = __ballot(lmin == bd);
    int winner = __ffsll(bal) - 1;
    if (lane == winner){
      unsigned long long mbest = g[0];
      #pragma unroll
      for (int gg=1;gg<NG;gg++) mbest = (g[gg]<mbest)?g[gg]:mbest;
      int pos = (int)(mbest & 0xffffffffull);
      if (r>0) orow[r-1] = lane + pos*64;
      int gi = pos / GS;
      #pragma unroll
      for (int gg=0; gg<NG; gg++){
        if (gg == gi){
          unsigned long long m = ~0ull;
          #pragma unroll
          for (int j=0;j<GS;j++){
            int p = gg*GS+j;
            unsigned long long kk = ((unsigned long long)d[p]<<32) | (unsigned)p;
            if (kk <= mbest) kk = ~0ull;
            m = (kk<m)?kk:m;
          }
          g[gg] = m;
        }
      }
      unsigned nl = (unsigned)(g[0]>>32);
      #pragma unroll
      for (int gg=1;gg<NG;gg++){ unsigned x = (unsigned)(g[gg]>>32); nl = (x<nl)?x:nl; }
      lmin = nl;
    }
  }
}

// pool KNN = prefix of the stage KNN (same dist matrix, stable top-k)
__global__ void k_poolidx(const int* __restrict__ idxsrc, const int* __restrict__ perm,
                          int* __restrict__ outp, int Vsrc, int numS, int total){
  int id = blockIdx.x*256 + threadIdx.x;
  if (id >= total) return;
  int j = id & 3, s = (id>>2) % numS, b = id/(numS*4);
  outp[id] = idxsrc[((size_t)b*Vsrc + perm[s])*20 + j];
}

__global__ void k_dirs(const float* __restrict__ verts, int V, const int* __restrict__ idx,
                       float* __restrict__ dirs, int total){
  int id = blockIdx.x*256 + threadIdx.x;
  if (id >= total) return;
  int v = (id/20) % V, b = id/(20*V);
  const float* vb = verts + (size_t)b*V*3;
  int nb = idx[id];
  float dx = vb[nb*3+0]-vb[v*3+0];
  float dy = vb[nb*3+1]-vb[v*3+1];
  float dz = vb[nb*3+2]-vb[v*3+2];
  float s = 1.f / fmaxf(sqrtf(dx*dx+dy*dy+dz*dz), 1e-12f);
  dirs[(size_t)id*3+0]=dx*s; dirs[(size_t)id*3+1]=dy*s; dirs[(size_t)id*3+2]=dz*s;
}

__global__ void k_surf(const float* __restrict__ dirs, const float* __restrict__ dir0,
                       ushort* __restrict__ fh, ushort* __restrict__ fl, int V){
  int id = blockIdx.x*256 + threadIdx.x;
  if (id >= BB*V*32) return;
  int k = id & 31; int vv = (id>>5) % V; int b = id/(32*V);
  float nx=dir0[k], ny=dir0[32+k], nz=dir0[64+k];
  float s = 1.f/fmaxf(sqrtf(nx*nx+ny*ny+nz*nz), 1e-12f);
  nx*=s; ny*=s; nz*=s;
  const float* dd = dirs + (size_t)(b*V+vv)*60;
  float m = 0.f;
  for (int n=0;n<20;n++){
    float th = dd[n*3]*nx + dd[n*3+1]*ny + dd[n*3+2]*nz;
    m = fmaxf(m, fmaxf(th, 0.f));
  }
  ushort h,l; splitbf(m, h, l);
  size_t p = (size_t)(b*V+vv)*32 + k;
  fh[p]=h; fl[p]=l;
}

template<int OUT>
__global__ void k_comb(const float* __restrict__ feat, const int* __restrict__ idx,
                       const float* __restrict__ dirs, const float* __restrict__ dw,
                       float* __restrict__ outp, ushort* __restrict__ oh, ushort* __restrict__ ol,
                       int V, int OC, int relu_flag){
  int id = blockIdx.x*256 + threadIdx.x;
  if (id >= BB*V*OC) return;
  int oc = id % OC, v = (id/OC) % V, b = id/(OC*V);
  float wx=dw[oc], wy=dw[OC+oc], wz=dw[2*OC+oc];
  float s = 1.f/fmaxf(sqrtf(wx*wx+wy*wy+wz*wz), 1e-12f);
  wx*=s; wy*=s; wz*=s;
  size_t row = (size_t)b*V + v;
  const int* ir = idx + row*20;
  const float* dd = dirs + row*60;
  float center = feat[row*2*OC + oc];
  float m = -INFINITY;
  for (int n=0;n<20;n++){
    int nb = ir[n];
    float th = dd[n*3]*wx + dd[n*3+1]*wy + dd[n*3+2]*wz;
    th = fmaxf(th, 0.f);
    float sup = feat[((size_t)b*V + nb)*2*OC + OC + oc];
    m = fmaxf(m, th*sup);
  }
  float rv = center + m;
  if (OUT == 0){
    outp[row*OC + oc] = relu_flag ? fmaxf(rv, 0.f) : rv;
  } else {
    rv = fmaxf(rv, 0.f);
    ushort h,l; splitbf(rv, h, l);
    oh[row*OC + oc]=h; ol[row*OC + oc]=l;
  }
}

template<int OUT>
__global__ void k_pool(const float* __restrict__ fm, const int* __restrict__ idx4,
                       float* __restrict__ outp, ushort* __restrict__ oh, ushort* __restrict__ ol,
                       int V, int C, int numS){
  int id = blockIdx.x*256 + threadIdx.x;
  if (id >= BB*numS*C) return;
  int c = id % C, sI = (id/C) % numS, b = id/(C*numS);
  const int* ir = idx4 + ((size_t)b*numS + sI)*4;
  float m = -INFINITY;
  for (int n=0;n<4;n++) m = fmaxf(m, fm[((size_t)b*V + ir[n])*C + c]);
  size_t p = ((size_t)b*numS + sI)*C + c;
  if (OUT == 0) outp[p] = m;
  else { ushort h,l; splitbf(m, h, l); oh[p]=h; ol[p]=l; }
}

__global__ void k_vgather(const float* __restrict__ vin, const int* __restrict__ perm,
                          float* __restrict__ vout, float* __restrict__ vbcs,
                          int V, int numS){
  int id = blockIdx.x*256 + threadIdx.x;
  if (id >= BB*numS*3) return;
  int c = id % 3, sI = (id/3) % numS, b = id/(3*numS);
  float val = vin[((size_t)b*V + perm[sI])*3 + c];
  vout[id] = val;
  vbcs[((size_t)b*3 + c)*numS + sI] = val;
}

__global__ void k_colmax(const float* __restrict__ x, float* __restrict__ o, int Vr, int C){
  int id = blockIdx.x*256 + threadIdx.x;
  if (id >= BB*C) return;
  int c = id % C, b = id / C;
  float m = -INFINITY;
  for (int v=0; v<Vr; v++) m = fmaxf(m, x[(size_t)(b*Vr+v)*C + c]);
  o[id] = m;
}

/* ---------------- FC head ---------------- */

__global__ __launch_bounds__(256) void k_emb2(const float* __restrict__ xmax, const float* __restrict__ fg,
                                              const float* __restrict__ fcw, const float* __restrict__ fcb,
                                              float* __restrict__ outp){
  int gid = blockIdx.x*4 + (threadIdx.x>>6);
  int lane = threadIdx.x & 63;
  if (gid >= BB*512) return;
  int e = gid & 511, b = gid >> 9;
  const float* wr = fcw + (size_t)e*2048;
  const float* xb = xmax + b*1024;
  const float* gb = fg + b*1024;
  float acc = 0.f;
  for (int k=lane; k<1024; k+=64)
    acc += xb[k]*wr[k] + gb[k]*wr[1024+k];
  #pragma unroll
  for (int off=32; off>0; off>>=1) acc += __shfl_xor(acc, off, 64);
  if (lane==0) outp[gid] = acc + fcb[e];
}

__global__ __launch_bounds__(256) void k_h2(const float* __restrict__ xmax, const float* __restrict__ fg,
                                            const float* __restrict__ clw1, const float* __restrict__ clb1,
                                            const float* __restrict__ gamma, const float* __restrict__ beta,
                                            float* __restrict__ h){
  int gid = blockIdx.x*4 + (threadIdx.x>>6);
  int lane = threadIdx.x & 63;
  if (gid >= BB*512) return;
  int j = gid & 511, b = gid >> 9;
  const float* wr = clw1 + (size_t)j*2048;
  const float* xb = xmax + b*1024;
  const float* gb = fg + b*1024;
  float acc = 0.f;
  for (int k=lane; k<1024; k+=64)
    acc += xb[k]*wr[k] + gb[k]*wr[1024+k];
  #pragma unroll
  for (int off=32; off>0; off>>=1) acc += __shfl_xor(acc, off, 64);
  if (lane==0){
    const float inv_s = 1.0f / sqrtf(1.0f + 1e-5f);
    float v = (acc + clb1[j]) * inv_s * gamma[j] + beta[j];
    h[gid] = fmaxf(v, 0.f);
  }
}

__global__ __launch_bounds__(256) void k_pred2(const float* __restrict__ h, const float* __restrict__ clw2,
                                               const float* __restrict__ clb2, float* __restrict__ outp){
  int gid = blockIdx.x*4 + (threadIdx.x>>6);
  int lane = threadIdx.x & 63;
  if (gid >= BB*6) return;
  int o = gid % 6, b = gid / 6;
  const float* hb = h + b*512;
  const float* wr = clw2 + o*512;
  float acc = 0.f;
  for (int k=lane; k<512; k+=64) acc += hb[k]*wr[k];
  #pragma unroll
  for (int off=32; off>0; off>>=1) acc += __shfl_xor(acc, off, 64);
  if (lane==0) outp[BB*512 + gid] = acc + clb2[o];
}

/* ---------------- launch ---------------- */

static inline int cdiv(long long a, int b){ return (int)((a + b - 1)/b); }

extern "C" void kernel_launch(void* const* d_in, const int* in_sizes, int n_in,
                              void* d_out, int out_size, void* d_ws, size_t ws_size,
                              hipStream_t stream){
  float* out = (float*)d_out;
  if (n_in != 30 || in_sizes[0] != BB*3*NN || out_size != BB*512 + BB*6){
    k_sentinel<<<cdiv(out_size,256),256,0,stream>>>(out, out_size, 2000.0f);
    return;
  }
  const float* xyz  = (const float*)d_in[0];
  const float* w1   = (const float*)d_in[1];
  const float* b1   = (const float*)d_in[2];
  const float* w2   = (const float*)d_in[3];
  const float* b2   = (const float*)d_in[4];
  const float* w3   = (const float*)d_in[5];
  const float* b3   = (const float*)d_in[6];
  const float* w4   = (const float*)d_in[7];
  const float* b4   = (const float*)d_in[8];
  const float* fcw  = (const float*)d_in[9];
  const float* fcb  = (const float*)d_in[10];
  const float* dir0 = (const float*)d_in[11];
  const float* wc1  = (const float*)d_in[12];
  const float* bc1  = (const float*)d_in[13];
  const float* dir1 = (const float*)d_in[14];
  const float* wc2  = (const float*)d_in[15];
  const float* bc2  = (const float*)d_in[16];
  const float* dir2 = (const float*)d_in[17];
  const float* wc3  = (const float*)d_in[18];
  const float* bc3  = (const float*)d_in[19];
  const float* dir3 = (const float*)d_in[20];
  const float* wc4  = (const float*)d_in[21];
  const float* bc4  = (const float*)d_in[22];
  const float* dir4 = (const float*)d_in[23];
  const float* clw1 = (const float*)d_in[24];
  const float* clb1 = (const float*)d_in[25];
  const float* gma  = (const float*)d_in[26];
  const float* bta  = (const float*)d_in[27];
  const float* clw2 = (const float*)d_in[28];
  const float* clb2 = (const float*)d_in[29];

  char* w = (char*)d_ws;
  size_t off = 0;
  auto A = [&](size_t bytes){ size_t r = off; off += (bytes + 255) & ~(size_t)255; return r; };
  const size_t oXMAX = A((size_t)BB*1024*4);
  const size_t oFG   = A((size_t)BB*1024*4);
  const size_t oGFP  = A((size_t)BB*128*2*2);
  const size_t oH    = A((size_t)BB*512*4);
  const size_t oP2048= A(2048*4);
  const size_t oP512 = A(512*4);
  const size_t oPK1  = A(2048*4);
  const size_t oPK2  = A(2048*4);
  const size_t oPK3  = A(512*4);
  const size_t oPA   = A(2048*4);
  const size_t oPMAX = A((size_t)BB*1024*32*4);
  const size_t oV0   = A((size_t)BB*2048*3*4);
  const size_t oV1   = A((size_t)BB*512*3*4);
  const size_t oV2   = A((size_t)BB*128*3*4);
  const size_t oV1S  = A((size_t)BB*3*512*4);
  const size_t oV2S  = A((size_t)BB*3*128*4);
  const size_t oIDX0 = A((size_t)BB*2048*20*4);   // aliased by x2T planes (dead before knn)
  const size_t oDIR0 = A((size_t)BB*2048*20*3*4);
  const size_t oFM0  = A((size_t)BB*2048*32*2*2);
  const size_t oFM1  = A((size_t)BB*2048*64*4);
  const size_t oI40  = A((size_t)BB*512*4*4);
  const size_t oFM1P = A((size_t)BB*512*64*2*2);
  const size_t oIDX1 = A((size_t)BB*512*20*4);
  const size_t oDIR1 = A((size_t)BB*512*20*3*4);
  const size_t oFM2  = A((size_t)BB*512*128*2*2);
  const size_t oFM3  = A((size_t)BB*512*256*4);
  const size_t oI41  = A((size_t)BB*128*4*4);
  const size_t oFM3P = A((size_t)BB*128*256*2*2);
  const size_t oIDX2 = A((size_t)BB*128*20*4);
  const size_t oDIR2 = A((size_t)BB*128*20*3*4);
  const size_t oFM4  = A((size_t)BB*128*1024*4);
  const size_t oBIGA = A((size_t)BB*256*NN*4);    // x1T planes then x3T planes
  const size_t oBIGB = A((size_t)BB*128*NN*4);    // feat f32
  const size_t oW2P  = A((size_t)128*64*2*2);
  const size_t oW3P  = A((size_t)256*256*2*2);
  const size_t oW4P  = A((size_t)1024*256*2*2);
  const size_t oWC1T = A((size_t)32*128*2*2);
  const size_t oWC2T = A((size_t)64*256*2*2);
  const size_t oWC3T = A((size_t)128*512*2*2);
  const size_t oWC4T = A((size_t)256*2048*2*2);
  if (off > ws_size){
    k_sentinel<<<cdiv(out_size,256),256,0,stream>>>(out, out_size, 1000.0f);
    return;
  }
  float* xmax = (float*)(w+oXMAX); float* fg = (float*)(w+oFG);
  float* hbuf = (float*)(w+oH);
  ushort* gfh = (ushort*)(w+oGFP); ushort* gfl = gfh + BB*128;
  int* p2048 = (int*)(w+oP2048);   int* p512 = (int*)(w+oP512);
  unsigned* pk1 = (unsigned*)(w+oPK1); unsigned* pk2 = (unsigned*)(w+oPK2);
  unsigned* pk3 = (unsigned*)(w+oPK3); int* pa = (int*)(w+oPA);
  float* pmax = (float*)(w+oPMAX);
  float* v0 = (float*)(w+oV0); float* v1 = (float*)(w+oV1); float* v2 = (float*)(w+oV2);
  float* v1s = (float*)(w+oV1S); float* v2s = (float*)(w+oV2S);
  int* idx0 = (int*)(w+oIDX0); int* idx1 = (int*)(w+oIDX1); int* idx2 = (int*)(w+oIDX2);
  int* i40 = (int*)(w+oI40);   int* i41 = (int*)(w+oI41);
  float* d0 = (float*)(w+oDIR0); float* d1 = (float*)(w+oDIR1); float* d2 = (float*)(w+oDIR2);
  ushort* fm0h = (ushort*)(w+oFM0); ushort* fm0l = fm0h + (size_t)BB*2048*32;
  float* fm1 = (float*)(w+oFM1);
  ushort* fm1ph = (ushort*)(w+oFM1P); ushort* fm1pl = fm1ph + (size_t)BB*512*64;
  ushort* fm2h = (ushort*)(w+oFM2); ushort* fm2l = fm2h + (size_t)BB*512*128;
  float* fm3 = (float*)(w+oFM3);
  ushort* fm3ph = (ushort*)(w+oFM3P); ushort* fm3pl = fm3ph + (size_t)BB*128*256;
  float* fm4 = (float*)(w+oFM4);
  ushort* x1h = (ushort*)(w+oBIGA); ushort* x1l = x1h + (size_t)BB*2048*64;
  ushort* x3h = (ushort*)(w+oBIGA); ushort* x3l = x3h + (size_t)BB*2048*256;
  ushort* x2h = (ushort*)(w+oIDX0); ushort* x2l = x2h + (size_t)BB*2048*128;
  float* feat = (float*)(w+oBIGB);
  ushort* w2ph = (ushort*)(w+oW2P); ushort* w2pl = w2ph + 128*64;
  ushort* w3ph = (ushort*)(w+oW3P); ushort* w3pl = w3ph + 256*256;
  ushort* w4ph = (ushort*)(w+oW4P); ushort* w4pl = w4ph + 1024*256;
  ushort* wc1h = (ushort*)(w+oWC1T); ushort* wc1l = wc1h + 32*128;
  ushort* wc2h = (ushort*)(w+oWC2T); ushort* wc2l = wc2h + 64*256;
  ushort* wc3h = (ushort*)(w+oWC3T); ushort* wc3l = wc3h + 128*512;
  ushort* wc4h = (ushort*)(w+oWC4T); ushort* wc4l = wc4h + 256*2048;

  // weight pre-split (merged)
  k_wsplit3<<<cdiv(128*64+256*256+1024*256,256),256,0,stream>>>(
      w2, w2ph, w2pl, 128*64,  w3, w3ph, w3pl, 256*256,  w4, w4ph, w4pl, 1024*256);
  k_wstr4<<<cdiv(32*128+64*256+128*512+256*2048,256),256,0,stream>>>(
      wc1, wc1h, wc1l, 32, 128,  wc2, wc2h, wc2l, 64, 256,
      wc3, wc3h, wc3l, 128, 512, wc4, wc4h, wc4l, 256, 2048);

  // MLP branch
  k_mlp1s<<<cdiv((long long)BB*NN*64,256),256,0,stream>>>(xyz, w1, b1, x1h, x1l);
  k_bgemm<4,1,0><<<dim3(32,1,BB),256,0,stream>>>(w2ph, w2pl, x1h, x1l, nullptr, nullptr,
      b2, nullptr, pmax, x2h, x2l, 64, 64, 64, 2048, (size_t)2048*64, 0, 128);
  k_gmax<<<cdiv(BB*128,256),256,0,stream>>>(pmax, gfh, gfl, 32, BB*128);
  k_bgemm<3,1,0><<<dim3(32,2,BB),256,0,stream>>>(w3ph, w3pl, x2h, x2l, gfh, gfl,
      b3, nullptr, nullptr, x3h, x3l, 256, 128, 128, 2048, (size_t)2048*128, 0, 256);
  k_bgemm<1,1,0><<<dim3(32,8,BB),256,0,stream>>>(w4ph, w4pl, x3h, x3l, nullptr, nullptr,
      b4, nullptr, pmax, nullptr, nullptr, 256, 256, 256, 2048, (size_t)2048*256, 0, 1024);
  k_xmax<<<cdiv(BB*1024,256),256,0,stream>>>(pmax, xmax);

  // permutations
  {
    unsigned ck0=0u, ck1=1u, nk0,nk1, s00,s01, s10,s11, sc0,sc1;
    tf2h(ck0,ck1, 0u,0u, nk0,nk1);
    tf2h(ck0,ck1, 0u,1u, s00,s01);
    tf2h(nk0,nk1, 0u,1u, s10,s11);
    tf2h(0u,2u,  0u,1u, sc0,sc1);
    k_permkeys3<<<8,256,0,stream>>>(s00,s01,pk1, s10,s11,pk2, sc0,sc1,pk3);
    k_permrank<<<8,256,0,stream>>>(2048, pk1, nullptr, pa);
    k_permrank<<<8,256,0,stream>>>(2048, pk2, pa, p2048);
    k_permrank<<<2,256,0,stream>>>(512, pk3, nullptr, p512);
  }

  // graph branch: stage 0 (V=2048)
  k_transpose<<<cdiv((long long)BB*NN*3,256),256,0,stream>>>(xyz, v0);
  k_knn_s<32,20><<<dim3(512,BB),256,0,stream>>>(xyz, 2048, idx0);
  k_dirs<<<cdiv((long long)BB*2048*20,256),256,0,stream>>>(v0, 2048, idx0, d0, BB*2048*20);
  k_surf<<<cdiv((long long)BB*2048*32,256),256,0,stream>>>(d0, dir0, fm0h, fm0l, 2048);
  k_bgemm<0,0,1><<<dim3(2,256,1),256,0,stream>>>(fm0h, fm0l, wc1h, wc1l, nullptr, nullptr,
      bc1, feat, nullptr, nullptr, nullptr, 32, 32, 32, 128, 0, 0, BB*2048);
  k_comb<0><<<cdiv((long long)BB*2048*64,256),256,0,stream>>>(feat, idx0, d0, dir1, fm1, nullptr, nullptr, 2048, 64, 1);
  // pool 1 (pool KNN = prefix of idx0)
  k_poolidx<<<cdiv(BB*512*4,256),256,0,stream>>>(idx0, p2048, i40, 2048, 512, BB*512*4);
  k_pool<1><<<cdiv((long long)BB*512*64,256),256,0,stream>>>(fm1, i40, nullptr, fm1ph, fm1pl, 2048, 64, 512);
  k_vgather<<<cdiv((long long)BB*512*3,256),256,0,stream>>>(v0, p2048, v1, v1s, 2048, 512);
  // stage 1 (V=512)
  k_knn_s<8,20><<<dim3(128,BB),256,0,stream>>>(v1s, 512, idx1);
  k_dirs<<<cdiv((long long)BB*512*20,256),256,0,stream>>>(v1, 512, idx1, d1, BB*512*20);
  k_bgemm<0,0,1><<<dim3(4,64,1),256,0,stream>>>(fm1ph, fm1pl, wc2h, wc2l, nullptr, nullptr,
      bc2, feat, nullptr, nullptr, nullptr, 64, 64, 64, 256, 0, 0, BB*512);
  k_comb<1><<<cdiv((long long)BB*512*128,256),256,0,stream>>>(feat, idx1, d1, dir2, nullptr, fm2h, fm2l, 512, 128, 1);
  k_bgemm<0,0,1><<<dim3(8,64,1),256,0,stream>>>(fm2h, fm2l, wc3h, wc3l, nullptr, nullptr,
      bc3, feat, nullptr, nullptr, nullptr, 128, 128, 128, 512, 0, 0, BB*512);
  k_comb<0><<<cdiv((long long)BB*512*256,256),256,0,stream>>>(feat, idx1, d1, dir3, fm3, nullptr, nullptr, 512, 256, 1);
  // pool 2 (pool KNN = prefix of idx1)
  k_poolidx<<<cdiv(BB*128*4,256),256,0,stream>>>(idx1, p512, i41, 512, 128, BB*128*4);
  k_pool<1><<<cdiv((long long)BB*128*256,256),256,0,stream>>>(fm3, i41, nullptr, fm3ph, fm3pl, 512, 256, 128);
  k_vgather<<<cdiv((long long)BB*128*3,256),256,0,stream>>>(v1, p512, v2, v2s, 512, 128);
  // stage 2 (V=128)
  k_knn_s<2,20><<<dim3(32,BB),256,0,stream>>>(v2s, 128, idx2);
  k_dirs<<<cdiv((long long)BB*128*20,256),256,0,stream>>>(v2, 128, idx2, d2, BB*128*20);
  k_bgemm<0,0,1><<<dim3(32,16,1),256,0,stream>>>(fm3ph, fm3pl, wc4h, wc4l, nullptr, nullptr,
      bc4, feat, nullptr, nullptr, nullptr, 256, 256, 256, 2048, 0, 0, BB*128);
  k_comb<0><<<cdiv((long long)BB*128*1024,256),256,0,stream>>>(feat, idx2, d2, dir4, fm4, nullptr, nullptr, 128, 1024, 0);
  k_colmax<<<cdiv(BB*1024,256),256,0,stream>>>(fm4, fg, 128, 1024);

  // FC head
  k_emb2<<<cdiv(BB*512,4),256,0,stream>>>(xmax, fg, fcw, fcb, out);
  k_h2<<<cdiv(BB*512,4),256,0,stream>>>(xmax, fg, clw1, clb1, gma, bta, hbuf);
  k_pred2<<<cdiv(BB*6,4),256,0,stream>>>(hbuf, clw2, clb2, out);
}